// Round 3
// baseline (819.273 us; speedup 1.0000x reference)
//
#include <hip/hip_runtime.h>
#include <hip/hip_cooperative_groups.h>
#include <math.h>

namespace cg = cooperative_groups;

// Problem dims
#define BL    6
#define CCH   64
#define C3    192
#define L2    1024
#define DIC   128
#define NST   16
#define K4    4
#define PSTR  1088   // padded plane stride: 34 rows * 32 cols
#define NCH   32     // scan chunks per sequence (32 steps each)

#define LOG2E 1.44269504088896340736f
#define LN2C  0.69314718055994530942f

__device__ __forceinline__ float fexp(float x){ return __builtin_amdgcn_exp2f(x*LOG2E); }
__device__ __forceinline__ float fsilu(float x){ return x / (1.f + fexp(-x)); }
__device__ __forceinline__ float fsoftplus(float x){
  if (x > 20.f) return x;
  return __builtin_amdgcn_logf(1.f + fexp(x)) * LN2C;
}
__device__ __forceinline__ float fgelu(float x){
  return 0.5f*x*(1.f + erff(x*0.70710678118654752440f));
}

// All device-side pointers in one param struct (single cooperative-launch arg)
struct MP {
  const float *img, *dz, *sg, *norm_g, *norm_b;
  const float *gn1_g, *gn1_b, *conv1_w, *conv1_b, *gn2_g, *gn2_b, *conv2_w, *conv2_b;
  const float *skip_w, *skip_b, *ln1_g, *ln1_b, *ln2_g, *ln2_b, *in_proj_w;
  const float *dwconv_w, *dwconv_b, *x_proj_w, *dt_proj_w, *dt_proj_b, *A_logs, *Ds;
  const float *out_norm_g, *out_norm_b, *out_proj_w, *fc1_w, *fc1_b, *fc2_w, *fc2_b;
  float *x3c, *xact1, *h1, *xact2, *xp, *x_cmaj, *z_t, *xc, *xconv;
  float *psum1, *psq1, *psum2, *psq2;
  float *part1, *part2, *hend, *u_t, *Bp, *Cp, *dtr, *Ssum, *Hin, *ys_t;
  float *out;
};

// ---------------- phase 1: per-pixel LN of frames + concat; per-block GN1 partials
__device__ __forceinline__ void ph_ln2d(int bx, float* SH, const MP& P){
  float (*ps)[16] = (float(*)[16])SH;          // 64
  float (*pq)[16] = (float(*)[16])(SH + 64);   // 64
  float *gs = SH + 128, *gq = SH + 132;
  int s = bx >> 6;
  int pg = bx & 63;
  int tid = threadIdx.x;
  int px = tid & 15; int cg = tid >> 4;
  int wv = tid >> 6; int lane = tid & 63;
  int p = pg*16 + px;
  int bsmp = s/3;
  const float* fr = P.img + (size_t)s*CCH*L2;
  float vals[4]; float sm=0.f, sq=0.f;
  #pragma unroll
  for (int j=0;j<4;++j){
    int c = cg*4 + j;
    float v = fr[c*L2 + p];
    vals[j]=v; sm+=v; sq+=v*v;
  }
  sm += __shfl_xor(sm,16,64); sq += __shfl_xor(sq,16,64);
  sm += __shfl_xor(sm,32,64); sq += __shfl_xor(sq,32,64);
  if (lane < 16){ ps[wv][lane]=sm; pq[wv][lane]=sq; }
  __syncthreads();
  sm = ps[0][px]+ps[1][px]+ps[2][px]+ps[3][px];
  sq = pq[0][px]+pq[1][px]+pq[2][px]+pq[3][px];
  float mean = sm*(1.f/CCH); float var = sq*(1.f/CCH)-mean*mean;
  float rs = rsqrtf(var + 1e-6f);
  float* o = P.x3c + (size_t)s*C3*L2;
  const float* dzp = P.dz + (size_t)bsmp*CCH*L2;
  const float* sgp = P.sg + (size_t)bsmp*CCH*L2;
  float gsm=0.f, gsq=0.f;
  #pragma unroll
  for (int j=0;j<4;++j){
    int c = cg*4+j;
    float dzv = dzp[c*L2+p];
    float nv  = (vals[j]-mean)*rs*P.norm_g[c] + P.norm_b[c];
    float sgv = sgp[c*L2+p];
    o[c*L2+p] = dzv;
    o[(CCH+c)*L2+p] = nv;
    o[(2*CCH+c)*L2+p] = sgv;
    gsm += dzv+nv+sgv; gsq += dzv*dzv+nv*nv+sgv*sgv;
  }
  for (int m=1;m<64;m<<=1){ gsm+=__shfl_xor(gsm,m,64); gsq+=__shfl_xor(gsq,m,64); }
  if (lane==0){ gs[wv]=gsm; gq[wv]=gsq; }
  __syncthreads();
  if (tid==0){
    P.psum1[bx] = gs[0]+gs[1]+gs[2]+gs[3];
    P.psq1 [bx] = gq[0]+gq[1]+gq[2]+gq[3];
  }
}

// ---------------- GN act + SiLU from partials, padded write
__device__ __forceinline__ void ph_gnact(int bx, const float* __restrict__ x,
    const float* __restrict__ psum, const float* __restrict__ psq,
    const float* __restrict__ g, const float* __restrict__ b,
    int ch, int parts, float inv_n, float eps, float* __restrict__ out){
  int s = bx / ch; int c = bx % ch;
  int tid = threadIdx.x;
  float sm=0.f, sq=0.f;
  for (int i=0;i<parts;++i){ sm += psum[s*parts+i]; sq += psq[s*parts+i]; }
  float mean = sm*inv_n;
  float var = sq*inv_n - mean*mean;
  float rs = rsqrtf(var + eps);
  float gc = g[c]*rs; float bc = b[c] - mean*rs*g[c];
  float4 v = *(const float4*)(x + (size_t)bx*1024 + tid*4);
  float4 o; o.x = fsilu(v.x*gc+bc); o.y = fsilu(v.y*gc+bc);
  o.z = fsilu(v.z*gc+bc); o.w = fsilu(v.w*gc+bc);
  float* pl = out + (size_t)bx*PSTR;
  *(float4*)(pl + 32 + tid*4) = o;
  float4 z4 = make_float4(0.f,0.f,0.f,0.f);
  if (tid < 8)  *(float4*)(pl + tid*4) = z4;
  else if (tid < 16) *(float4*)(pl + 1056 + (tid-8)*4) = z4;
}

// conv helpers (R1, 2-co)
__device__ __forceinline__ void conv_row_acc(float4& a0, float4& a1, float4 mid, float lf, float rt,
    const float* wp0, const float* wp1){
  float w0=wp0[0], w1=wp0[1], w2=wp0[2];
  a0.x = fmaf(w0,lf,   fmaf(w1,mid.x, fmaf(w2,mid.y, a0.x)));
  a0.y = fmaf(w0,mid.x,fmaf(w1,mid.y, fmaf(w2,mid.z, a0.y)));
  a0.z = fmaf(w0,mid.y,fmaf(w1,mid.z, fmaf(w2,mid.w, a0.z)));
  a0.w = fmaf(w0,mid.z,fmaf(w1,mid.w, fmaf(w2,rt,    a0.w)));
  float v0=wp1[0], v1=wp1[1], v2=wp1[2];
  a1.x = fmaf(v0,lf,   fmaf(v1,mid.x, fmaf(v2,mid.y, a1.x)));
  a1.y = fmaf(v0,mid.x,fmaf(v1,mid.y, fmaf(v2,mid.z, a1.y)));
  a1.z = fmaf(v0,mid.y,fmaf(v1,mid.z, fmaf(v2,mid.w, a1.z)));
  a1.w = fmaf(v0,mid.z,fmaf(v1,mid.w, fmaf(v2,rt,    a1.w)));
}

__device__ __forceinline__ void conv_ci_body(float4 m0, float4 m1, float4 m2, int q,
    const float* wp0, const float* wp1, float4& a0, float4& a1){
  float lf0=__shfl_up(m0.w,1,64), rt0=__shfl_down(m0.x,1,64);
  float lf1=__shfl_up(m1.w,1,64), rt1=__shfl_down(m1.x,1,64);
  float lf2=__shfl_up(m2.w,1,64), rt2=__shfl_down(m2.x,1,64);
  if (q==0){ lf0=0.f; lf1=0.f; lf2=0.f; }
  if (q==7){ rt0=0.f; rt1=0.f; rt2=0.f; }
  conv_row_acc(a0,a1,m0,lf0,rt0, wp0+0, wp1+0);
  conv_row_acc(a0,a1,m1,lf1,rt1, wp0+3, wp1+3);
  conv_row_acc(a0,a1,m2,lf2,rt2, wp0+6, wp1+6);
}

// ---------------- phase 3: conv1 192ci->64co, split-K=8 (R1 shape: 2 co/block)
__device__ __forceinline__ void ph_conv1(int bx, const MP& P){
  int kk = bx&7; int cop=(bx>>3)&31; int s=bx>>8;
  int co0 = cop*2, co1 = co0+1;
  int tid = threadIdx.x; int row = tid>>3; int q = tid&7; int col0 = q*4;
  float4 a0 = make_float4(0.f,0.f,0.f,0.f);
  float4 a1 = make_float4(0.f,0.f,0.f,0.f);
  int ci0 = kk*24;
  const float* pl = P.xact1 + ((size_t)s*C3 + ci0)*PSTR + row*32 + col0;
  const float* wp0 = P.conv1_w + (size_t)(co0*C3 + ci0)*9;
  const float* wp1 = P.conv1_w + (size_t)(co1*C3 + ci0)*9;
  float4 m0 = *(const float4*)(pl);
  float4 m1 = *(const float4*)(pl+32);
  float4 m2 = *(const float4*)(pl+64);
  #pragma unroll 2
  for (int i=0;i<24;++i){
    const float* pn = pl + (i<23 ? PSTR : 0);
    float4 n0 = *(const float4*)(pn);
    float4 n1 = *(const float4*)(pn+32);
    float4 n2 = *(const float4*)(pn+64);
    conv_ci_body(m0,m1,m2,q, wp0, wp1, a0, a1);
    wp0 += 9; wp1 += 9; pl = pn; m0=n0; m1=n1; m2=n2;
  }
  float* pp = P.part1 + (size_t)kk*(BL*CCH*L2) + ((size_t)s*CCH+co0)*L2 + row*32+col0;
  *(float4*)pp = a0;
  *(float4*)(pp+L2) = a1;
}

// ---------------- phase 4: reduce conv1 partials + bias -> h1; GN2 partials
__device__ __forceinline__ void ph_reduce1(int bx, float* SH, const MP& P){
  float* s_sm = SH; float* s_sq = SH + 4;
  int co = bx & 63; int s = bx >> 6;
  size_t ofs = ((size_t)s*CCH+co)*L2 + threadIdx.x*4;
  const size_t stride = (size_t)BL*CCH*L2;
  float4 acc = *(const float4*)(P.part1 + ofs);
  #pragma unroll
  for (int kk=1;kk<8;++kk){
    float4 r = *(const float4*)(P.part1 + (size_t)kk*stride + ofs);
    acc.x += r.x; acc.y += r.y; acc.z += r.z; acc.w += r.w;
  }
  float bv = P.conv1_b[co];
  acc.x += bv; acc.y += bv; acc.z += bv; acc.w += bv;
  *(float4*)(P.h1 + ofs) = acc;
  float sm = acc.x+acc.y+acc.z+acc.w;
  float sq = acc.x*acc.x+acc.y*acc.y+acc.z*acc.z+acc.w*acc.w;
  for (int m=1;m<64;m<<=1){ sm+=__shfl_xor(sm,m,64); sq+=__shfl_xor(sq,m,64); }
  int wv = threadIdx.x>>6;
  if ((threadIdx.x&63)==0){ s_sm[wv]=sm; s_sq[wv]=sq; }
  __syncthreads();
  if (threadIdx.x==0){
    P.psum2[bx] = s_sm[0]+s_sm[1]+s_sm[2]+s_sm[3];
    P.psq2 [bx] = s_sq[0]+s_sq[1]+s_sq[2]+s_sq[3];
  }
}

// ---------------- phase 6: conv2 (roles 0/1 = 32ci) + skip 1x1 (role 2)  [R1 shape]
__device__ __forceinline__ void ph_conv2(int bx, const MP& P){
  int t = bx; int role = t % 3; t /= 3;
  int cop = t & 31; int s = t >> 5;
  int co0 = cop*2, co1 = co0+1;
  int tid = threadIdx.x; int row = tid>>3; int q = tid&7; int col0 = q*4;
  int p = row*32+col0;
  float4 a0 = make_float4(0.f,0.f,0.f,0.f);
  float4 a1 = make_float4(0.f,0.f,0.f,0.f);
  if (role < 2){
    int ci0 = role*32;
    const float* pl = P.xact2 + ((size_t)s*CCH + ci0)*PSTR + row*32 + col0;
    const float* wp0 = P.conv2_w + (size_t)(co0*CCH + ci0)*9;
    const float* wp1 = P.conv2_w + (size_t)(co1*CCH + ci0)*9;
    float4 m0 = *(const float4*)(pl);
    float4 m1 = *(const float4*)(pl+32);
    float4 m2 = *(const float4*)(pl+64);
    #pragma unroll 2
    for (int i=0;i<32;++i){
      const float* pn = pl + (i<31 ? PSTR : 0);
      float4 n0 = *(const float4*)(pn);
      float4 n1 = *(const float4*)(pn+32);
      float4 n2 = *(const float4*)(pn+64);
      conv_ci_body(m0,m1,m2,q, wp0, wp1, a0, a1);
      wp0 += 9; wp1 += 9; pl = pn; m0=n0; m1=n1; m2=n2;
    }
  } else {
    const float* x3 = P.x3c + (size_t)s*C3*L2 + p;
    #pragma unroll 4
    for (int ci=0; ci<C3; ++ci){
      float4 v = *(const float4*)(x3 + (size_t)ci*L2);
      float ws0 = P.skip_w[co0*C3+ci], ws1 = P.skip_w[co1*C3+ci];
      a0.x = fmaf(ws0,v.x,a0.x); a0.y = fmaf(ws0,v.y,a0.y); a0.z = fmaf(ws0,v.z,a0.z); a0.w = fmaf(ws0,v.w,a0.w);
      a1.x = fmaf(ws1,v.x,a1.x); a1.y = fmaf(ws1,v.y,a1.y); a1.z = fmaf(ws1,v.z,a1.z); a1.w = fmaf(ws1,v.w,a1.w);
    }
  }
  float* pp = P.part2 + (size_t)role*(BL*CCH*L2) + ((size_t)s*CCH+co0)*L2 + p;
  *(float4*)pp = a0;
  *(float4*)(pp+L2) = a1;
}

// ---------------- phase 7: reduce2
__device__ __forceinline__ void ph_reduce2(int bx, const MP& P){
  int co = bx & 63; int s = bx >> 6;
  int p = threadIdx.x*4;
  size_t ofs = ((size_t)s*CCH+co)*L2 + p;
  const size_t stride = (size_t)BL*CCH*L2;
  float4 r0 = *(const float4*)(P.part2 + ofs);
  float4 r1 = *(const float4*)(P.part2 + stride + ofs);
  float4 r2 = *(const float4*)(P.part2 + 2*stride + ofs);
  float bv = P.conv2_b[co]+P.skip_b[co];
  float4 o;
  o.x = r0.x+r1.x+r2.x+bv;
  o.y = r0.y+r1.y+r2.y+bv;
  o.z = r0.z+r1.z+r2.z+bv;
  o.w = r0.w+r1.w+r2.w+bv;
  *(float4*)(P.x_cmaj + ofs) = o;
  float* xpb = P.xp + ((size_t)s*L2 + p)*CCH + co;
  xpb[0] = o.x; xpb[CCH] = o.y; xpb[2*CCH] = o.z; xpb[3*CCH] = o.w;
}

// ---------------- phase 8: ln1 + in_proj, split-o
__device__ __forceinline__ void ph_ln1_inproj(int bx, float* SH, const MP& P){
  float* xn_s = SH;  // 64*65 = 4160
  int oq = bx & 3; int pg = (bx>>2)&15; int s = bx>>6;
  int p0 = pg*64;
  int tid = threadIdx.x; int wv = __builtin_amdgcn_readfirstlane(tid>>6); int lane = tid&63;
  for (int j=0;j<16;++j){
    int pl = wv*16 + j; int p = p0 + pl;
    float v = P.xp[((size_t)s*L2 + p)*CCH + lane];
    float sm = v, sq = v*v;
    for (int m=1;m<64;m<<=1){ sm += __shfl_xor(sm,m,64); sq += __shfl_xor(sq,m,64); }
    float mean = sm*(1.f/64.f); float var = sq*(1.f/64.f) - mean*mean;
    float rs = rsqrtf(var + 1e-5f);
    xn_s[pl*65 + lane] = (v-mean)*rs*P.ln1_g[lane] + P.ln1_b[lane];
  }
  __syncthreads();
  int px_l = tid & 63;
  int og = __builtin_amdgcn_readfirstlane(tid >> 6);
  int o0 = oq*64 + og*16;
  float acc[16];
  #pragma unroll
  for (int oi=0;oi<16;++oi) acc[oi]=0.f;
  for (int c=0;c<64;++c){
    float xv = xn_s[px_l*65 + c];
    #pragma unroll
    for (int oi=0;oi<16;++oi) acc[oi] = fmaf(P.in_proj_w[(o0+oi)*64 + c], xv, acc[oi]);
  }
  int p = p0 + px_l;
  if (oq < 2){
    #pragma unroll
    for (int oi=0;oi<16;++oi) P.xc[((size_t)s*DIC + o0 + oi)*L2 + p] = acc[oi];
  } else {
    #pragma unroll
    for (int oi=0;oi<16;++oi) P.z_t[((size_t)s*DIC + (o0-128) + oi)*L2 + p] = acc[oi];
  }
}

// ---------------- phase 9: depthwise 3x3 + SiLU
__device__ __forceinline__ void ph_dwconv(int bx, const MP& P){
  int dch = bx & 127; int s = bx >> 7;
  int tid = threadIdx.x; int row = tid>>3; int q = tid&7; int col0 = q*4;
  const float* xr = P.xc + ((size_t)s*DIC+dch)*L2;
  const float* wp = P.dwconv_w + dch*9;
  float bv = P.dwconv_b[dch];
  float4 acc = make_float4(bv,bv,bv,bv);
  #pragma unroll
  for (int dy=-1;dy<=1;++dy){
    int r = row+dy;
    float4 mid = make_float4(0.f,0.f,0.f,0.f);
    if (0<=r && r<32) mid = *(const float4*)(xr + r*32 + col0);
    float lf = __shfl_up(mid.w,1,64); if(q==0) lf=0.f;
    float rt = __shfl_down(mid.x,1,64); if(q==7) rt=0.f;
    float w0=wp[(dy+1)*3], w1=wp[(dy+1)*3+1], w2=wp[(dy+1)*3+2];
    acc.x = fmaf(w0,lf,   fmaf(w1,mid.x, fmaf(w2,mid.y, acc.x)));
    acc.y = fmaf(w0,mid.x,fmaf(w1,mid.y, fmaf(w2,mid.z, acc.y)));
    acc.z = fmaf(w0,mid.y,fmaf(w1,mid.z, fmaf(w2,mid.w, acc.z)));
    acc.w = fmaf(w0,mid.z,fmaf(w1,mid.w, fmaf(w2,rt,    acc.w)));
  }
  acc.x = fsilu(acc.x); acc.y = fsilu(acc.y); acc.z = fsilu(acc.z); acc.w = fsilu(acc.w);
  *(float4*)(P.xconv + ((size_t)s*DIC+dch)*L2 + row*32+col0) = acc;
}

// ---------------- phase 10: x_proj -> dt ranks, B, C, u_t (k==0)
__device__ __forceinline__ void ph_xproj(int bx, float* SH, const MP& P){
  float* smem = SH;    // 128*68 = 8704
  int pg = bx & 15; int sk = bx >> 4;
  int k = sk & 3; int s = sk >> 2;
  int tid = threadIdx.x;
  for (int i = tid; i < 128*16; i += 256){
    int dr = i>>4; int j4 = (i&15)*4;
    float4 v = *(const float4*)(P.xconv + ((size_t)(s*DIC + dr))*L2 + pg*64 + j4);
    *(float4*)&smem[dr*68 + j4] = v;
  }
  __syncthreads();
  if (k == 0){
    float* ub = P.u_t + ((size_t)(s*L2) + pg*64)*DIC;
    for (int i = tid; i < 64*128; i += 256){
      int px2 = i>>7; int dd = i&127;
      ub[(size_t)px2*DIC + dd] = smem[dd*68 + px2];
    }
  }
  int px = tid & 63;
  int cgrp = __builtin_amdgcn_readfirstlane(tid >> 6);
  int c0 = cgrp*9;
  const float* wb = P.x_proj_w + (size_t)(k*36 + c0)*DIC;
  float acc[9];
  #pragma unroll
  for (int ci=0;ci<9;++ci) acc[ci]=0.f;
  for (int d=0; d<DIC; ++d){
    float xv = smem[d*68 + px];
    #pragma unroll
    for (int ci=0;ci<9;++ci) acc[ci] = fmaf(wb[ci*DIC+d], xv, acc[ci]);
  }
  __syncthreads();
  #pragma unroll
  for (int ci=0;ci<9;++ci) smem[(c0+ci)*68 + px] = acc[ci];
  __syncthreads();
  {
    int pp = tid >> 2; int r = tid & 3;
    P.dtr[((size_t)sk*L2 + pg*64 + pp)*4 + r] = smem[r*68 + pp];
  }
  float* Bb = P.Bp + ((size_t)sk*L2 + pg*64)*NST;
  float* Cb = P.Cp + ((size_t)sk*L2 + pg*64)*NST;
  for (int i = tid; i < 1024; i += 256){
    int pp = i>>4; int n = i&15;
    Bb[pp*NST + n] = smem[(4+n)*68 + pp];
    Cb[pp*NST + n] = smem[(20+n)*68 + pp];
  }
}

// scan pixel for direction k, chunk ch, step j
__device__ __forceinline__ int scan_pix32(int ch, int j, int k){
  if (k==0) return ch*32 + j;
  if (k==1) return j*32 + ch;
  if (k==2) return 1023 - (ch*32 + j);
  return 1023 - (j*32 + ch);
}

struct StepB { float4 dt4; float uv; float4 B0,B1,B2,B3; };
__device__ __forceinline__ StepB loadB(const float* dr, const float* ub, const float* Bb, int p){
  StepB r;
  r.dt4 = *(const float4*)(dr + (size_t)p*4);
  r.uv = ub[(size_t)p*DIC];
  const float* bp = Bb + p*NST;
  r.B0 = *(const float4*)bp; r.B1 = *(const float4*)(bp+4);
  r.B2 = *(const float4*)(bp+8); r.B3 = *(const float4*)(bp+12);
  return r;
}
__device__ __forceinline__ float dt_eval(float4 w4, float bb, float4 d4){
  return fsoftplus(fmaf(w4.x,d4.x,fmaf(w4.y,d4.y,fmaf(w4.z,d4.z,fmaf(w4.w,d4.w,bb)))));
}

// ---------------- phase 11: scan pass 1 (chunk-local h + sum(dt))
__device__ __forceinline__ void ph_scan_part(int bx, const MP& P){
  int chp = bx & 15; int sk = bx >> 4;
  int k = sk & 3; int s = sk >> 2;
  int tid = threadIdx.x; int d = tid & 127; int ch = chp*2 + (tid>>7);
  float aco[16];
  {
    const float* ab = P.A_logs + (size_t)(k*DIC+d)*NST;
    #pragma unroll
    for (int n=0;n<16;++n) aco[n] = -LOG2E * fexp(ab[n]);
  }
  float4 w4 = *(const float4*)(P.dt_proj_w + (size_t)(k*DIC+d)*4);
  float bb = P.dt_proj_b[k*DIC+d];
  float h[16]; float Sacc = 0.f;
  #pragma unroll
  for (int n=0;n<16;++n) h[n]=0.f;
  const float* dr = P.dtr + (size_t)sk*L2*4;
  const float* ub = P.u_t + (size_t)s*L2*DIC + d;
  const float* Bb = P.Bp + (size_t)sk*L2*NST;
  StepB cur = loadB(dr, ub, Bb, scan_pix32(ch, 0, k));
  #pragma unroll 4
  for (int j=0;j<32;++j){
    StepB nxt;
    if (j < 31) nxt = loadB(dr, ub, Bb, scan_pix32(ch, j+1, k));
    float dtv = dt_eval(w4, bb, cur.dt4);
    Sacc += dtv;
    float tv = dtv*cur.uv;
    #define PSTEP(NI, BV) { float a_ = __builtin_amdgcn_exp2f(dtv*aco[NI]); \
      h[NI] = fmaf(a_, h[NI], tv*(BV)); }
    PSTEP(0,cur.B0.x) PSTEP(1,cur.B0.y) PSTEP(2,cur.B0.z) PSTEP(3,cur.B0.w)
    PSTEP(4,cur.B1.x) PSTEP(5,cur.B1.y) PSTEP(6,cur.B1.z) PSTEP(7,cur.B1.w)
    PSTEP(8,cur.B2.x) PSTEP(9,cur.B2.y) PSTEP(10,cur.B2.z) PSTEP(11,cur.B2.w)
    PSTEP(12,cur.B3.x) PSTEP(13,cur.B3.y) PSTEP(14,cur.B3.z) PSTEP(15,cur.B3.w)
    #undef PSTEP
    cur = nxt;
  }
  size_t base = ((size_t)(sk*NCH + ch)*DIC + d)*NST;
  #pragma unroll
  for (int q4=0;q4<4;++q4)
    *(float4*)(P.hend + base + q4*4)  = make_float4(h[q4*4],h[q4*4+1],h[q4*4+2],h[q4*4+3]);
  P.Ssum[(size_t)(sk*NCH + ch)*DIC + d] = Sacc;
}

// ---------------- phase 12: serial chunk prefix
__device__ __forceinline__ void ph_scan_fix(int bx, const MP& P){
  int t = bx*256 + threadIdx.x;
  int n = t & 15; int d = (t>>4) & 127; int sk = t >> 11; int k = sk & 3;
  float aco = -LOG2E * fexp(P.A_logs[(size_t)(k*DIC+d)*NST + n]);
  float H = 0.f;
  #pragma unroll 8
  for (int ch=0; ch<NCH; ++ch){
    size_t sidx = (size_t)(sk*NCH + ch)*DIC + d;
    float pa = __builtin_amdgcn_exp2f(aco * P.Ssum[sidx]);
    float he = P.hend[sidx*NST + n];
    P.Hin[sidx*NST + n] = H;
    H = fmaf(pa, H, he);
  }
}

// ---------------- phase 13: full scan + y output
__device__ __forceinline__ void ph_scan_y(int bx, const MP& P){
  int chp = bx & 15; int sk = bx >> 4;
  int k = sk & 3; int s = sk >> 2;
  int tid = threadIdx.x; int d = tid & 127; int ch = chp*2 + (tid>>7);
  float aco[16];
  {
    const float* ab = P.A_logs + (size_t)(k*DIC+d)*NST;
    #pragma unroll
    for (int n=0;n<16;++n) aco[n] = -LOG2E * fexp(ab[n]);
  }
  float4 w4 = *(const float4*)(P.dt_proj_w + (size_t)(k*DIC+d)*4);
  float bb = P.dt_proj_b[k*DIC+d];
  float Dv = P.Ds[k*DIC+d];
  float h[16];
  size_t hbase = ((size_t)(sk*NCH + ch)*DIC + d)*NST;
  #pragma unroll
  for (int q4=0;q4<4;++q4){
    float4 hv = *(const float4*)(P.Hin + hbase + q4*4);
    h[q4*4]=hv.x; h[q4*4+1]=hv.y; h[q4*4+2]=hv.z; h[q4*4+3]=hv.w;
  }
  const float* dr = P.dtr + (size_t)sk*L2*4;
  const float* ub = P.u_t + (size_t)s*L2*DIC + d;
  const float* Bb = P.Bp + (size_t)sk*L2*NST;
  const float* Cb = P.Cp + (size_t)sk*L2*NST;
  float* yb = P.ys_t + (size_t)sk*L2*DIC + d;
  int pcur = scan_pix32(ch, 0, k);
  StepB cur = loadB(dr, ub, Bb, pcur);
  float4 Cc0 = *(const float4*)(Cb + pcur*NST);
  float4 Cc1 = *(const float4*)(Cb + pcur*NST + 4);
  float4 Cc2 = *(const float4*)(Cb + pcur*NST + 8);
  float4 Cc3 = *(const float4*)(Cb + pcur*NST + 12);
  #pragma unroll 4
  for (int j=0;j<32;++j){
    StepB nxt; float4 Cn0, Cn1, Cn2, Cn3; int pn = pcur;
    if (j < 31){
      pn = scan_pix32(ch, j+1, k);
      nxt = loadB(dr, ub, Bb, pn);
      Cn0 = *(const float4*)(Cb + pn*NST);
      Cn1 = *(const float4*)(Cb + pn*NST + 4);
      Cn2 = *(const float4*)(Cb + pn*NST + 8);
      Cn3 = *(const float4*)(Cb + pn*NST + 12);
    }
    float dtv = dt_eval(w4, bb, cur.dt4);
    float tv = dtv*cur.uv;
    float y0=0.f, y1=0.f, y2=0.f, y3=0.f;
    #define YSTEP(NI, BV, CV, YA) { float a_ = __builtin_amdgcn_exp2f(dtv*aco[NI]); \
      h[NI] = fmaf(a_, h[NI], tv*(BV)); YA = fmaf(h[NI], (CV), YA); }
    YSTEP(0,cur.B0.x,Cc0.x,y0) YSTEP(1,cur.B0.y,Cc0.y,y1) YSTEP(2,cur.B0.z,Cc0.z,y2) YSTEP(3,cur.B0.w,Cc0.w,y3)
    YSTEP(4,cur.B1.x,Cc1.x,y0) YSTEP(5,cur.B1.y,Cc1.y,y1) YSTEP(6,cur.B1.z,Cc1.z,y2) YSTEP(7,cur.B1.w,Cc1.w,y3)
    YSTEP(8,cur.B2.x,Cc2.x,y0) YSTEP(9,cur.B2.y,Cc2.y,y1) YSTEP(10,cur.B2.z,Cc2.z,y2) YSTEP(11,cur.B2.w,Cc2.w,y3)
    YSTEP(12,cur.B3.x,Cc3.x,y0) YSTEP(13,cur.B3.y,Cc3.y,y1) YSTEP(14,cur.B3.z,Cc3.z,y2) YSTEP(15,cur.B3.w,Cc3.w,y3)
    #undef YSTEP
    yb[(size_t)pcur*DIC] = fmaf(cur.uv, Dv, (y0+y1)+(y2+y3));
    cur = nxt; Cc0 = Cn0; Cc1 = Cn1; Cc2 = Cn2; Cc3 = Cn3; pcur = pn;
  }
}

// ---------------- phase 14: fused tail
__device__ __forceinline__ void ph_tail(int bx, float* SH, const MP& P){
  float* yt  = SH;           // 128*17 = 2176
  float* xvt = SH + 2176;    // 64*17  = 1088
  float* ts  = SH + 3264;    // 64*17  = 1088
  int s = bx >> 6; int pg = bx & 63;
  int tid = threadIdx.x;
  {
    int wv = __builtin_amdgcn_readfirstlane(tid>>6); int lane = tid&63;
    int d0 = lane, d1 = lane+64;
    for (int i=0;i<4;++i){
      int px = i*4 + wv; int p = pg*16 + px;
      const float* yb = P.ys_t + ((size_t)(s*4)*L2 + p)*DIC;
      float ya = yb[d0] + yb[(size_t)L2*DIC + d0] + yb[(size_t)2*L2*DIC + d0] + yb[(size_t)3*L2*DIC + d0];
      float yc = yb[d1] + yb[(size_t)L2*DIC + d1] + yb[(size_t)2*L2*DIC + d1] + yb[(size_t)3*L2*DIC + d1];
      float sm = ya+yc, sq = ya*ya+yc*yc;
      for (int m=1;m<64;m<<=1){ sm+=__shfl_xor(sm,m,64); sq+=__shfl_xor(sq,m,64); }
      float mean = sm*(1.f/128.f); float var = sq*(1.f/128.f)-mean*mean;
      float rs = rsqrtf(var + 1e-5f);
      float yn0 = (ya-mean)*rs*P.out_norm_g[d0] + P.out_norm_b[d0];
      float yn1 = (yc-mean)*rs*P.out_norm_g[d1] + P.out_norm_b[d1];
      float zv0 = P.z_t[((size_t)s*DIC+d0)*L2 + p];
      float zv1 = P.z_t[((size_t)s*DIC+d1)*L2 + p];
      yt[d0*17 + px] = yn0 * fsilu(zv0);
      yt[d1*17 + px] = yn1 * fsilu(zv1);
    }
  }
  __syncthreads();
  {
    int px = tid & 15; int cgp = tid >> 4;
    int c0 = cgp*4;
    float a0=0.f,a1=0.f,a2=0.f,a3=0.f;
    for (int d=0; d<DIC; ++d){
      float yv = yt[d*17 + px];
      a0 = fmaf(P.out_proj_w[(c0+0)*DIC + d], yv, a0);
      a1 = fmaf(P.out_proj_w[(c0+1)*DIC + d], yv, a1);
      a2 = fmaf(P.out_proj_w[(c0+2)*DIC + d], yv, a2);
      a3 = fmaf(P.out_proj_w[(c0+3)*DIC + d], yv, a3);
    }
    int p = pg*16 + px;
    size_t base = ((size_t)s*CCH + c0)*L2 + p;
    xvt[(c0+0)*17 + px] = P.x_cmaj[base]      + a0;
    xvt[(c0+1)*17 + px] = P.x_cmaj[base+L2]   + a1;
    xvt[(c0+2)*17 + px] = P.x_cmaj[base+2*L2] + a2;
    xvt[(c0+3)*17 + px] = P.x_cmaj[base+3*L2] + a3;
  }
  __syncthreads();
  int px = tid & 15; int cgp = tid >> 4;
  float sm=0.f, sq=0.f;
  for (int c=0;c<64;++c){ float v = xvt[c*17+px]; sm+=v; sq+=v*v; }
  float mean = sm*(1.f/64.f);
  float rs = rsqrtf(sq*(1.f/64.f) - mean*mean + 1e-5f);
  int o0 = cgp*4;
  float t[4];
  #pragma unroll
  for (int oi=0;oi<4;++oi) t[oi] = P.fc1_b[o0+oi];
  for (int c=0;c<64;++c){
    float xn = (xvt[c*17+px]-mean)*rs*P.ln2_g[c] + P.ln2_b[c];
    #pragma unroll
    for (int oi=0;oi<4;++oi) t[oi] = fmaf(xn, P.fc1_w[(o0+oi)*64 + c], t[oi]);
  }
  #pragma unroll
  for (int oi=0;oi<4;++oi) ts[(o0+oi)*17 + px] = fgelu(t[oi]);
  __syncthreads();
  int c0 = cgp*4;
  float acc[4];
  #pragma unroll
  for (int ci=0;ci<4;++ci) acc[ci] = xvt[(c0+ci)*17+px] + P.fc2_b[c0+ci];
  for (int o=0;o<64;++o){
    float tv = ts[o*17+px];
    #pragma unroll
    for (int ci=0;ci<4;++ci) acc[ci] = fmaf(tv, P.fc2_w[(c0+ci)*64 + o], acc[ci]);
  }
  int p = pg*16 + px;
  #pragma unroll
  for (int ci=0;ci<4;++ci) P.out[((size_t)s*CCH + c0+ci)*L2 + p] = acc[ci];
}

#define PHASE(NBLK, BODY) \
  for (int bx = blockIdx.x; bx < (NBLK); bx += GD){ BODY; __syncthreads(); } \
  grid.sync();

__global__ __launch_bounds__(256, 2) void k_mega(MP P){
  cg::grid_group grid = cg::this_grid();
  __shared__ float SH[8704];
  const int GD = gridDim.x;

  PHASE(384,  ph_ln2d(bx, SH, P))
  PHASE(1152, ph_gnact(bx, P.x3c, P.psum1, P.psq1, P.gn1_g, P.gn1_b, C3, 64,
                       1.f/(C3*L2), 1e-5f, P.xact1))
  PHASE(1536, ph_conv1(bx, P))
  PHASE(384,  ph_reduce1(bx, SH, P))
  PHASE(384,  ph_gnact(bx, P.h1, P.psum2, P.psq2, P.gn2_g, P.gn2_b, CCH, 64,
                       1.f/(CCH*L2), 1e-5f, P.xact2))
  PHASE(576,  ph_conv2(bx, P))
  PHASE(384,  ph_reduce2(bx, P))
  PHASE(384,  ph_ln1_inproj(bx, SH, P))
  PHASE(768,  ph_dwconv(bx, P))
  PHASE(384,  ph_xproj(bx, SH, P))
  PHASE(384,  ph_scan_part(bx, P))
  PHASE(192,  ph_scan_fix(bx, P))
  PHASE(384,  ph_scan_y(bx, P))
  // last phase: no trailing grid.sync needed
  for (int bx = blockIdx.x; bx < 384; bx += GD){ ph_tail(bx, SH, P); __syncthreads(); }
}

extern "C" void kernel_launch(void* const* d_in, const int* in_sizes, int n_in,
                              void* d_out, int out_size, void* d_ws, size_t ws_size,
                              hipStream_t stream){
  (void)in_sizes; (void)n_in; (void)out_size; (void)ws_size;
  float* ws = (float*)d_ws;
  float* x3c    = ws;                       // 1,179,648
  float* xact1  = x3c    + 1179648;         // 1,253,376 (padded)
  float* h1     = xact1  + 1253376;         // 393,216
  float* xact2  = h1     + 393216;          // 417,792 (padded)
  float* xp     = xact2  + 417792;          // 393,216
  float* x_cmaj = xp     + 393216;          // 393,216
  float* z_t    = x_cmaj + 393216;          // 786,432
  float* xc     = z_t    + 786432;          // 786,432
  float* xconv  = xc     + 786432;          // 786,432
  float* hole   = xconv  + 786432;          // 884,736 scratch (dtr + Ssum)
  float* scanbuf= hole   + 884736;          // 3,145,728 (conv1 partials, then Hin)
  float* ys_t   = scanbuf+ 3145728;         // 3,145,728 (conv2 partials first)
  float* statsb = ys_t   + 3145728;         // psum1(384) psq1(384) psum2(384) psq2(384)

  MP P;
  P.img      = (const float*)d_in[0];
  P.dz       = (const float*)d_in[1];
  P.sg       = (const float*)d_in[2];
  P.norm_g   = (const float*)d_in[3];
  P.norm_b   = (const float*)d_in[4];
  P.gn1_g    = (const float*)d_in[5];
  P.gn1_b    = (const float*)d_in[6];
  P.conv1_w  = (const float*)d_in[7];
  P.conv1_b  = (const float*)d_in[8];
  P.gn2_g    = (const float*)d_in[9];
  P.gn2_b    = (const float*)d_in[10];
  P.conv2_w  = (const float*)d_in[11];
  P.conv2_b  = (const float*)d_in[12];
  P.skip_w   = (const float*)d_in[13];
  P.skip_b   = (const float*)d_in[14];
  P.ln1_g    = (const float*)d_in[15];
  P.ln1_b    = (const float*)d_in[16];
  P.ln2_g    = (const float*)d_in[17];
  P.ln2_b    = (const float*)d_in[18];
  P.in_proj_w= (const float*)d_in[19];
  P.dwconv_w = (const float*)d_in[20];
  P.dwconv_b = (const float*)d_in[21];
  P.x_proj_w = (const float*)d_in[22];
  P.dt_proj_w= (const float*)d_in[23];
  P.dt_proj_b= (const float*)d_in[24];
  P.A_logs   = (const float*)d_in[25];
  P.Ds       = (const float*)d_in[26];
  P.out_norm_g = (const float*)d_in[27];
  P.out_norm_b = (const float*)d_in[28];
  P.out_proj_w = (const float*)d_in[29];
  P.fc1_w    = (const float*)d_in[30];
  P.fc1_b    = (const float*)d_in[31];
  P.fc2_w    = (const float*)d_in[32];
  P.fc2_b    = (const float*)d_in[33];
  P.x3c = x3c; P.xact1 = xact1; P.h1 = h1; P.xact2 = xact2; P.xp = xp;
  P.x_cmaj = x_cmaj; P.z_t = z_t; P.xc = xc; P.xconv = xconv;
  P.psum1 = statsb; P.psq1 = statsb + 384; P.psum2 = statsb + 768; P.psq2 = statsb + 1152;
  // aliases into dead regions (ordering enforced by grid.sync between phases)
  P.part1 = scanbuf;                               // conv1 partials; dead before Hin
  P.part2 = ys_t;                                  // conv2 partials; dead before ys_t
  P.hend  = x3c;                                   // x3c dead after conv2 (phase 6)
  P.u_t   = h1;                                    // h1 dead after gnact2 (phase 5)
  P.Bp    = xp;                                    // xp dead after ln1_inproj (phase 8)
  P.Cp    = xc;                                    // xc dead after dwconv (phase 9)
  P.dtr   = hole;                                  // 98,304
  P.Ssum  = hole + 98304;                          // 98,304
  P.Hin   = scanbuf;                               // part1 dead after reduce1 (phase 4)
  P.ys_t  = ys_t;
  P.out   = (float*)d_out;

  static int g_grid = 0;
  if (g_grid == 0){
    int mb = 0;
    if (hipOccupancyMaxActiveBlocksPerMultiprocessor(&mb, (const void*)k_mega, 256, 0)
        != hipSuccess || mb < 1) mb = 1;
    long g = (long)mb * 256;   // 256 CUs on MI355X
    if (g > 384) g = 384;
    g_grid = (int)g;
  }
  void* args[] = { (void*)&P };
  hipLaunchCooperativeKernel((const void*)k_mega, dim3(g_grid), dim3(256), args, 0, stream);
}

// Round 4
// 372.014 us; speedup vs baseline: 2.2023x; 2.2023x over previous
//
#include <hip/hip_runtime.h>
#include <math.h>

// Problem dims
#define BL    6
#define CCH   64
#define C3    192
#define L2    1024
#define DIC   128
#define NST   16
#define K4    4
#define NCH   32     // scan chunks per sequence (32 steps each)

#define LOG2E 1.44269504088896340736f
#define LN2C  0.69314718055994530942f

__device__ __forceinline__ float fexp(float x){ return __builtin_amdgcn_exp2f(x*LOG2E); }
__device__ __forceinline__ float fsilu(float x){ return x / (1.f + fexp(-x)); }
__device__ __forceinline__ float fsoftplus(float x){
  if (x > 20.f) return x;
  return __builtin_amdgcn_logf(1.f + fexp(x)) * LN2C;
}
__device__ __forceinline__ float fgelu(float x){
  return 0.5f*x*(1.f + erff(x*0.70710678118654752440f));
}

// ---------------- k1: per-pixel LN of frames + concat; per-block GN1 partials (R1 verbatim)
__global__ __launch_bounds__(256) void k_ln2d(const float* __restrict__ img,
    const float* __restrict__ dz, const float* __restrict__ sg,
    const float* __restrict__ g, const float* __restrict__ b, float* __restrict__ x3c,
    float* __restrict__ psum1, float* __restrict__ psq1){
  __shared__ float ps[4][16], pq[4][16], gs[4], gq[4];
  int s = blockIdx.x >> 6;
  int pg = blockIdx.x & 63;
  int tid = threadIdx.x;
  int px = tid & 15; int cg = tid >> 4;
  int wv = tid >> 6; int lane = tid & 63;
  int p = pg*16 + px;
  int bsmp = s/3;
  const float* fr = img + (size_t)s*CCH*L2;
  float vals[4]; float sm=0.f, sq=0.f;
  #pragma unroll
  for (int j=0;j<4;++j){
    int c = cg*4 + j;
    float v = fr[c*L2 + p];
    vals[j]=v; sm+=v; sq+=v*v;
  }
  sm += __shfl_xor(sm,16,64); sq += __shfl_xor(sq,16,64);
  sm += __shfl_xor(sm,32,64); sq += __shfl_xor(sq,32,64);
  if (lane < 16){ ps[wv][lane]=sm; pq[wv][lane]=sq; }
  __syncthreads();
  sm = ps[0][px]+ps[1][px]+ps[2][px]+ps[3][px];
  sq = pq[0][px]+pq[1][px]+pq[2][px]+pq[3][px];
  float mean = sm*(1.f/CCH); float var = sq*(1.f/CCH)-mean*mean;
  float rs = rsqrtf(var + 1e-6f);
  float* o = x3c + (size_t)s*C3*L2;
  const float* dzp = dz + (size_t)bsmp*CCH*L2;
  const float* sgp = sg + (size_t)bsmp*CCH*L2;
  float gsm=0.f, gsq=0.f;
  #pragma unroll
  for (int j=0;j<4;++j){
    int c = cg*4+j;
    float dzv = dzp[c*L2+p];
    float nv  = (vals[j]-mean)*rs*g[c] + b[c];
    float sgv = sgp[c*L2+p];
    o[c*L2+p] = dzv;
    o[(CCH+c)*L2+p] = nv;
    o[(2*CCH+c)*L2+p] = sgv;
    gsm += dzv+nv+sgv; gsq += dzv*dzv+nv*nv+sgv*sgv;
  }
  for (int m=1;m<64;m<<=1){ gsm+=__shfl_xor(gsm,m,64); gsq+=__shfl_xor(gsq,m,64); }
  if (lane==0){ gs[wv]=gsm; gq[wv]=gsq; }
  __syncthreads();
  if (tid==0){
    psum1[blockIdx.x] = gs[0]+gs[1]+gs[2]+gs[3];
    psq1 [blockIdx.x] = gq[0]+gq[1]+gq[2]+gq[3];
  }
}

// conv helpers (R1, 2-co)
__device__ __forceinline__ void conv_row_acc(float4& a0, float4& a1, float4 mid, float lf, float rt,
    const float* wp0, const float* wp1){
  float w0=wp0[0], w1=wp0[1], w2=wp0[2];
  a0.x = fmaf(w0,lf,   fmaf(w1,mid.x, fmaf(w2,mid.y, a0.x)));
  a0.y = fmaf(w0,mid.x,fmaf(w1,mid.y, fmaf(w2,mid.z, a0.y)));
  a0.z = fmaf(w0,mid.y,fmaf(w1,mid.z, fmaf(w2,mid.w, a0.z)));
  a0.w = fmaf(w0,mid.z,fmaf(w1,mid.w, fmaf(w2,rt,    a0.w)));
  float v0=wp1[0], v1=wp1[1], v2=wp1[2];
  a1.x = fmaf(v0,lf,   fmaf(v1,mid.x, fmaf(v2,mid.y, a1.x)));
  a1.y = fmaf(v0,mid.x,fmaf(v1,mid.y, fmaf(v2,mid.z, a1.y)));
  a1.z = fmaf(v0,mid.y,fmaf(v1,mid.z, fmaf(v2,mid.w, a1.z)));
  a1.w = fmaf(v0,mid.z,fmaf(v1,mid.w, fmaf(v2,rt,    a1.w)));
}

__device__ __forceinline__ void conv_ci_body(float4 m0, float4 m1, float4 m2, int q,
    const float* wp0, const float* wp1, float4& a0, float4& a1){
  float lf0=__shfl_up(m0.w,1,64), rt0=__shfl_down(m0.x,1,64);
  float lf1=__shfl_up(m1.w,1,64), rt1=__shfl_down(m1.x,1,64);
  float lf2=__shfl_up(m2.w,1,64), rt2=__shfl_down(m2.x,1,64);
  if (q==0){ lf0=0.f; lf1=0.f; lf2=0.f; }
  if (q==7){ rt0=0.f; rt1=0.f; rt2=0.f; }
  conv_row_acc(a0,a1,m0,lf0,rt0, wp0+0, wp1+0);
  conv_row_acc(a0,a1,m1,lf1,rt1, wp0+3, wp1+3);
  conv_row_acc(a0,a1,m2,lf2,rt2, wp0+6, wp1+6);
}

__device__ __forceinline__ float4 act4(float4 v, float gc, float bc){
  float4 o;
  o.x = fsilu(v.x*gc+bc); o.y = fsilu(v.y*gc+bc);
  o.z = fsilu(v.z*gc+bc); o.w = fsilu(v.w*gc+bc);
  return o;
}

// ---------------- k2: conv1 192ci->64co, split-K=8, GN1-act applied at load (R1 shape)
__global__ __launch_bounds__(256) void k_conv1_act(const float* __restrict__ x3c,
    const float* __restrict__ psum, const float* __restrict__ psq,
    const float* __restrict__ g, const float* __restrict__ b,
    const float* __restrict__ w, float* __restrict__ part){
  int bx = blockIdx.x; int kk = bx&7; int cop=(bx>>3)&31; int s=bx>>8;
  int co0 = cop*2, co1 = co0+1;
  int tid = threadIdx.x; int row = tid>>3; int q = tid&7; int col0 = q*4;
  // GN1 stats (same accumulation order as old k_gnact_pad)
  float sm=0.f, sq_=0.f;
  for (int i=0;i<64;++i){ sm += psum[s*64+i]; sq_ += psq[s*64+i]; }
  float mean = sm*(1.f/(C3*L2));
  float var = sq_*(1.f/(C3*L2)) - mean*mean;
  float rs = rsqrtf(var + 1e-5f);
  float4 z4 = make_float4(0.f,0.f,0.f,0.f);
  float4 a0 = z4, a1 = z4;
  int ci0 = kk*24;
  bool v0 = (row > 0), v2 = (row < 31);
  const float* plane = x3c + ((size_t)s*C3 + ci0)*L2 + col0;
  const float* wp0 = w + (size_t)(co0*C3 + ci0)*9;
  const float* wp1 = w + (size_t)(co1*C3 + ci0)*9;
  float4 r0 = v0 ? *(const float4*)(plane + (row-1)*32) : z4;
  float4 r1 =      *(const float4*)(plane + row*32);
  float4 r2 = v2 ? *(const float4*)(plane + (row+1)*32) : z4;
  #pragma unroll 2
  for (int i=0;i<24;++i){
    const float* pn = plane + (i<23 ? L2 : 0);
    float4 n0 = v0 ? *(const float4*)(pn + (row-1)*32) : z4;
    float4 n1 =      *(const float4*)(pn + row*32);
    float4 n2 = v2 ? *(const float4*)(pn + (row+1)*32) : z4;
    int c = ci0 + i;
    float gw = g[c];
    float gc = gw*rs; float bc = b[c] - mean*rs*gw;
    float4 m0 = v0 ? act4(r0,gc,bc) : z4;
    float4 m1 = act4(r1,gc,bc);
    float4 m2 = v2 ? act4(r2,gc,bc) : z4;
    conv_ci_body(m0,m1,m2,q, wp0, wp1, a0, a1);
    wp0 += 9; wp1 += 9; plane = pn; r0=n0; r1=n1; r2=n2;
  }
  float* pp = part + (size_t)kk*(BL*CCH*L2) + ((size_t)s*CCH+co0)*L2 + row*32+col0;
  *(float4*)pp = a0;
  *(float4*)(pp+L2) = a1;
}

// ---------------- k3: reduce conv1 partials + bias -> h1; GN2 partials (R1 verbatim)
__global__ __launch_bounds__(256) void k_reduce1(const float* __restrict__ part,
    const float* __restrict__ bias, float* __restrict__ h1,
    float* __restrict__ psum2, float* __restrict__ psq2){
  int co = blockIdx.x & 63; int s = blockIdx.x >> 6;
  size_t ofs = ((size_t)s*CCH+co)*L2 + threadIdx.x*4;
  const size_t stride = (size_t)BL*CCH*L2;
  float4 acc = *(const float4*)(part + ofs);
  #pragma unroll
  for (int kk=1;kk<8;++kk){
    float4 r = *(const float4*)(part + (size_t)kk*stride + ofs);
    acc.x += r.x; acc.y += r.y; acc.z += r.z; acc.w += r.w;
  }
  float bv = bias[co];
  acc.x += bv; acc.y += bv; acc.z += bv; acc.w += bv;
  *(float4*)(h1 + ofs) = acc;
  float sm = acc.x+acc.y+acc.z+acc.w;
  float sq = acc.x*acc.x+acc.y*acc.y+acc.z*acc.z+acc.w*acc.w;
  for (int m=1;m<64;m<<=1){ sm+=__shfl_xor(sm,m,64); sq+=__shfl_xor(sq,m,64); }
  __shared__ float s_sm[4], s_sq[4];
  int wv = threadIdx.x>>6;
  if ((threadIdx.x&63)==0){ s_sm[wv]=sm; s_sq[wv]=sq; }
  __syncthreads();
  if (threadIdx.x==0){
    psum2[blockIdx.x] = s_sm[0]+s_sm[1]+s_sm[2]+s_sm[3];
    psq2 [blockIdx.x] = s_sq[0]+s_sq[1]+s_sq[2]+s_sq[3];
  }
}

// ---------------- k4: conv2 (roles 0/1, GN2-act at load) + skip 1x1 (role 2) (R1 shape)
__global__ __launch_bounds__(256) void k_conv2_act(const float* __restrict__ h1,
    const float* __restrict__ x3c,
    const float* __restrict__ psum, const float* __restrict__ psq,
    const float* __restrict__ g, const float* __restrict__ b,
    const float* __restrict__ w2, const float* __restrict__ wsk,
    float* __restrict__ part){
  int t = blockIdx.x; int role = t % 3; t /= 3;
  int cop = t & 31; int s = t >> 5;
  int co0 = cop*2, co1 = co0+1;
  int tid = threadIdx.x; int row = tid>>3; int q = tid&7; int col0 = q*4;
  int p = row*32+col0;
  float4 z4 = make_float4(0.f,0.f,0.f,0.f);
  float4 a0 = z4, a1 = z4;
  if (role < 2){
    float sm=0.f, sq_=0.f;
    for (int i=0;i<64;++i){ sm += psum[s*64+i]; sq_ += psq[s*64+i]; }
    float mean = sm*(1.f/(CCH*L2));
    float var = sq_*(1.f/(CCH*L2)) - mean*mean;
    float rs = rsqrtf(var + 1e-5f);
    int ci0 = role*32;
    bool v0 = (row > 0), v2 = (row < 31);
    const float* plane = h1 + ((size_t)s*CCH + ci0)*L2 + col0;
    const float* wp0 = w2 + (size_t)(co0*CCH + ci0)*9;
    const float* wp1 = w2 + (size_t)(co1*CCH + ci0)*9;
    float4 r0 = v0 ? *(const float4*)(plane + (row-1)*32) : z4;
    float4 r1 =      *(const float4*)(plane + row*32);
    float4 r2 = v2 ? *(const float4*)(plane + (row+1)*32) : z4;
    #pragma unroll 2
    for (int i=0;i<32;++i){
      const float* pn = plane + (i<31 ? L2 : 0);
      float4 n0 = v0 ? *(const float4*)(pn + (row-1)*32) : z4;
      float4 n1 =      *(const float4*)(pn + row*32);
      float4 n2 = v2 ? *(const float4*)(pn + (row+1)*32) : z4;
      int c = ci0 + i;
      float gw = g[c];
      float gc = gw*rs; float bc = b[c] - mean*rs*gw;
      float4 m0 = v0 ? act4(r0,gc,bc) : z4;
      float4 m1 = act4(r1,gc,bc);
      float4 m2 = v2 ? act4(r2,gc,bc) : z4;
      conv_ci_body(m0,m1,m2,q, wp0, wp1, a0, a1);
      wp0 += 9; wp1 += 9; plane = pn; r0=n0; r1=n1; r2=n2;
    }
  } else {
    const float* x3 = x3c + (size_t)s*C3*L2 + p;
    #pragma unroll 4
    for (int ci=0; ci<C3; ++ci){
      float4 v = *(const float4*)(x3 + (size_t)ci*L2);
      float ws0 = wsk[co0*C3+ci], ws1 = wsk[co1*C3+ci];
      a0.x = fmaf(ws0,v.x,a0.x); a0.y = fmaf(ws0,v.y,a0.y); a0.z = fmaf(ws0,v.z,a0.z); a0.w = fmaf(ws0,v.w,a0.w);
      a1.x = fmaf(ws1,v.x,a1.x); a1.y = fmaf(ws1,v.y,a1.y); a1.z = fmaf(ws1,v.z,a1.z); a1.w = fmaf(ws1,v.w,a1.w);
    }
  }
  float* pp = part + (size_t)role*(BL*CCH*L2) + ((size_t)s*CCH+co0)*L2 + p;
  *(float4*)pp = a0;
  *(float4*)(pp+L2) = a1;
}

// ---------------- k5: reduce2 + ln1 + in_proj fused (xp buffer eliminated)
__global__ __launch_bounds__(256) void k_red2_ln1_inproj(const float* __restrict__ part,
    const float* __restrict__ b2, const float* __restrict__ bsk,
    const float* __restrict__ g, const float* __restrict__ b,
    const float* __restrict__ W,
    float* __restrict__ x_cmaj, float* __restrict__ xc, float* __restrict__ z_t){
  __shared__ float xn_s[64*65];
  int bx = blockIdx.x; int oq = bx & 3; int pg = (bx>>2)&15; int s = bx>>6;
  int p0 = pg*64;
  int tid = threadIdx.x;
  const size_t stride = (size_t)BL*CCH*L2;
  // reduce part2 (3 roles) + bias -> LDS tile [px][co]; oq==0 writes x_cmaj
  #pragma unroll
  for (int kq=0;kq<4;++kq){
    int f = kq*256 + tid;
    int co = f >> 4; int px4 = (f & 15)*4;
    size_t ofs = ((size_t)s*CCH+co)*L2 + p0 + px4;
    float4 r0 = *(const float4*)(part + ofs);
    float4 r1 = *(const float4*)(part + stride + ofs);
    float4 r2 = *(const float4*)(part + 2*stride + ofs);
    float bv = b2[co]+bsk[co];
    float4 o;
    o.x = r0.x+r1.x+r2.x+bv;
    o.y = r0.y+r1.y+r2.y+bv;
    o.z = r0.z+r1.z+r2.z+bv;
    o.w = r0.w+r1.w+r2.w+bv;
    if (oq == 0) *(float4*)(x_cmaj + ofs) = o;
    xn_s[(px4+0)*65 + co] = o.x;
    xn_s[(px4+1)*65 + co] = o.y;
    xn_s[(px4+2)*65 + co] = o.z;
    xn_s[(px4+3)*65 + co] = o.w;
  }
  __syncthreads();
  // LN in place (identical math to R1 k_ln1_inproj)
  {
    int wv = __builtin_amdgcn_readfirstlane(tid>>6); int lane = tid&63;
    for (int j=0;j<16;++j){
      int pl = wv*16 + j;
      float v = xn_s[pl*65 + lane];
      float sm = v, sq = v*v;
      for (int m=1;m<64;m<<=1){ sm += __shfl_xor(sm,m,64); sq += __shfl_xor(sq,m,64); }
      float mean = sm*(1.f/64.f); float var = sq*(1.f/64.f) - mean*mean;
      float rs = rsqrtf(var + 1e-5f);
      xn_s[pl*65 + lane] = (v-mean)*rs*g[lane] + b[lane];
    }
  }
  __syncthreads();
  int px_l = tid & 63;
  int og = __builtin_amdgcn_readfirstlane(tid >> 6);
  int o0 = oq*64 + og*16;
  float acc[16];
  #pragma unroll
  for (int oi=0;oi<16;++oi) acc[oi]=0.f;
  for (int c=0;c<64;++c){
    float xv = xn_s[px_l*65 + c];
    #pragma unroll
    for (int oi=0;oi<16;++oi) acc[oi] = fmaf(W[(o0+oi)*64 + c], xv, acc[oi]);
  }
  int p = p0 + px_l;
  if (oq < 2){
    #pragma unroll
    for (int oi=0;oi<16;++oi) xc[((size_t)s*DIC + o0 + oi)*L2 + p] = acc[oi];
  } else {
    #pragma unroll
    for (int oi=0;oi<16;++oi) z_t[((size_t)s*DIC + (o0-128) + oi)*L2 + p] = acc[oi];
  }
}

// ---------------- k6: x_proj + INLINE depthwise 3x3 + SiLU (R2 body; Cp un-aliased)
__global__ __launch_bounds__(256) void k_xproj_dt(const float* __restrict__ xc,
    const float* __restrict__ dww, const float* __restrict__ dwb,
    const float* __restrict__ W,
    float* __restrict__ dtr, float* __restrict__ Bp, float* __restrict__ Cp,
    float* __restrict__ u_t){
  __shared__ float smem[128*68];
  int bx = blockIdx.x; int pg = bx & 15; int sk = bx >> 4;
  int k = sk & 3; int s = sk >> 2;
  int tid = threadIdx.x;
  for (int i = tid; i < 128*16; i += 256){
    int dr = i>>4; int j4 = (i&15)*4;
    int rw = j4>>5; int col0 = j4 & 31;
    int gr = pg*2 + rw;
    int q = i&7;
    const float* xr = xc + ((size_t)s*DIC+dr)*L2;
    const float* wp = dww + dr*9;
    float bv = dwb[dr];
    float4 acc = make_float4(bv,bv,bv,bv);
    #pragma unroll
    for (int dy=-1;dy<=1;++dy){
      int r = gr+dy;
      float4 mid = make_float4(0.f,0.f,0.f,0.f);
      if (0<=r && r<32) mid = *(const float4*)(xr + r*32 + col0);
      float lf = __shfl_up(mid.w,1,64); if(q==0) lf=0.f;
      float rt = __shfl_down(mid.x,1,64); if(q==7) rt=0.f;
      float w0=wp[(dy+1)*3], w1=wp[(dy+1)*3+1], w2=wp[(dy+1)*3+2];
      acc.x = fmaf(w0,lf,   fmaf(w1,mid.x, fmaf(w2,mid.y, acc.x)));
      acc.y = fmaf(w0,mid.x,fmaf(w1,mid.y, fmaf(w2,mid.z, acc.y)));
      acc.z = fmaf(w0,mid.y,fmaf(w1,mid.z, fmaf(w2,mid.w, acc.z)));
      acc.w = fmaf(w0,mid.z,fmaf(w1,mid.w, fmaf(w2,rt,    acc.w)));
    }
    acc.x = fsilu(acc.x); acc.y = fsilu(acc.y); acc.z = fsilu(acc.z); acc.w = fsilu(acc.w);
    *(float4*)&smem[dr*68 + j4] = acc;
  }
  __syncthreads();
  if (k == 0){
    float* ub = u_t + ((size_t)(s*L2) + pg*64)*DIC;
    for (int i = tid; i < 64*128; i += 256){
      int px2 = i>>7; int dd = i&127;
      ub[(size_t)px2*DIC + dd] = smem[dd*68 + px2];
    }
  }
  int px = tid & 63;
  int cgrp = __builtin_amdgcn_readfirstlane(tid >> 6);
  int c0 = cgrp*9;
  const float* wb = W + (size_t)(k*36 + c0)*DIC;
  float acc[9];
  #pragma unroll
  for (int ci=0;ci<9;++ci) acc[ci]=0.f;
  for (int d=0; d<DIC; ++d){
    float xv = smem[d*68 + px];
    #pragma unroll
    for (int ci=0;ci<9;++ci) acc[ci] = fmaf(wb[ci*DIC+d], xv, acc[ci]);
  }
  __syncthreads();
  #pragma unroll
  for (int ci=0;ci<9;++ci) smem[(c0+ci)*68 + px] = acc[ci];
  __syncthreads();
  {
    int pp = tid >> 2; int r = tid & 3;
    dtr[((size_t)sk*L2 + pg*64 + pp)*4 + r] = smem[r*68 + pp];
  }
  float* Bb = Bp + ((size_t)sk*L2 + pg*64)*NST;
  float* Cb = Cp + ((size_t)sk*L2 + pg*64)*NST;
  for (int i = tid; i < 1024; i += 256){
    int pp = i>>4; int n = i&15;
    Bb[pp*NST + n] = smem[(4+n)*68 + pp];
    Cb[pp*NST + n] = smem[(20+n)*68 + pp];
  }
}

// scan pixel for direction k, chunk ch (32 steps), step j
__device__ __forceinline__ int scan_pix32(int ch, int j, int k){
  if (k==0) return ch*32 + j;
  if (k==1) return j*32 + ch;
  if (k==2) return 1023 - (ch*32 + j);
  return 1023 - (j*32 + ch);
}

struct StepB { float4 dt4; float uv; float4 B0,B1,B2,B3; };
__device__ __forceinline__ StepB loadB(const float* dr, const float* ub, const float* Bb, int p){
  StepB r;
  r.dt4 = *(const float4*)(dr + (size_t)p*4);
  r.uv = ub[(size_t)p*DIC];
  const float* bp = Bb + p*NST;
  r.B0 = *(const float4*)bp; r.B1 = *(const float4*)(bp+4);
  r.B2 = *(const float4*)(bp+8); r.B3 = *(const float4*)(bp+12);
  return r;
}
__device__ __forceinline__ float dt_eval(float4 w4, float bb, float4 d4){
  return fsoftplus(fmaf(w4.x,d4.x,fmaf(w4.y,d4.y,fmaf(w4.z,d4.z,fmaf(w4.w,d4.w,bb)))));
}

// ---------------- k7: scan pass 1 (R1 verbatim)
__global__ __launch_bounds__(256,2) void k_scan_part3(const float* __restrict__ dtr,
    const float* __restrict__ dtw, const float* __restrict__ dtb,
    const float* __restrict__ u_t, const float* __restrict__ Bp,
    const float* __restrict__ A_logs, float* __restrict__ hend, float* __restrict__ Ssum){
  int bx = blockIdx.x; int chp = bx & 15; int sk = bx >> 4;
  int k = sk & 3; int s = sk >> 2;
  int tid = threadIdx.x; int d = tid & 127; int ch = chp*2 + (tid>>7);
  float aco[16];
  {
    const float* ab = A_logs + (size_t)(k*DIC+d)*NST;
    #pragma unroll
    for (int n=0;n<16;++n) aco[n] = -LOG2E * fexp(ab[n]);
  }
  float4 w4 = *(const float4*)(dtw + (size_t)(k*DIC+d)*4);
  float bb = dtb[k*DIC+d];
  float h[16]; float Sacc = 0.f;
  #pragma unroll
  for (int n=0;n<16;++n) h[n]=0.f;
  const float* dr = dtr + (size_t)sk*L2*4;
  const float* ub = u_t + (size_t)s*L2*DIC + d;
  const float* Bb = Bp + (size_t)sk*L2*NST;
  StepB cur = loadB(dr, ub, Bb, scan_pix32(ch, 0, k));
  #pragma unroll 4
  for (int j=0;j<32;++j){
    StepB nxt;
    if (j < 31) nxt = loadB(dr, ub, Bb, scan_pix32(ch, j+1, k));
    float dtv = dt_eval(w4, bb, cur.dt4);
    Sacc += dtv;
    float tv = dtv*cur.uv;
    #define PSTEP(NI, BV) { float a_ = __builtin_amdgcn_exp2f(dtv*aco[NI]); \
      h[NI] = fmaf(a_, h[NI], tv*(BV)); }
    PSTEP(0,cur.B0.x) PSTEP(1,cur.B0.y) PSTEP(2,cur.B0.z) PSTEP(3,cur.B0.w)
    PSTEP(4,cur.B1.x) PSTEP(5,cur.B1.y) PSTEP(6,cur.B1.z) PSTEP(7,cur.B1.w)
    PSTEP(8,cur.B2.x) PSTEP(9,cur.B2.y) PSTEP(10,cur.B2.z) PSTEP(11,cur.B2.w)
    PSTEP(12,cur.B3.x) PSTEP(13,cur.B3.y) PSTEP(14,cur.B3.z) PSTEP(15,cur.B3.w)
    #undef PSTEP
    cur = nxt;
  }
  size_t base = ((size_t)(sk*NCH + ch)*DIC + d)*NST;
  #pragma unroll
  for (int q4=0;q4<4;++q4)
    *(float4*)(hend + base + q4*4)  = make_float4(h[q4*4],h[q4*4+1],h[q4*4+2],h[q4*4+3]);
  Ssum[(size_t)(sk*NCH + ch)*DIC + d] = Sacc;
}

// ---------------- k8: serial chunk prefix (R1 verbatim)
__global__ __launch_bounds__(256) void k_scan_fix3(const float* __restrict__ hend,
    const float* __restrict__ Ssum, const float* __restrict__ A_logs,
    float* __restrict__ Hin){
  int t = blockIdx.x*256 + threadIdx.x;
  int n = t & 15; int d = (t>>4) & 127; int sk = t >> 11; int k = sk & 3;
  float aco = -LOG2E * fexp(A_logs[(size_t)(k*DIC+d)*NST + n]);
  float H = 0.f;
  #pragma unroll 8
  for (int ch=0; ch<NCH; ++ch){
    size_t sidx = (size_t)(sk*NCH + ch)*DIC + d;
    float pa = __builtin_amdgcn_exp2f(aco * Ssum[sidx]);
    float he = hend[sidx*NST + n];
    Hin[sidx*NST + n] = H;
    H = fmaf(pa, H, he);
  }
}

// ---------------- k9: full scan + y output (R1 verbatim)
__global__ __launch_bounds__(256,2) void k_scan_y3(const float* __restrict__ dtr,
    const float* __restrict__ dtw, const float* __restrict__ dtb,
    const float* __restrict__ u_t, const float* __restrict__ Bp, const float* __restrict__ Cp,
    const float* __restrict__ A_logs, const float* __restrict__ Ds,
    const float* __restrict__ Hin, float* __restrict__ ys_t){
  int bx = blockIdx.x; int chp = bx & 15; int sk = bx >> 4;
  int k = sk & 3; int s = sk >> 2;
  int tid = threadIdx.x; int d = tid & 127; int ch = chp*2 + (tid>>7);
  float aco[16];
  {
    const float* ab = A_logs + (size_t)(k*DIC+d)*NST;
    #pragma unroll
    for (int n=0;n<16;++n) aco[n] = -LOG2E * fexp(ab[n]);
  }
  float4 w4 = *(const float4*)(dtw + (size_t)(k*DIC+d)*4);
  float bb = dtb[k*DIC+d];
  float Dv = Ds[k*DIC+d];
  float h[16];
  size_t hbase = ((size_t)(sk*NCH + ch)*DIC + d)*NST;
  #pragma unroll
  for (int q4=0;q4<4;++q4){
    float4 hv = *(const float4*)(Hin + hbase + q4*4);
    h[q4*4]=hv.x; h[q4*4+1]=hv.y; h[q4*4+2]=hv.z; h[q4*4+3]=hv.w;
  }
  const float* dr = dtr + (size_t)sk*L2*4;
  const float* ub = u_t + (size_t)s*L2*DIC + d;
  const float* Bb = Bp + (size_t)sk*L2*NST;
  const float* Cb = Cp + (size_t)sk*L2*NST;
  float* yb = ys_t + (size_t)sk*L2*DIC + d;
  int pcur = scan_pix32(ch, 0, k);
  StepB cur = loadB(dr, ub, Bb, pcur);
  float4 Cc0 = *(const float4*)(Cb + pcur*NST);
  float4 Cc1 = *(const float4*)(Cb + pcur*NST + 4);
  float4 Cc2 = *(const float4*)(Cb + pcur*NST + 8);
  float4 Cc3 = *(const float4*)(Cb + pcur*NST + 12);
  #pragma unroll 4
  for (int j=0;j<32;++j){
    StepB nxt; float4 Cn0, Cn1, Cn2, Cn3; int pn = pcur;
    if (j < 31){
      pn = scan_pix32(ch, j+1, k);
      nxt = loadB(dr, ub, Bb, pn);
      Cn0 = *(const float4*)(Cb + pn*NST);
      Cn1 = *(const float4*)(Cb + pn*NST + 4);
      Cn2 = *(const float4*)(Cb + pn*NST + 8);
      Cn3 = *(const float4*)(Cb + pn*NST + 12);
    }
    float dtv = dt_eval(w4, bb, cur.dt4);
    float tv = dtv*cur.uv;
    float y0=0.f, y1=0.f, y2=0.f, y3=0.f;
    #define YSTEP(NI, BV, CV, YA) { float a_ = __builtin_amdgcn_exp2f(dtv*aco[NI]); \
      h[NI] = fmaf(a_, h[NI], tv*(BV)); YA = fmaf(h[NI], (CV), YA); }
    YSTEP(0,cur.B0.x,Cc0.x,y0) YSTEP(1,cur.B0.y,Cc0.y,y1) YSTEP(2,cur.B0.z,Cc0.z,y2) YSTEP(3,cur.B0.w,Cc0.w,y3)
    YSTEP(4,cur.B1.x,Cc1.x,y0) YSTEP(5,cur.B1.y,Cc1.y,y1) YSTEP(6,cur.B1.z,Cc1.z,y2) YSTEP(7,cur.B1.w,Cc1.w,y3)
    YSTEP(8,cur.B2.x,Cc2.x,y0) YSTEP(9,cur.B2.y,Cc2.y,y1) YSTEP(10,cur.B2.z,Cc2.z,y2) YSTEP(11,cur.B2.w,Cc2.w,y3)
    YSTEP(12,cur.B3.x,Cc3.x,y0) YSTEP(13,cur.B3.y,Cc3.y,y1) YSTEP(14,cur.B3.z,Cc3.z,y2) YSTEP(15,cur.B3.w,Cc3.w,y3)
    #undef YSTEP
    yb[(size_t)pcur*DIC] = fmaf(cur.uv, Dv, (y0+y1)+(y2+y3));
    cur = nxt; Cc0 = Cn0; Cc1 = Cn1; Cc2 = Cn2; Cc3 = Cn3; pcur = pn;
  }
}

// ---------------- k10: fused tail (R1 verbatim)
__global__ __launch_bounds__(256) void k_tail(const float* __restrict__ ys_t,
    const float* __restrict__ z_t, const float* __restrict__ ong, const float* __restrict__ onb,
    const float* __restrict__ Wop, const float* __restrict__ x_cmaj,
    const float* __restrict__ g2, const float* __restrict__ b2n,
    const float* __restrict__ w1, const float* __restrict__ b1,
    const float* __restrict__ w2, const float* __restrict__ b2,
    float* __restrict__ out){
  __shared__ float yt[128*17];
  __shared__ float xvt[64*17];
  __shared__ float ts[64*17];
  int s = blockIdx.x >> 6; int pg = blockIdx.x & 63;
  int tid = threadIdx.x;
  {
    int wv = __builtin_amdgcn_readfirstlane(tid>>6); int lane = tid&63;
    int d0 = lane, d1 = lane+64;
    for (int i=0;i<4;++i){
      int px = i*4 + wv; int p = pg*16 + px;
      const float* yb = ys_t + ((size_t)(s*4)*L2 + p)*DIC;
      float ya = yb[d0] + yb[(size_t)L2*DIC + d0] + yb[(size_t)2*L2*DIC + d0] + yb[(size_t)3*L2*DIC + d0];
      float yc = yb[d1] + yb[(size_t)L2*DIC + d1] + yb[(size_t)2*L2*DIC + d1] + yb[(size_t)3*L2*DIC + d1];
      float sm = ya+yc, sq = ya*ya+yc*yc;
      for (int m=1;m<64;m<<=1){ sm+=__shfl_xor(sm,m,64); sq+=__shfl_xor(sq,m,64); }
      float mean = sm*(1.f/128.f); float var = sq*(1.f/128.f)-mean*mean;
      float rs = rsqrtf(var + 1e-5f);
      float yn0 = (ya-mean)*rs*ong[d0] + onb[d0];
      float yn1 = (yc-mean)*rs*ong[d1] + onb[d1];
      float zv0 = z_t[((size_t)s*DIC+d0)*L2 + p];
      float zv1 = z_t[((size_t)s*DIC+d1)*L2 + p];
      yt[d0*17 + px] = yn0 * fsilu(zv0);
      yt[d1*17 + px] = yn1 * fsilu(zv1);
    }
  }
  __syncthreads();
  {
    int px = tid & 15; int cgp = tid >> 4;
    int c0 = cgp*4;
    float a0=0.f,a1=0.f,a2=0.f,a3=0.f;
    for (int d=0; d<DIC; ++d){
      float yv = yt[d*17 + px];
      a0 = fmaf(Wop[(c0+0)*DIC + d], yv, a0);
      a1 = fmaf(Wop[(c0+1)*DIC + d], yv, a1);
      a2 = fmaf(Wop[(c0+2)*DIC + d], yv, a2);
      a3 = fmaf(Wop[(c0+3)*DIC + d], yv, a3);
    }
    int p = pg*16 + px;
    size_t base = ((size_t)s*CCH + c0)*L2 + p;
    xvt[(c0+0)*17 + px] = x_cmaj[base]      + a0;
    xvt[(c0+1)*17 + px] = x_cmaj[base+L2]   + a1;
    xvt[(c0+2)*17 + px] = x_cmaj[base+2*L2] + a2;
    xvt[(c0+3)*17 + px] = x_cmaj[base+3*L2] + a3;
  }
  __syncthreads();
  int px = tid & 15; int cgp = tid >> 4;
  float sm=0.f, sq=0.f;
  for (int c=0;c<64;++c){ float v = xvt[c*17+px]; sm+=v; sq+=v*v; }
  float mean = sm*(1.f/64.f);
  float rs = rsqrtf(sq*(1.f/64.f) - mean*mean + 1e-5f);
  int o0 = cgp*4;
  float t[4];
  #pragma unroll
  for (int oi=0;oi<4;++oi) t[oi] = b1[o0+oi];
  for (int c=0;c<64;++c){
    float xn = (xvt[c*17+px]-mean)*rs*g2[c] + b2n[c];
    #pragma unroll
    for (int oi=0;oi<4;++oi) t[oi] = fmaf(xn, w1[(o0+oi)*64 + c], t[oi]);
  }
  #pragma unroll
  for (int oi=0;oi<4;++oi) ts[(o0+oi)*17 + px] = fgelu(t[oi]);
  __syncthreads();
  int c0 = cgp*4;
  float acc[4];
  #pragma unroll
  for (int ci=0;ci<4;++ci) acc[ci] = xvt[(c0+ci)*17+px] + b2[c0+ci];
  for (int o=0;o<64;++o){
    float tv = ts[o*17+px];
    #pragma unroll
    for (int ci=0;ci<4;++ci) acc[ci] = fmaf(tv, w2[(c0+ci)*64 + o], acc[ci]);
  }
  int p = pg*16 + px;
  #pragma unroll
  for (int ci=0;ci<4;++ci) out[((size_t)s*CCH + c0+ci)*L2 + p] = acc[ci];
}

extern "C" void kernel_launch(void* const* d_in, const int* in_sizes, int n_in,
                              void* d_out, int out_size, void* d_ws, size_t ws_size,
                              hipStream_t stream){
  (void)in_sizes; (void)n_in; (void)out_size; (void)ws_size;
  const float* img      = (const float*)d_in[0];
  const float* dz       = (const float*)d_in[1];
  const float* sg       = (const float*)d_in[2];
  const float* norm_g   = (const float*)d_in[3];
  const float* norm_b   = (const float*)d_in[4];
  const float* gn1_g    = (const float*)d_in[5];
  const float* gn1_b    = (const float*)d_in[6];
  const float* conv1_w  = (const float*)d_in[7];
  const float* conv1_b  = (const float*)d_in[8];
  const float* gn2_g    = (const float*)d_in[9];
  const float* gn2_b    = (const float*)d_in[10];
  const float* conv2_w  = (const float*)d_in[11];
  const float* conv2_b  = (const float*)d_in[12];
  const float* skip_w   = (const float*)d_in[13];
  const float* skip_b   = (const float*)d_in[14];
  const float* ln1_g    = (const float*)d_in[15];
  const float* ln1_b    = (const float*)d_in[16];
  const float* ln2_g    = (const float*)d_in[17];
  const float* ln2_b    = (const float*)d_in[18];
  const float* in_proj_w= (const float*)d_in[19];
  const float* dwconv_w = (const float*)d_in[20];
  const float* dwconv_b = (const float*)d_in[21];
  const float* x_proj_w = (const float*)d_in[22];
  const float* dt_proj_w= (const float*)d_in[23];
  const float* dt_proj_b= (const float*)d_in[24];
  const float* A_logs   = (const float*)d_in[25];
  const float* Ds       = (const float*)d_in[26];
  const float* out_norm_g = (const float*)d_in[27];
  const float* out_norm_b = (const float*)d_in[28];
  const float* out_proj_w = (const float*)d_in[29];
  const float* fc1_w    = (const float*)d_in[30];
  const float* fc1_b    = (const float*)d_in[31];
  const float* fc2_w    = (const float*)d_in[32];
  const float* fc2_b    = (const float*)d_in[33];

  float* ws = (float*)d_ws;   // layout kept identical to R1 (some slots now free)
  float* x3c    = ws;                       // 1,179,648
  float* xact1  = x3c    + 1179648;         // 1,253,376 (FREE — hend spillover)
  float* h1     = xact1  + 1253376;         // 393,216
  float* xact2  = h1     + 393216;          // 417,792 (FREE — u_t spillover)
  float* xpslot = xact2  + 417792;          // 393,216 (now hosts Bp)
  float* x_cmaj = xpslot + 393216;          // 393,216
  float* z_t    = x_cmaj + 393216;          // 786,432
  float* xc     = z_t    + 786432;          // 786,432
  float* xconv  = xc     + 786432;          // 786,432 (FREE)
  float* hole   = xconv  + 786432;          // 884,736 (dtr + Ssum + Cp)
  float* scanbuf= hole   + 884736;          // 3,145,728 (conv1 partials, then Hin)
  float* ys_t   = scanbuf+ 3145728;         // 3,145,728 (conv2 partials first)
  float* statsb = ys_t   + 3145728;         // psum1(384) psq1(384) psum2(384) psq2(384)
  float* psum1  = statsb;
  float* psq1   = statsb + 384;
  float* psum2  = statsb + 768;
  float* psq2   = statsb + 1152;
  // aliases into dead regions
  float* part1  = scanbuf;          // conv1 partials — consumed before Hin written
  float* part2  = ys_t;             // conv2 partials — consumed before ys_t written
  float* hend   = x3c;              // x3c dead after conv2 (k4); extends into xact1 slot
  float* u_t    = h1;               // h1 dead after conv2 (k4); extends into xact2 slot
  float* Bp     = xpslot;           // dedicated slot (xp buffer eliminated)
  float* dtr    = hole;             // 98,304
  float* Ssum   = hole + 98304;     // 98,304
  float* Cp     = hole + 196608;    // 393,216 (NO aliasing with xc — fixes R2 latent race)
  float* Hin    = scanbuf;          // part1 dead after reduce1 (k3)

  k_ln2d<<<384, 256, 0, stream>>>(img, dz, sg, norm_g, norm_b, x3c, psum1, psq1);
  k_conv1_act<<<1536, 256, 0, stream>>>(x3c, psum1, psq1, gn1_g, gn1_b, conv1_w, part1);
  k_reduce1<<<384, 256, 0, stream>>>(part1, conv1_b, h1, psum2, psq2);
  k_conv2_act<<<576, 256, 0, stream>>>(h1, x3c, psum2, psq2, gn2_g, gn2_b, conv2_w, skip_w, part2);
  k_red2_ln1_inproj<<<384, 256, 0, stream>>>(part2, conv2_b, skip_b, ln1_g, ln1_b, in_proj_w,
                                             x_cmaj, xc, z_t);
  k_xproj_dt<<<384, 256, 0, stream>>>(xc, dwconv_w, dwconv_b, x_proj_w, dtr, Bp, Cp, u_t);
  k_scan_part3<<<384, 256, 0, stream>>>(dtr, dt_proj_w, dt_proj_b, u_t, Bp, A_logs, hend, Ssum);
  k_scan_fix3<<<192, 256, 0, stream>>>(hend, Ssum, A_logs, Hin);
  k_scan_y3<<<384, 256, 0, stream>>>(dtr, dt_proj_w, dt_proj_b, u_t, Bp, Cp, A_logs, Ds, Hin, ys_t);
  k_tail<<<384, 256, 0, stream>>>(ys_t, z_t, out_norm_g, out_norm_b, out_proj_w, x_cmaj,
                                  ln2_g, ln2_b, fc1_w, fc1_b, fc2_w, fc2_b, (float*)d_out);
}

// Round 5
// 305.303 us; speedup vs baseline: 2.6835x; 1.2185x over previous
//
#include <hip/hip_runtime.h>
#include <math.h>

// Problem dims
#define BL    6
#define CCH   64
#define C3    192
#define L2    1024
#define DIC   128
#define NST   16
#define K4    4
#define PSTR  1088   // padded plane stride: 34 rows * 32 cols
#define NCH   32     // scan chunks per sequence (32 steps each)

#define LOG2E 1.44269504088896340736f
#define LN2C  0.69314718055994530942f

__device__ __forceinline__ float fexp(float x){ return __builtin_amdgcn_exp2f(x*LOG2E); }
// silu via hardware v_rcp_f32 (error ~1ulp; avoids ~12-instr IEEE div sequence)
__device__ __forceinline__ float fsilu(float x){ return x * __builtin_amdgcn_rcpf(1.f + fexp(-x)); }
__device__ __forceinline__ float fsoftplus(float x){
  if (x > 20.f) return x;
  return __builtin_amdgcn_logf(1.f + fexp(x)) * LN2C;
}
__device__ __forceinline__ float fgelu(float x){
  return 0.5f*x*(1.f + erff(x*0.70710678118654752440f));
}

// ---------------- k1: per-pixel LN of frames + concat; per-block GN1 partials (R1 verbatim)
__global__ __launch_bounds__(256) void k_ln2d(const float* __restrict__ img,
    const float* __restrict__ dz, const float* __restrict__ sg,
    const float* __restrict__ g, const float* __restrict__ b, float* __restrict__ x3c,
    float* __restrict__ psum1, float* __restrict__ psq1){
  __shared__ float ps[4][16], pq[4][16], gs[4], gq[4];
  int s = blockIdx.x >> 6;
  int pg = blockIdx.x & 63;
  int tid = threadIdx.x;
  int px = tid & 15; int cg = tid >> 4;
  int wv = tid >> 6; int lane = tid & 63;
  int p = pg*16 + px;
  int bsmp = s/3;
  const float* fr = img + (size_t)s*CCH*L2;
  float vals[4]; float sm=0.f, sq=0.f;
  #pragma unroll
  for (int j=0;j<4;++j){
    int c = cg*4 + j;
    float v = fr[c*L2 + p];
    vals[j]=v; sm+=v; sq+=v*v;
  }
  sm += __shfl_xor(sm,16,64); sq += __shfl_xor(sq,16,64);
  sm += __shfl_xor(sm,32,64); sq += __shfl_xor(sq,32,64);
  if (lane < 16){ ps[wv][lane]=sm; pq[wv][lane]=sq; }
  __syncthreads();
  sm = ps[0][px]+ps[1][px]+ps[2][px]+ps[3][px];
  sq = pq[0][px]+pq[1][px]+pq[2][px]+pq[3][px];
  float mean = sm*(1.f/CCH); float var = sq*(1.f/CCH)-mean*mean;
  float rs = rsqrtf(var + 1e-6f);
  float* o = x3c + (size_t)s*C3*L2;
  const float* dzp = dz + (size_t)bsmp*CCH*L2;
  const float* sgp = sg + (size_t)bsmp*CCH*L2;
  float gsm=0.f, gsq=0.f;
  #pragma unroll
  for (int j=0;j<4;++j){
    int c = cg*4+j;
    float dzv = dzp[c*L2+p];
    float nv  = (vals[j]-mean)*rs*g[c] + b[c];
    float sgv = sgp[c*L2+p];
    o[c*L2+p] = dzv;
    o[(CCH+c)*L2+p] = nv;
    o[(2*CCH+c)*L2+p] = sgv;
    gsm += dzv+nv+sgv; gsq += dzv*dzv+nv*nv+sgv*sgv;
  }
  for (int m=1;m<64;m<<=1){ gsm+=__shfl_xor(gsm,m,64); gsq+=__shfl_xor(gsq,m,64); }
  if (lane==0){ gs[wv]=gsm; gq[wv]=gsq; }
  __syncthreads();
  if (tid==0){
    psum1[blockIdx.x] = gs[0]+gs[1]+gs[2]+gs[3];
    psq1 [blockIdx.x] = gq[0]+gq[1]+gq[2]+gq[3];
  }
}

// ---------------- k2/k5: GN act + SiLU from per-block partials, padded write (R1 verbatim)
__global__ __launch_bounds__(256) void k_gnact_pad(const float* __restrict__ x,
    const float* __restrict__ psum, const float* __restrict__ psq,
    const float* __restrict__ g, const float* __restrict__ b,
    int ch, int parts, float inv_n, float eps, float* __restrict__ out){
  int bx = blockIdx.x;
  int s = bx / ch; int c = bx % ch;
  int tid = threadIdx.x;
  float sm=0.f, sq=0.f;
  for (int i=0;i<parts;++i){ sm += psum[s*parts+i]; sq += psq[s*parts+i]; }
  float mean = sm*inv_n;
  float var = sq*inv_n - mean*mean;
  float rs = rsqrtf(var + eps);
  float gc = g[c]*rs; float bc = b[c] - mean*rs*g[c];
  float4 v = *(const float4*)(x + (size_t)bx*1024 + tid*4);
  float4 o; o.x = fsilu(v.x*gc+bc); o.y = fsilu(v.y*gc+bc);
  o.z = fsilu(v.z*gc+bc); o.w = fsilu(v.w*gc+bc);
  float* pl = out + (size_t)bx*PSTR;
  *(float4*)(pl + 32 + tid*4) = o;
  float4 z4 = make_float4(0.f,0.f,0.f,0.f);
  if (tid < 8)  *(float4*)(pl + tid*4) = z4;
  else if (tid < 16) *(float4*)(pl + 1056 + (tid-8)*4) = z4;
}

// conv helpers (R1, 2-co)
__device__ __forceinline__ void conv_row_acc(float4& a0, float4& a1, float4 mid, float lf, float rt,
    const float* wp0, const float* wp1){
  float w0=wp0[0], w1=wp0[1], w2=wp0[2];
  a0.x = fmaf(w0,lf,   fmaf(w1,mid.x, fmaf(w2,mid.y, a0.x)));
  a0.y = fmaf(w0,mid.x,fmaf(w1,mid.y, fmaf(w2,mid.z, a0.y)));
  a0.z = fmaf(w0,mid.y,fmaf(w1,mid.z, fmaf(w2,mid.w, a0.z)));
  a0.w = fmaf(w0,mid.z,fmaf(w1,mid.w, fmaf(w2,rt,    a0.w)));
  float v0=wp1[0], v1=wp1[1], v2=wp1[2];
  a1.x = fmaf(v0,lf,   fmaf(v1,mid.x, fmaf(v2,mid.y, a1.x)));
  a1.y = fmaf(v0,mid.x,fmaf(v1,mid.y, fmaf(v2,mid.z, a1.y)));
  a1.z = fmaf(v0,mid.y,fmaf(v1,mid.z, fmaf(v2,mid.w, a1.z)));
  a1.w = fmaf(v0,mid.z,fmaf(v1,mid.w, fmaf(v2,rt,    a1.w)));
}

__device__ __forceinline__ void conv_ci_body(float4 m0, float4 m1, float4 m2, int q,
    const float* wp0, const float* wp1, float4& a0, float4& a1){
  float lf0=__shfl_up(m0.w,1,64), rt0=__shfl_down(m0.x,1,64);
  float lf1=__shfl_up(m1.w,1,64), rt1=__shfl_down(m1.x,1,64);
  float lf2=__shfl_up(m2.w,1,64), rt2=__shfl_down(m2.x,1,64);
  if (q==0){ lf0=0.f; lf1=0.f; lf2=0.f; }
  if (q==7){ rt0=0.f; rt1=0.f; rt2=0.f; }
  conv_row_acc(a0,a1,m0,lf0,rt0, wp0+0, wp1+0);
  conv_row_acc(a0,a1,m1,lf1,rt1, wp0+3, wp1+3);
  conv_row_acc(a0,a1,m2,lf2,rt2, wp0+6, wp1+6);
}

// ---------------- k3: conv1 192ci->64co, split-K=8, padded input (R1 verbatim)
__global__ __launch_bounds__(256) void k_conv1_split(const float* __restrict__ xact,
    const float* __restrict__ w, float* __restrict__ part){
  int bx = blockIdx.x; int kk = bx&7; int cop=(bx>>3)&31; int s=bx>>8;
  int co0 = cop*2, co1 = co0+1;
  int tid = threadIdx.x; int row = tid>>3; int q = tid&7; int col0 = q*4;
  float4 a0 = make_float4(0.f,0.f,0.f,0.f);
  float4 a1 = make_float4(0.f,0.f,0.f,0.f);
  int ci0 = kk*24;
  const float* pl = xact + ((size_t)s*C3 + ci0)*PSTR + row*32 + col0;
  const float* wp0 = w + (size_t)(co0*C3 + ci0)*9;
  const float* wp1 = w + (size_t)(co1*C3 + ci0)*9;
  float4 m0 = *(const float4*)(pl);
  float4 m1 = *(const float4*)(pl+32);
  float4 m2 = *(const float4*)(pl+64);
  #pragma unroll 2
  for (int i=0;i<24;++i){
    const float* pn = pl + (i<23 ? PSTR : 0);
    float4 n0 = *(const float4*)(pn);
    float4 n1 = *(const float4*)(pn+32);
    float4 n2 = *(const float4*)(pn+64);
    conv_ci_body(m0,m1,m2,q, wp0, wp1, a0, a1);
    wp0 += 9; wp1 += 9; pl = pn; m0=n0; m1=n1; m2=n2;
  }
  float* pp = part + (size_t)kk*(BL*CCH*L2) + ((size_t)s*CCH+co0)*L2 + row*32+col0;
  *(float4*)pp = a0;
  *(float4*)(pp+L2) = a1;
}

// ---------------- k4: reduce conv1 partials + bias -> h1; GN2 partials (R1 verbatim)
__global__ __launch_bounds__(256) void k_reduce1(const float* __restrict__ part,
    const float* __restrict__ bias, float* __restrict__ h1,
    float* __restrict__ psum2, float* __restrict__ psq2){
  int co = blockIdx.x & 63; int s = blockIdx.x >> 6;
  size_t ofs = ((size_t)s*CCH+co)*L2 + threadIdx.x*4;
  const size_t stride = (size_t)BL*CCH*L2;
  float4 acc = *(const float4*)(part + ofs);
  #pragma unroll
  for (int kk=1;kk<8;++kk){
    float4 r = *(const float4*)(part + (size_t)kk*stride + ofs);
    acc.x += r.x; acc.y += r.y; acc.z += r.z; acc.w += r.w;
  }
  float bv = bias[co];
  acc.x += bv; acc.y += bv; acc.z += bv; acc.w += bv;
  *(float4*)(h1 + ofs) = acc;
  float sm = acc.x+acc.y+acc.z+acc.w;
  float sq = acc.x*acc.x+acc.y*acc.y+acc.z*acc.z+acc.w*acc.w;
  for (int m=1;m<64;m<<=1){ sm+=__shfl_xor(sm,m,64); sq+=__shfl_xor(sq,m,64); }
  __shared__ float s_sm[4], s_sq[4];
  int wv = threadIdx.x>>6;
  if ((threadIdx.x&63)==0){ s_sm[wv]=sm; s_sq[wv]=sq; }
  __syncthreads();
  if (threadIdx.x==0){
    psum2[blockIdx.x] = s_sm[0]+s_sm[1]+s_sm[2]+s_sm[3];
    psq2 [blockIdx.x] = s_sq[0]+s_sq[1]+s_sq[2]+s_sq[3];
  }
}

// ---------------- k6: conv2 (roles 0/1 = 32ci each) + skip 1x1 (role 2) (R1 verbatim)
__global__ __launch_bounds__(256) void k_conv2_split(const float* __restrict__ xact2,
    const float* __restrict__ x3c, const float* __restrict__ w2,
    const float* __restrict__ wsk, float* __restrict__ part){
  int t = blockIdx.x; int role = t % 3; t /= 3;
  int cop = t & 31; int s = t >> 5;
  int co0 = cop*2, co1 = co0+1;
  int tid = threadIdx.x; int row = tid>>3; int q = tid&7; int col0 = q*4;
  int p = row*32+col0;
  float4 a0 = make_float4(0.f,0.f,0.f,0.f);
  float4 a1 = make_float4(0.f,0.f,0.f,0.f);
  if (role < 2){
    int ci0 = role*32;
    const float* pl = xact2 + ((size_t)s*CCH + ci0)*PSTR + row*32 + col0;
    const float* wp0 = w2 + (size_t)(co0*CCH + ci0)*9;
    const float* wp1 = w2 + (size_t)(co1*CCH + ci0)*9;
    float4 m0 = *(const float4*)(pl);
    float4 m1 = *(const float4*)(pl+32);
    float4 m2 = *(const float4*)(pl+64);
    #pragma unroll 2
    for (int i=0;i<32;++i){
      const float* pn = pl + (i<31 ? PSTR : 0);
      float4 n0 = *(const float4*)(pn);
      float4 n1 = *(const float4*)(pn+32);
      float4 n2 = *(const float4*)(pn+64);
      conv_ci_body(m0,m1,m2,q, wp0, wp1, a0, a1);
      wp0 += 9; wp1 += 9; pl = pn; m0=n0; m1=n1; m2=n2;
    }
  } else {
    const float* x3 = x3c + (size_t)s*C3*L2 + p;
    #pragma unroll 4
    for (int ci=0; ci<C3; ++ci){
      float4 v = *(const float4*)(x3 + (size_t)ci*L2);
      float ws0 = wsk[co0*C3+ci], ws1 = wsk[co1*C3+ci];
      a0.x = fmaf(ws0,v.x,a0.x); a0.y = fmaf(ws0,v.y,a0.y); a0.z = fmaf(ws0,v.z,a0.z); a0.w = fmaf(ws0,v.w,a0.w);
      a1.x = fmaf(ws1,v.x,a1.x); a1.y = fmaf(ws1,v.y,a1.y); a1.z = fmaf(ws1,v.z,a1.z); a1.w = fmaf(ws1,v.w,a1.w);
    }
  }
  float* pp = part + (size_t)role*(BL*CCH*L2) + ((size_t)s*CCH+co0)*L2 + p;
  *(float4*)pp = a0;
  *(float4*)(pp+L2) = a1;
}

// ---------------- k7: reduce2 + ln1 + in_proj fused (kept from R4; xp buffer eliminated)
__global__ __launch_bounds__(256) void k_red2_ln1_inproj(const float* __restrict__ part,
    const float* __restrict__ b2, const float* __restrict__ bsk,
    const float* __restrict__ g, const float* __restrict__ b,
    const float* __restrict__ W,
    float* __restrict__ x_cmaj, float* __restrict__ xc, float* __restrict__ z_t){
  __shared__ float xn_s[64*65];
  int bx = blockIdx.x; int oq = bx & 3; int pg = (bx>>2)&15; int s = bx>>6;
  int p0 = pg*64;
  int tid = threadIdx.x;
  const size_t stride = (size_t)BL*CCH*L2;
  #pragma unroll
  for (int kq=0;kq<4;++kq){
    int f = kq*256 + tid;
    int co = f >> 4; int px4 = (f & 15)*4;
    size_t ofs = ((size_t)s*CCH+co)*L2 + p0 + px4;
    float4 r0 = *(const float4*)(part + ofs);
    float4 r1 = *(const float4*)(part + stride + ofs);
    float4 r2 = *(const float4*)(part + 2*stride + ofs);
    float bv = b2[co]+bsk[co];
    float4 o;
    o.x = r0.x+r1.x+r2.x+bv;
    o.y = r0.y+r1.y+r2.y+bv;
    o.z = r0.z+r1.z+r2.z+bv;
    o.w = r0.w+r1.w+r2.w+bv;
    if (oq == 0) *(float4*)(x_cmaj + ofs) = o;
    xn_s[(px4+0)*65 + co] = o.x;
    xn_s[(px4+1)*65 + co] = o.y;
    xn_s[(px4+2)*65 + co] = o.z;
    xn_s[(px4+3)*65 + co] = o.w;
  }
  __syncthreads();
  {
    int wv = __builtin_amdgcn_readfirstlane(tid>>6); int lane = tid&63;
    for (int j=0;j<16;++j){
      int pl = wv*16 + j;
      float v = xn_s[pl*65 + lane];
      float sm = v, sq = v*v;
      for (int m=1;m<64;m<<=1){ sm += __shfl_xor(sm,m,64); sq += __shfl_xor(sq,m,64); }
      float mean = sm*(1.f/64.f); float var = sq*(1.f/64.f) - mean*mean;
      float rs = rsqrtf(var + 1e-5f);
      xn_s[pl*65 + lane] = (v-mean)*rs*g[lane] + b[lane];
    }
  }
  __syncthreads();
  int px_l = tid & 63;
  int og = __builtin_amdgcn_readfirstlane(tid >> 6);
  int o0 = oq*64 + og*16;
  float acc[16];
  #pragma unroll
  for (int oi=0;oi<16;++oi) acc[oi]=0.f;
  for (int c=0;c<64;++c){
    float xv = xn_s[px_l*65 + c];
    #pragma unroll
    for (int oi=0;oi<16;++oi) acc[oi] = fmaf(W[(o0+oi)*64 + c], xv, acc[oi]);
  }
  int p = p0 + px_l;
  if (oq < 2){
    #pragma unroll
    for (int oi=0;oi<16;++oi) xc[((size_t)s*DIC + o0 + oi)*L2 + p] = acc[oi];
  } else {
    #pragma unroll
    for (int oi=0;oi<16;++oi) z_t[((size_t)s*DIC + (o0-128) + oi)*L2 + p] = acc[oi];
  }
}

// ---------------- k8: x_proj + INLINE depthwise 3x3 + SiLU (kept from R4)
__global__ __launch_bounds__(256) void k_xproj_dt(const float* __restrict__ xc,
    const float* __restrict__ dww, const float* __restrict__ dwb,
    const float* __restrict__ W,
    float* __restrict__ dtr, float* __restrict__ Bp, float* __restrict__ Cp,
    float* __restrict__ u_t){
  __shared__ float smem[128*68];
  int bx = blockIdx.x; int pg = bx & 15; int sk = bx >> 4;
  int k = sk & 3; int s = sk >> 2;
  int tid = threadIdx.x;
  for (int i = tid; i < 128*16; i += 256){
    int dr = i>>4; int j4 = (i&15)*4;
    int rw = j4>>5; int col0 = j4 & 31;
    int gr = pg*2 + rw;
    int q = i&7;
    const float* xr = xc + ((size_t)s*DIC+dr)*L2;
    const float* wp = dww + dr*9;
    float bv = dwb[dr];
    float4 acc = make_float4(bv,bv,bv,bv);
    #pragma unroll
    for (int dy=-1;dy<=1;++dy){
      int r = gr+dy;
      float4 mid = make_float4(0.f,0.f,0.f,0.f);
      if (0<=r && r<32) mid = *(const float4*)(xr + r*32 + col0);
      float lf = __shfl_up(mid.w,1,64); if(q==0) lf=0.f;
      float rt = __shfl_down(mid.x,1,64); if(q==7) rt=0.f;
      float w0=wp[(dy+1)*3], w1=wp[(dy+1)*3+1], w2=wp[(dy+1)*3+2];
      acc.x = fmaf(w0,lf,   fmaf(w1,mid.x, fmaf(w2,mid.y, acc.x)));
      acc.y = fmaf(w0,mid.x,fmaf(w1,mid.y, fmaf(w2,mid.z, acc.y)));
      acc.z = fmaf(w0,mid.y,fmaf(w1,mid.z, fmaf(w2,mid.w, acc.z)));
      acc.w = fmaf(w0,mid.z,fmaf(w1,mid.w, fmaf(w2,rt,    acc.w)));
    }
    acc.x = fsilu(acc.x); acc.y = fsilu(acc.y); acc.z = fsilu(acc.z); acc.w = fsilu(acc.w);
    *(float4*)&smem[dr*68 + j4] = acc;
  }
  __syncthreads();
  if (k == 0){
    float* ub = u_t + ((size_t)(s*L2) + pg*64)*DIC;
    for (int i = tid; i < 64*128; i += 256){
      int px2 = i>>7; int dd = i&127;
      ub[(size_t)px2*DIC + dd] = smem[dd*68 + px2];
    }
  }
  int px = tid & 63;
  int cgrp = __builtin_amdgcn_readfirstlane(tid >> 6);
  int c0 = cgrp*9;
  const float* wb = W + (size_t)(k*36 + c0)*DIC;
  float acc[9];
  #pragma unroll
  for (int ci=0;ci<9;++ci) acc[ci]=0.f;
  for (int d=0; d<DIC; ++d){
    float xv = smem[d*68 + px];
    #pragma unroll
    for (int ci=0;ci<9;++ci) acc[ci] = fmaf(wb[ci*DIC+d], xv, acc[ci]);
  }
  __syncthreads();
  #pragma unroll
  for (int ci=0;ci<9;++ci) smem[(c0+ci)*68 + px] = acc[ci];
  __syncthreads();
  {
    int pp = tid >> 2; int r = tid & 3;
    dtr[((size_t)sk*L2 + pg*64 + pp)*4 + r] = smem[r*68 + pp];
  }
  float* Bb = Bp + ((size_t)sk*L2 + pg*64)*NST;
  float* Cb = Cp + ((size_t)sk*L2 + pg*64)*NST;
  for (int i = tid; i < 1024; i += 256){
    int pp = i>>4; int n = i&15;
    Bb[pp*NST + n] = smem[(4+n)*68 + pp];
    Cb[pp*NST + n] = smem[(20+n)*68 + pp];
  }
}

// scan pixel for direction k, chunk ch (32 steps), step j
__device__ __forceinline__ int scan_pix32(int ch, int j, int k){
  if (k==0) return ch*32 + j;
  if (k==1) return j*32 + ch;
  if (k==2) return 1023 - (ch*32 + j);
  return 1023 - (j*32 + ch);
}

struct StepB { float4 dt4; float uv; float4 B0,B1,B2,B3; };
__device__ __forceinline__ StepB loadB(const float* dr, const float* ub, const float* Bb, int p){
  StepB r;
  r.dt4 = *(const float4*)(dr + (size_t)p*4);
  r.uv = ub[(size_t)p*DIC];
  const float* bp = Bb + p*NST;
  r.B0 = *(const float4*)bp; r.B1 = *(const float4*)(bp+4);
  r.B2 = *(const float4*)(bp+8); r.B3 = *(const float4*)(bp+12);
  return r;
}
__device__ __forceinline__ float dt_eval(float4 w4, float bb, float4 d4){
  return fsoftplus(fmaf(w4.x,d4.x,fmaf(w4.y,d4.y,fmaf(w4.z,d4.z,fmaf(w4.w,d4.w,bb)))));
}

// ---------------- k9: scan pass 1 (R1 verbatim)
__global__ __launch_bounds__(256,2) void k_scan_part3(const float* __restrict__ dtr,
    const float* __restrict__ dtw, const float* __restrict__ dtb,
    const float* __restrict__ u_t, const float* __restrict__ Bp,
    const float* __restrict__ A_logs, float* __restrict__ hend, float* __restrict__ Ssum){
  int bx = blockIdx.x; int chp = bx & 15; int sk = bx >> 4;
  int k = sk & 3; int s = sk >> 2;
  int tid = threadIdx.x; int d = tid & 127; int ch = chp*2 + (tid>>7);
  float aco[16];
  {
    const float* ab = A_logs + (size_t)(k*DIC+d)*NST;
    #pragma unroll
    for (int n=0;n<16;++n) aco[n] = -LOG2E * fexp(ab[n]);
  }
  float4 w4 = *(const float4*)(dtw + (size_t)(k*DIC+d)*4);
  float bb = dtb[k*DIC+d];
  float h[16]; float Sacc = 0.f;
  #pragma unroll
  for (int n=0;n<16;++n) h[n]=0.f;
  const float* dr = dtr + (size_t)sk*L2*4;
  const float* ub = u_t + (size_t)s*L2*DIC + d;
  const float* Bb = Bp + (size_t)sk*L2*NST;
  StepB cur = loadB(dr, ub, Bb, scan_pix32(ch, 0, k));
  #pragma unroll 4
  for (int j=0;j<32;++j){
    StepB nxt;
    if (j < 31) nxt = loadB(dr, ub, Bb, scan_pix32(ch, j+1, k));
    float dtv = dt_eval(w4, bb, cur.dt4);
    Sacc += dtv;
    float tv = dtv*cur.uv;
    #define PSTEP(NI, BV) { float a_ = __builtin_amdgcn_exp2f(dtv*aco[NI]); \
      h[NI] = fmaf(a_, h[NI], tv*(BV)); }
    PSTEP(0,cur.B0.x) PSTEP(1,cur.B0.y) PSTEP(2,cur.B0.z) PSTEP(3,cur.B0.w)
    PSTEP(4,cur.B1.x) PSTEP(5,cur.B1.y) PSTEP(6,cur.B1.z) PSTEP(7,cur.B1.w)
    PSTEP(8,cur.B2.x) PSTEP(9,cur.B2.y) PSTEP(10,cur.B2.z) PSTEP(11,cur.B2.w)
    PSTEP(12,cur.B3.x) PSTEP(13,cur.B3.y) PSTEP(14,cur.B3.z) PSTEP(15,cur.B3.w)
    #undef PSTEP
    cur = nxt;
  }
  size_t base = ((size_t)(sk*NCH + ch)*DIC + d)*NST;
  #pragma unroll
  for (int q4=0;q4<4;++q4)
    *(float4*)(hend + base + q4*4)  = make_float4(h[q4*4],h[q4*4+1],h[q4*4+2],h[q4*4+3]);
  Ssum[(size_t)(sk*NCH + ch)*DIC + d] = Sacc;
}

// ---------------- k10: serial chunk prefix (R1 verbatim)
__global__ __launch_bounds__(256) void k_scan_fix3(const float* __restrict__ hend,
    const float* __restrict__ Ssum, const float* __restrict__ A_logs,
    float* __restrict__ Hin){
  int t = blockIdx.x*256 + threadIdx.x;
  int n = t & 15; int d = (t>>4) & 127; int sk = t >> 11; int k = sk & 3;
  float aco = -LOG2E * fexp(A_logs[(size_t)(k*DIC+d)*NST + n]);
  float H = 0.f;
  #pragma unroll 8
  for (int ch=0; ch<NCH; ++ch){
    size_t sidx = (size_t)(sk*NCH + ch)*DIC + d;
    float pa = __builtin_amdgcn_exp2f(aco * Ssum[sidx]);
    float he = hend[sidx*NST + n];
    Hin[sidx*NST + n] = H;
    H = fmaf(pa, H, he);
  }
}

// ---------------- k11: full scan + y output (R1 verbatim)
__global__ __launch_bounds__(256,2) void k_scan_y3(const float* __restrict__ dtr,
    const float* __restrict__ dtw, const float* __restrict__ dtb,
    const float* __restrict__ u_t, const float* __restrict__ Bp, const float* __restrict__ Cp,
    const float* __restrict__ A_logs, const float* __restrict__ Ds,
    const float* __restrict__ Hin, float* __restrict__ ys_t){
  int bx = blockIdx.x; int chp = bx & 15; int sk = bx >> 4;
  int k = sk & 3; int s = sk >> 2;
  int tid = threadIdx.x; int d = tid & 127; int ch = chp*2 + (tid>>7);
  float aco[16];
  {
    const float* ab = A_logs + (size_t)(k*DIC+d)*NST;
    #pragma unroll
    for (int n=0;n<16;++n) aco[n] = -LOG2E * fexp(ab[n]);
  }
  float4 w4 = *(const float4*)(dtw + (size_t)(k*DIC+d)*4);
  float bb = dtb[k*DIC+d];
  float Dv = Ds[k*DIC+d];
  float h[16];
  size_t hbase = ((size_t)(sk*NCH + ch)*DIC + d)*NST;
  #pragma unroll
  for (int q4=0;q4<4;++q4){
    float4 hv = *(const float4*)(Hin + hbase + q4*4);
    h[q4*4]=hv.x; h[q4*4+1]=hv.y; h[q4*4+2]=hv.z; h[q4*4+3]=hv.w;
  }
  const float* dr = dtr + (size_t)sk*L2*4;
  const float* ub = u_t + (size_t)s*L2*DIC + d;
  const float* Bb = Bp + (size_t)sk*L2*NST;
  const float* Cb = Cp + (size_t)sk*L2*NST;
  float* yb = ys_t + (size_t)sk*L2*DIC + d;
  int pcur = scan_pix32(ch, 0, k);
  StepB cur = loadB(dr, ub, Bb, pcur);
  float4 Cc0 = *(const float4*)(Cb + pcur*NST);
  float4 Cc1 = *(const float4*)(Cb + pcur*NST + 4);
  float4 Cc2 = *(const float4*)(Cb + pcur*NST + 8);
  float4 Cc3 = *(const float4*)(Cb + pcur*NST + 12);
  #pragma unroll 4
  for (int j=0;j<32;++j){
    StepB nxt; float4 Cn0, Cn1, Cn2, Cn3; int pn = pcur;
    if (j < 31){
      pn = scan_pix32(ch, j+1, k);
      nxt = loadB(dr, ub, Bb, pn);
      Cn0 = *(const float4*)(Cb + pn*NST);
      Cn1 = *(const float4*)(Cb + pn*NST + 4);
      Cn2 = *(const float4*)(Cb + pn*NST + 8);
      Cn3 = *(const float4*)(Cb + pn*NST + 12);
    }
    float dtv = dt_eval(w4, bb, cur.dt4);
    float tv = dtv*cur.uv;
    float y0=0.f, y1=0.f, y2=0.f, y3=0.f;
    #define YSTEP(NI, BV, CV, YA) { float a_ = __builtin_amdgcn_exp2f(dtv*aco[NI]); \
      h[NI] = fmaf(a_, h[NI], tv*(BV)); YA = fmaf(h[NI], (CV), YA); }
    YSTEP(0,cur.B0.x,Cc0.x,y0) YSTEP(1,cur.B0.y,Cc0.y,y1) YSTEP(2,cur.B0.z,Cc0.z,y2) YSTEP(3,cur.B0.w,Cc0.w,y3)
    YSTEP(4,cur.B1.x,Cc1.x,y0) YSTEP(5,cur.B1.y,Cc1.y,y1) YSTEP(6,cur.B1.z,Cc1.z,y2) YSTEP(7,cur.B1.w,Cc1.w,y3)
    YSTEP(8,cur.B2.x,Cc2.x,y0) YSTEP(9,cur.B2.y,Cc2.y,y1) YSTEP(10,cur.B2.z,Cc2.z,y2) YSTEP(11,cur.B2.w,Cc2.w,y3)
    YSTEP(12,cur.B3.x,Cc3.x,y0) YSTEP(13,cur.B3.y,Cc3.y,y1) YSTEP(14,cur.B3.z,Cc3.z,y2) YSTEP(15,cur.B3.w,Cc3.w,y3)
    #undef YSTEP
    yb[(size_t)pcur*DIC] = fmaf(cur.uv, Dv, (y0+y1)+(y2+y3));
    cur = nxt; Cc0 = Cn0; Cc1 = Cn1; Cc2 = Cn2; Cc3 = Cn3; pcur = pn;
  }
}

// ---------------- k12: fused tail (R1 verbatim)
__global__ __launch_bounds__(256) void k_tail(const float* __restrict__ ys_t,
    const float* __restrict__ z_t, const float* __restrict__ ong, const float* __restrict__ onb,
    const float* __restrict__ Wop, const float* __restrict__ x_cmaj,
    const float* __restrict__ g2, const float* __restrict__ b2n,
    const float* __restrict__ w1, const float* __restrict__ b1,
    const float* __restrict__ w2, const float* __restrict__ b2,
    float* __restrict__ out){
  __shared__ float yt[128*17];
  __shared__ float xvt[64*17];
  __shared__ float ts[64*17];
  int s = blockIdx.x >> 6; int pg = blockIdx.x & 63;
  int tid = threadIdx.x;
  {
    int wv = __builtin_amdgcn_readfirstlane(tid>>6); int lane = tid&63;
    int d0 = lane, d1 = lane+64;
    for (int i=0;i<4;++i){
      int px = i*4 + wv; int p = pg*16 + px;
      const float* yb = ys_t + ((size_t)(s*4)*L2 + p)*DIC;
      float ya = yb[d0] + yb[(size_t)L2*DIC + d0] + yb[(size_t)2*L2*DIC + d0] + yb[(size_t)3*L2*DIC + d0];
      float yc = yb[d1] + yb[(size_t)L2*DIC + d1] + yb[(size_t)2*L2*DIC + d1] + yb[(size_t)3*L2*DIC + d1];
      float sm = ya+yc, sq = ya*ya+yc*yc;
      for (int m=1;m<64;m<<=1){ sm+=__shfl_xor(sm,m,64); sq+=__shfl_xor(sq,m,64); }
      float mean = sm*(1.f/128.f); float var = sq*(1.f/128.f)-mean*mean;
      float rs = rsqrtf(var + 1e-5f);
      float yn0 = (ya-mean)*rs*ong[d0] + onb[d0];
      float yn1 = (yc-mean)*rs*ong[d1] + onb[d1];
      float zv0 = z_t[((size_t)s*DIC+d0)*L2 + p];
      float zv1 = z_t[((size_t)s*DIC+d1)*L2 + p];
      yt[d0*17 + px] = yn0 * fsilu(zv0);
      yt[d1*17 + px] = yn1 * fsilu(zv1);
    }
  }
  __syncthreads();
  {
    int px = tid & 15; int cgp = tid >> 4;
    int c0 = cgp*4;
    float a0=0.f,a1=0.f,a2=0.f,a3=0.f;
    for (int d=0; d<DIC; ++d){
      float yv = yt[d*17 + px];
      a0 = fmaf(Wop[(c0+0)*DIC + d], yv, a0);
      a1 = fmaf(Wop[(c0+1)*DIC + d], yv, a1);
      a2 = fmaf(Wop[(c0+2)*DIC + d], yv, a2);
      a3 = fmaf(Wop[(c0+3)*DIC + d], yv, a3);
    }
    int p = pg*16 + px;
    size_t base = ((size_t)s*CCH + c0)*L2 + p;
    xvt[(c0+0)*17 + px] = x_cmaj[base]      + a0;
    xvt[(c0+1)*17 + px] = x_cmaj[base+L2]   + a1;
    xvt[(c0+2)*17 + px] = x_cmaj[base+2*L2] + a2;
    xvt[(c0+3)*17 + px] = x_cmaj[base+3*L2] + a3;
  }
  __syncthreads();
  int px = tid & 15; int cgp = tid >> 4;
  float sm=0.f, sq=0.f;
  for (int c=0;c<64;++c){ float v = xvt[c*17+px]; sm+=v; sq+=v*v; }
  float mean = sm*(1.f/64.f);
  float rs = rsqrtf(sq*(1.f/64.f) - mean*mean + 1e-5f);
  int o0 = cgp*4;
  float t[4];
  #pragma unroll
  for (int oi=0;oi<4;++oi) t[oi] = b1[o0+oi];
  for (int c=0;c<64;++c){
    float xn = (xvt[c*17+px]-mean)*rs*g2[c] + b2n[c];
    #pragma unroll
    for (int oi=0;oi<4;++oi) t[oi] = fmaf(xn, w1[(o0+oi)*64 + c], t[oi]);
  }
  #pragma unroll
  for (int oi=0;oi<4;++oi) ts[(o0+oi)*17 + px] = fgelu(t[oi]);
  __syncthreads();
  int c0 = cgp*4;
  float acc[4];
  #pragma unroll
  for (int ci=0;ci<4;++ci) acc[ci] = xvt[(c0+ci)*17+px] + b2[c0+ci];
  for (int o=0;o<64;++o){
    float tv = ts[o*17+px];
    #pragma unroll
    for (int ci=0;ci<4;++ci) acc[ci] = fmaf(tv, w2[(c0+ci)*64 + o], acc[ci]);
  }
  int p = pg*16 + px;
  #pragma unroll
  for (int ci=0;ci<4;++ci) out[((size_t)s*CCH + c0+ci)*L2 + p] = acc[ci];
}

extern "C" void kernel_launch(void* const* d_in, const int* in_sizes, int n_in,
                              void* d_out, int out_size, void* d_ws, size_t ws_size,
                              hipStream_t stream){
  (void)in_sizes; (void)n_in; (void)out_size; (void)ws_size;
  const float* img      = (const float*)d_in[0];
  const float* dz       = (const float*)d_in[1];
  const float* sg       = (const float*)d_in[2];
  const float* norm_g   = (const float*)d_in[3];
  const float* norm_b   = (const float*)d_in[4];
  const float* gn1_g    = (const float*)d_in[5];
  const float* gn1_b    = (const float*)d_in[6];
  const float* conv1_w  = (const float*)d_in[7];
  const float* conv1_b  = (const float*)d_in[8];
  const float* gn2_g    = (const float*)d_in[9];
  const float* gn2_b    = (const float*)d_in[10];
  const float* conv2_w  = (const float*)d_in[11];
  const float* conv2_b  = (const float*)d_in[12];
  const float* skip_w   = (const float*)d_in[13];
  const float* skip_b   = (const float*)d_in[14];
  const float* ln1_g    = (const float*)d_in[15];
  const float* ln1_b    = (const float*)d_in[16];
  const float* ln2_g    = (const float*)d_in[17];
  const float* ln2_b    = (const float*)d_in[18];
  const float* in_proj_w= (const float*)d_in[19];
  const float* dwconv_w = (const float*)d_in[20];
  const float* dwconv_b = (const float*)d_in[21];
  const float* x_proj_w = (const float*)d_in[22];
  const float* dt_proj_w= (const float*)d_in[23];
  const float* dt_proj_b= (const float*)d_in[24];
  const float* A_logs   = (const float*)d_in[25];
  const float* Ds       = (const float*)d_in[26];
  const float* out_norm_g = (const float*)d_in[27];
  const float* out_norm_b = (const float*)d_in[28];
  const float* out_proj_w = (const float*)d_in[29];
  const float* fc1_w    = (const float*)d_in[30];
  const float* fc1_b    = (const float*)d_in[31];
  const float* fc2_w    = (const float*)d_in[32];
  const float* fc2_b    = (const float*)d_in[33];

  float* ws = (float*)d_ws;
  float* x3c    = ws;                       // 1,179,648
  float* xact1  = x3c    + 1179648;         // 1,253,376 (padded GN1 act)
  float* h1     = xact1  + 1253376;         // 393,216
  float* xact2  = h1     + 393216;          // 417,792 (padded GN2 act)
  float* xpslot = xact2  + 417792;          // 393,216 (hosts Bp)
  float* x_cmaj = xpslot + 393216;          // 393,216
  float* z_t    = x_cmaj + 393216;          // 786,432
  float* xc     = z_t    + 786432;          // 786,432
  float* cpslot = xc     + 786432;          // 786,432 (hosts Cp; xconv eliminated)
  float* hole   = cpslot + 786432;          // 884,736 (dtr + Ssum)
  float* scanbuf= hole   + 884736;          // 3,145,728 (conv1 partials, then Hin)
  float* ys_t   = scanbuf+ 3145728;         // 3,145,728 (conv2 partials first)
  float* statsb = ys_t   + 3145728;         // psum1(384) psq1(384) psum2(384) psq2(384)
  float* psum1  = statsb;
  float* psq1   = statsb + 384;
  float* psum2  = statsb + 768;
  float* psq2   = statsb + 1152;
  // aliases into dead regions
  float* part1  = scanbuf;          // conv1 partials — consumed before Hin written
  float* part2  = ys_t;             // conv2 partials — consumed before ys_t written
  float* hend   = x3c;              // x3c+xact1 dead after conv2/conv1
  float* u_t    = h1;               // h1+xact2 dead after gnact2/conv2
  float* Bp     = xpslot;
  float* Cp     = cpslot;           // dedicated slot — no alias with xc
  float* dtr    = hole;             // 98,304
  float* Ssum   = hole + 98304;     // 98,304
  float* Hin    = scanbuf;          // part1 dead after reduce1

  k_ln2d<<<384, 256, 0, stream>>>(img, dz, sg, norm_g, norm_b, x3c, psum1, psq1);
  k_gnact_pad<<<6*C3, 256, 0, stream>>>(x3c, psum1, psq1, gn1_g, gn1_b, C3, 64,
                                        1.f/(C3*L2), 1e-5f, xact1);
  k_conv1_split<<<1536, 256, 0, stream>>>(xact1, conv1_w, part1);
  k_reduce1<<<384, 256, 0, stream>>>(part1, conv1_b, h1, psum2, psq2);
  k_gnact_pad<<<6*CCH, 256, 0, stream>>>(h1, psum2, psq2, gn2_g, gn2_b, CCH, 64,
                                         1.f/(CCH*L2), 1e-5f, xact2);
  k_conv2_split<<<576, 256, 0, stream>>>(xact2, x3c, conv2_w, skip_w, part2);
  k_red2_ln1_inproj<<<384, 256, 0, stream>>>(part2, conv2_b, skip_b, ln1_g, ln1_b, in_proj_w,
                                             x_cmaj, xc, z_t);
  k_xproj_dt<<<384, 256, 0, stream>>>(xc, dwconv_w, dwconv_b, x_proj_w, dtr, Bp, Cp, u_t);
  k_scan_part3<<<384, 256, 0, stream>>>(dtr, dt_proj_w, dt_proj_b, u_t, Bp, A_logs, hend, Ssum);
  k_scan_fix3<<<192, 256, 0, stream>>>(hend, Ssum, A_logs, Hin);
  k_scan_y3<<<384, 256, 0, stream>>>(dtr, dt_proj_w, dt_proj_b, u_t, Bp, Cp, A_logs, Ds, Hin, ys_t);
  k_tail<<<384, 256, 0, stream>>>(ys_t, z_t, out_norm_g, out_norm_b, out_proj_w, x_cmaj,
                                  ln2_g, ln2_b, fc1_w, fc1_b, fc2_w, fc2_b, (float*)d_out);
}

// Round 6
// 291.201 us; speedup vs baseline: 2.8134x; 1.0484x over previous
//
#include <hip/hip_runtime.h>
#include <math.h>

// Problem dims
#define BL    6
#define CCH   64
#define C3    192
#define L2    1024
#define DIC   128
#define NST   16
#define K4    4
#define PSTR  1088   // padded plane stride: 34 rows * 32 cols
#define NCH   32     // scan chunks per sequence (32 steps each)

#define LOG2E 1.44269504088896340736f
#define LN2C  0.69314718055994530942f

__device__ __forceinline__ float fexp(float x){ return __builtin_amdgcn_exp2f(x*LOG2E); }
__device__ __forceinline__ float fsilu(float x){ return x * __builtin_amdgcn_rcpf(1.f + fexp(-x)); }
__device__ __forceinline__ float fsoftplus(float x){
  if (x > 20.f) return x;
  return __builtin_amdgcn_logf(1.f + fexp(x)) * LN2C;
}
__device__ __forceinline__ float fgelu(float x){
  return 0.5f*x*(1.f + erff(x*0.70710678118654752440f));
}

// ---------------- k1: per-pixel LN of frames + concat; per-block GN1 partials
__global__ __launch_bounds__(256) void k_ln2d(const float* __restrict__ img,
    const float* __restrict__ dz, const float* __restrict__ sg,
    const float* __restrict__ g, const float* __restrict__ b, float* __restrict__ x3c,
    float* __restrict__ psum1, float* __restrict__ psq1){
  __shared__ float ps[4][16], pq[4][16], gs[4], gq[4];
  int s = blockIdx.x >> 6;
  int pg = blockIdx.x & 63;
  int tid = threadIdx.x;
  int px = tid & 15; int cg = tid >> 4;
  int wv = tid >> 6; int lane = tid & 63;
  int p = pg*16 + px;
  int bsmp = s/3;
  const float* fr = img + (size_t)s*CCH*L2;
  float vals[4]; float sm=0.f, sq=0.f;
  #pragma unroll
  for (int j=0;j<4;++j){
    int c = cg*4 + j;
    float v = fr[c*L2 + p];
    vals[j]=v; sm+=v; sq+=v*v;
  }
  sm += __shfl_xor(sm,16,64); sq += __shfl_xor(sq,16,64);
  sm += __shfl_xor(sm,32,64); sq += __shfl_xor(sq,32,64);
  if (lane < 16){ ps[wv][lane]=sm; pq[wv][lane]=sq; }
  __syncthreads();
  sm = ps[0][px]+ps[1][px]+ps[2][px]+ps[3][px];
  sq = pq[0][px]+pq[1][px]+pq[2][px]+pq[3][px];
  float mean = sm*(1.f/CCH); float var = sq*(1.f/CCH)-mean*mean;
  float rs = rsqrtf(var + 1e-6f);
  float* o = x3c + (size_t)s*C3*L2;
  const float* dzp = dz + (size_t)bsmp*CCH*L2;
  const float* sgp = sg + (size_t)bsmp*CCH*L2;
  float gsm=0.f, gsq=0.f;
  #pragma unroll
  for (int j=0;j<4;++j){
    int c = cg*4+j;
    float dzv = dzp[c*L2+p];
    float nv  = (vals[j]-mean)*rs*g[c] + b[c];
    float sgv = sgp[c*L2+p];
    o[c*L2+p] = dzv;
    o[(CCH+c)*L2+p] = nv;
    o[(2*CCH+c)*L2+p] = sgv;
    gsm += dzv+nv+sgv; gsq += dzv*dzv+nv*nv+sgv*sgv;
  }
  for (int m=1;m<64;m<<=1){ gsm+=__shfl_xor(gsm,m,64); gsq+=__shfl_xor(gsq,m,64); }
  if (lane==0){ gs[wv]=gsm; gq[wv]=gsq; }
  __syncthreads();
  if (tid==0){
    psum1[blockIdx.x] = gs[0]+gs[1]+gs[2]+gs[3];
    psq1 [blockIdx.x] = gq[0]+gq[1]+gq[2]+gq[3];
  }
}

// ---------------- GN act + SiLU from per-block partials, padded write
__global__ __launch_bounds__(256) void k_gnact_pad(const float* __restrict__ x,
    const float* __restrict__ psum, const float* __restrict__ psq,
    const float* __restrict__ g, const float* __restrict__ b,
    int ch, int parts, float inv_n, float eps, float* __restrict__ out){
  int bx = blockIdx.x;
  int s = bx / ch; int c = bx % ch;
  int tid = threadIdx.x;
  float sm=0.f, sq=0.f;
  for (int i=0;i<parts;++i){ sm += psum[s*parts+i]; sq += psq[s*parts+i]; }
  float mean = sm*inv_n;
  float var = sq*inv_n - mean*mean;
  float rs = rsqrtf(var + eps);
  float gc = g[c]*rs; float bc = b[c] - mean*rs*g[c];
  float4 v = *(const float4*)(x + (size_t)bx*1024 + tid*4);
  float4 o; o.x = fsilu(v.x*gc+bc); o.y = fsilu(v.y*gc+bc);
  o.z = fsilu(v.z*gc+bc); o.w = fsilu(v.w*gc+bc);
  float* pl = out + (size_t)bx*PSTR;
  *(float4*)(pl + 32 + tid*4) = o;
  float4 z4 = make_float4(0.f,0.f,0.f,0.f);
  if (tid < 8)  *(float4*)(pl + tid*4) = z4;
  else if (tid < 16) *(float4*)(pl + 1056 + (tid-8)*4) = z4;
}

// conv helpers (2-co)
__device__ __forceinline__ void conv_row_acc(float4& a0, float4& a1, float4 mid, float lf, float rt,
    const float* wp0, const float* wp1){
  float w0=wp0[0], w1=wp0[1], w2=wp0[2];
  a0.x = fmaf(w0,lf,   fmaf(w1,mid.x, fmaf(w2,mid.y, a0.x)));
  a0.y = fmaf(w0,mid.x,fmaf(w1,mid.y, fmaf(w2,mid.z, a0.y)));
  a0.z = fmaf(w0,mid.y,fmaf(w1,mid.z, fmaf(w2,mid.w, a0.z)));
  a0.w = fmaf(w0,mid.z,fmaf(w1,mid.w, fmaf(w2,rt,    a0.w)));
  float v0=wp1[0], v1=wp1[1], v2=wp1[2];
  a1.x = fmaf(v0,lf,   fmaf(v1,mid.x, fmaf(v2,mid.y, a1.x)));
  a1.y = fmaf(v0,mid.x,fmaf(v1,mid.y, fmaf(v2,mid.z, a1.y)));
  a1.z = fmaf(v0,mid.y,fmaf(v1,mid.z, fmaf(v2,mid.w, a1.z)));
  a1.w = fmaf(v0,mid.z,fmaf(v1,mid.w, fmaf(v2,rt,    a1.w)));
}

__device__ __forceinline__ void conv_ci_body(float4 m0, float4 m1, float4 m2, int q,
    const float* wp0, const float* wp1, float4& a0, float4& a1){
  float lf0=__shfl_up(m0.w,1,64), rt0=__shfl_down(m0.x,1,64);
  float lf1=__shfl_up(m1.w,1,64), rt1=__shfl_down(m1.x,1,64);
  float lf2=__shfl_up(m2.w,1,64), rt2=__shfl_down(m2.x,1,64);
  if (q==0){ lf0=0.f; lf1=0.f; lf2=0.f; }
  if (q==7){ rt0=0.f; rt1=0.f; rt2=0.f; }
  conv_row_acc(a0,a1,m0,lf0,rt0, wp0+0, wp1+0);
  conv_row_acc(a0,a1,m1,lf1,rt1, wp0+3, wp1+3);
  conv_row_acc(a0,a1,m2,lf2,rt2, wp0+6, wp1+6);
}

// ---------------- k3: conv1 192ci->64co, split-K=8, padded input
__global__ __launch_bounds__(256) void k_conv1_split(const float* __restrict__ xact,
    const float* __restrict__ w, float* __restrict__ part){
  int bx = blockIdx.x; int kk = bx&7; int cop=(bx>>3)&31; int s=bx>>8;
  int co0 = cop*2, co1 = co0+1;
  int tid = threadIdx.x; int row = tid>>3; int q = tid&7; int col0 = q*4;
  float4 a0 = make_float4(0.f,0.f,0.f,0.f);
  float4 a1 = make_float4(0.f,0.f,0.f,0.f);
  int ci0 = kk*24;
  const float* pl = xact + ((size_t)s*C3 + ci0)*PSTR + row*32 + col0;
  const float* wp0 = w + (size_t)(co0*C3 + ci0)*9;
  const float* wp1 = w + (size_t)(co1*C3 + ci0)*9;
  float4 m0 = *(const float4*)(pl);
  float4 m1 = *(const float4*)(pl+32);
  float4 m2 = *(const float4*)(pl+64);
  #pragma unroll 2
  for (int i=0;i<24;++i){
    const float* pn = pl + (i<23 ? PSTR : 0);
    float4 n0 = *(const float4*)(pn);
    float4 n1 = *(const float4*)(pn+32);
    float4 n2 = *(const float4*)(pn+64);
    conv_ci_body(m0,m1,m2,q, wp0, wp1, a0, a1);
    wp0 += 9; wp1 += 9; pl = pn; m0=n0; m1=n1; m2=n2;
  }
  float* pp = part + (size_t)kk*(BL*CCH*L2) + ((size_t)s*CCH+co0)*L2 + row*32+col0;
  *(float4*)pp = a0;
  *(float4*)(pp+L2) = a1;
}

// ---------------- k4: reduce conv1 partials + bias -> h1; GN2 partials
__global__ __launch_bounds__(256) void k_reduce1(const float* __restrict__ part,
    const float* __restrict__ bias, float* __restrict__ h1,
    float* __restrict__ psum2, float* __restrict__ psq2){
  int co = blockIdx.x & 63; int s = blockIdx.x >> 6;
  size_t ofs = ((size_t)s*CCH+co)*L2 + threadIdx.x*4;
  const size_t stride = (size_t)BL*CCH*L2;
  float4 acc = *(const float4*)(part + ofs);
  #pragma unroll
  for (int kk=1;kk<8;++kk){
    float4 r = *(const float4*)(part + (size_t)kk*stride + ofs);
    acc.x += r.x; acc.y += r.y; acc.z += r.z; acc.w += r.w;
  }
  float bv = bias[co];
  acc.x += bv; acc.y += bv; acc.z += bv; acc.w += bv;
  *(float4*)(h1 + ofs) = acc;
  float sm = acc.x+acc.y+acc.z+acc.w;
  float sq = acc.x*acc.x+acc.y*acc.y+acc.z*acc.z+acc.w*acc.w;
  for (int m=1;m<64;m<<=1){ sm+=__shfl_xor(sm,m,64); sq+=__shfl_xor(sq,m,64); }
  __shared__ float s_sm[4], s_sq[4];
  int wv = threadIdx.x>>6;
  if ((threadIdx.x&63)==0){ s_sm[wv]=sm; s_sq[wv]=sq; }
  __syncthreads();
  if (threadIdx.x==0){
    psum2[blockIdx.x] = s_sm[0]+s_sm[1]+s_sm[2]+s_sm[3];
    psq2 [blockIdx.x] = s_sq[0]+s_sq[1]+s_sq[2]+s_sq[3];
  }
}

// ---------------- k6: conv2 SIX roles: 0-3 conv 16ci each; 4-5 skip 96ci each
__global__ __launch_bounds__(256) void k_conv2_split(const float* __restrict__ xact2,
    const float* __restrict__ x3c, const float* __restrict__ w2,
    const float* __restrict__ wsk, float* __restrict__ part){
  int t = blockIdx.x; int role = t % 6; t /= 6;
  int cop = t & 31; int s = t >> 5;
  int co0 = cop*2, co1 = co0+1;
  int tid = threadIdx.x; int row = tid>>3; int q = tid&7; int col0 = q*4;
  int p = row*32+col0;
  float4 a0 = make_float4(0.f,0.f,0.f,0.f);
  float4 a1 = make_float4(0.f,0.f,0.f,0.f);
  if (role < 4){
    int ci0 = role*16;
    const float* pl = xact2 + ((size_t)s*CCH + ci0)*PSTR + row*32 + col0;
    const float* wp0 = w2 + (size_t)(co0*CCH + ci0)*9;
    const float* wp1 = w2 + (size_t)(co1*CCH + ci0)*9;
    float4 m0 = *(const float4*)(pl);
    float4 m1 = *(const float4*)(pl+32);
    float4 m2 = *(const float4*)(pl+64);
    #pragma unroll 2
    for (int i=0;i<16;++i){
      const float* pn = pl + (i<15 ? PSTR : 0);
      float4 n0 = *(const float4*)(pn);
      float4 n1 = *(const float4*)(pn+32);
      float4 n2 = *(const float4*)(pn+64);
      conv_ci_body(m0,m1,m2,q, wp0, wp1, a0, a1);
      wp0 += 9; wp1 += 9; pl = pn; m0=n0; m1=n1; m2=n2;
    }
  } else {
    int ci0 = (role-4)*96;
    const float* x3 = x3c + ((size_t)s*C3 + ci0)*L2 + p;
    const float* w0p = wsk + co0*C3 + ci0;
    const float* w1p = wsk + co1*C3 + ci0;
    #pragma unroll 4
    for (int ci=0; ci<96; ++ci){
      float4 v = *(const float4*)(x3 + (size_t)ci*L2);
      float ws0 = w0p[ci], ws1 = w1p[ci];
      a0.x = fmaf(ws0,v.x,a0.x); a0.y = fmaf(ws0,v.y,a0.y); a0.z = fmaf(ws0,v.z,a0.z); a0.w = fmaf(ws0,v.w,a0.w);
      a1.x = fmaf(ws1,v.x,a1.x); a1.y = fmaf(ws1,v.y,a1.y); a1.z = fmaf(ws1,v.z,a1.z); a1.w = fmaf(ws1,v.w,a1.w);
    }
  }
  float* pp = part + (size_t)role*(BL*CCH*L2) + ((size_t)s*CCH+co0)*L2 + p;
  *(float4*)pp = a0;
  *(float4*)(pp+L2) = a1;
}

// ---------------- k7: reduce2(6 slots) + ln1 + in_proj fused, oq split x8
__global__ __launch_bounds__(256) void k_red2_ln1_inproj(const float* __restrict__ part,
    const float* __restrict__ b2, const float* __restrict__ bsk,
    const float* __restrict__ g, const float* __restrict__ b,
    const float* __restrict__ W,
    float* __restrict__ x_cmaj, float* __restrict__ xc, float* __restrict__ z_t){
  __shared__ float xn_s[64*65];
  int bx = blockIdx.x; int oq = bx & 7; int pg = (bx>>3)&15; int s = bx>>7;
  int p0 = pg*64;
  int tid = threadIdx.x;
  const size_t stride = (size_t)BL*CCH*L2;
  #pragma unroll
  for (int kq=0;kq<4;++kq){
    int f = kq*256 + tid;
    int co = f >> 4; int px4 = (f & 15)*4;
    size_t ofs = ((size_t)s*CCH+co)*L2 + p0 + px4;
    float4 r0 = *(const float4*)(part + ofs);
    float4 r1 = *(const float4*)(part + stride + ofs);
    float4 r2 = *(const float4*)(part + 2*stride + ofs);
    float4 r3 = *(const float4*)(part + 3*stride + ofs);
    float4 r4 = *(const float4*)(part + 4*stride + ofs);
    float4 r5 = *(const float4*)(part + 5*stride + ofs);
    float bv = b2[co]+bsk[co];
    float4 o;
    o.x = ((r0.x+r1.x)+(r2.x+r3.x))+(r4.x+r5.x)+bv;
    o.y = ((r0.y+r1.y)+(r2.y+r3.y))+(r4.y+r5.y)+bv;
    o.z = ((r0.z+r1.z)+(r2.z+r3.z))+(r4.z+r5.z)+bv;
    o.w = ((r0.w+r1.w)+(r2.w+r3.w))+(r4.w+r5.w)+bv;
    if (oq == 0) *(float4*)(x_cmaj + ofs) = o;
    xn_s[(px4+0)*65 + co] = o.x;
    xn_s[(px4+1)*65 + co] = o.y;
    xn_s[(px4+2)*65 + co] = o.z;
    xn_s[(px4+3)*65 + co] = o.w;
  }
  __syncthreads();
  {
    int wv = __builtin_amdgcn_readfirstlane(tid>>6); int lane = tid&63;
    for (int j=0;j<16;++j){
      int pl = wv*16 + j;
      float v = xn_s[pl*65 + lane];
      float sm = v, sq = v*v;
      for (int m=1;m<64;m<<=1){ sm += __shfl_xor(sm,m,64); sq += __shfl_xor(sq,m,64); }
      float mean = sm*(1.f/64.f); float var = sq*(1.f/64.f) - mean*mean;
      float rs = rsqrtf(var + 1e-5f);
      xn_s[pl*65 + lane] = (v-mean)*rs*g[lane] + b[lane];
    }
  }
  __syncthreads();
  int px_l = tid & 63;
  int og = __builtin_amdgcn_readfirstlane(tid >> 6);
  int o0 = oq*32 + og*8;
  float acc[8];
  #pragma unroll
  for (int oi=0;oi<8;++oi) acc[oi]=0.f;
  for (int c=0;c<64;++c){
    float xv = xn_s[px_l*65 + c];
    #pragma unroll
    for (int oi=0;oi<8;++oi) acc[oi] = fmaf(W[(o0+oi)*64 + c], xv, acc[oi]);
  }
  int p = p0 + px_l;
  if (oq < 4){
    #pragma unroll
    for (int oi=0;oi<8;++oi) xc[((size_t)s*DIC + o0 + oi)*L2 + p] = acc[oi];
  } else {
    #pragma unroll
    for (int oi=0;oi<8;++oi) z_t[((size_t)s*DIC + (o0-128) + oi)*L2 + p] = acc[oi];
  }
}

// ---------------- k8: x_proj + INLINE depthwise 3x3 + SiLU
__global__ __launch_bounds__(256) void k_xproj_dt(const float* __restrict__ xc,
    const float* __restrict__ dww, const float* __restrict__ dwb,
    const float* __restrict__ W,
    float* __restrict__ dtr, float* __restrict__ Bp, float* __restrict__ Cp,
    float* __restrict__ u_t){
  __shared__ float smem[128*68];
  int bx = blockIdx.x; int pg = bx & 15; int sk = bx >> 4;
  int k = sk & 3; int s = sk >> 2;
  int tid = threadIdx.x;
  for (int i = tid; i < 128*16; i += 256){
    int dr = i>>4; int j4 = (i&15)*4;
    int rw = j4>>5; int col0 = j4 & 31;
    int gr = pg*2 + rw;
    int q = i&7;
    const float* xr = xc + ((size_t)s*DIC+dr)*L2;
    const float* wp = dww + dr*9;
    float bv = dwb[dr];
    float4 acc = make_float4(bv,bv,bv,bv);
    #pragma unroll
    for (int dy=-1;dy<=1;++dy){
      int r = gr+dy;
      float4 mid = make_float4(0.f,0.f,0.f,0.f);
      if (0<=r && r<32) mid = *(const float4*)(xr + r*32 + col0);
      float lf = __shfl_up(mid.w,1,64); if(q==0) lf=0.f;
      float rt = __shfl_down(mid.x,1,64); if(q==7) rt=0.f;
      float w0=wp[(dy+1)*3], w1=wp[(dy+1)*3+1], w2=wp[(dy+1)*3+2];
      acc.x = fmaf(w0,lf,   fmaf(w1,mid.x, fmaf(w2,mid.y, acc.x)));
      acc.y = fmaf(w0,mid.x,fmaf(w1,mid.y, fmaf(w2,mid.z, acc.y)));
      acc.z = fmaf(w0,mid.y,fmaf(w1,mid.z, fmaf(w2,mid.w, acc.z)));
      acc.w = fmaf(w0,mid.z,fmaf(w1,mid.w, fmaf(w2,rt,    acc.w)));
    }
    acc.x = fsilu(acc.x); acc.y = fsilu(acc.y); acc.z = fsilu(acc.z); acc.w = fsilu(acc.w);
    *(float4*)&smem[dr*68 + j4] = acc;
  }
  __syncthreads();
  if (k == 0){
    float* ub = u_t + ((size_t)(s*L2) + pg*64)*DIC;
    for (int i = tid; i < 64*128; i += 256){
      int px2 = i>>7; int dd = i&127;
      ub[(size_t)px2*DIC + dd] = smem[dd*68 + px2];
    }
  }
  int px = tid & 63;
  int cgrp = __builtin_amdgcn_readfirstlane(tid >> 6);
  int c0 = cgrp*9;
  const float* wb = W + (size_t)(k*36 + c0)*DIC;
  float acc[9];
  #pragma unroll
  for (int ci=0;ci<9;++ci) acc[ci]=0.f;
  for (int d=0; d<DIC; ++d){
    float xv = smem[d*68 + px];
    #pragma unroll
    for (int ci=0;ci<9;++ci) acc[ci] = fmaf(wb[ci*DIC+d], xv, acc[ci]);
  }
  __syncthreads();
  #pragma unroll
  for (int ci=0;ci<9;++ci) smem[(c0+ci)*68 + px] = acc[ci];
  __syncthreads();
  {
    int pp = tid >> 2; int r = tid & 3;
    dtr[((size_t)sk*L2 + pg*64 + pp)*4 + r] = smem[r*68 + pp];
  }
  float* Bb = Bp + ((size_t)sk*L2 + pg*64)*NST;
  float* Cb = Cp + ((size_t)sk*L2 + pg*64)*NST;
  for (int i = tid; i < 1024; i += 256){
    int pp = i>>4; int n = i&15;
    Bb[pp*NST + n] = smem[(4+n)*68 + pp];
    Cb[pp*NST + n] = smem[(20+n)*68 + pp];
  }
}

// scan pixel for direction k, chunk ch (32 steps), step j
__device__ __forceinline__ int scan_pix32(int ch, int j, int k){
  if (k==0) return ch*32 + j;
  if (k==1) return j*32 + ch;
  if (k==2) return 1023 - (ch*32 + j);
  return 1023 - (j*32 + ch);
}

// half-state step (8 of 16 SSM states per thread)
struct StepH { float4 dt4; float uv; float4 B0,B1; };
__device__ __forceinline__ StepH loadH(const float* dr, const float* ub, const float* Bb, int p){
  StepH r;
  r.dt4 = *(const float4*)(dr + (size_t)p*4);
  r.uv = ub[(size_t)p*DIC];
  const float* bp = Bb + p*NST;   // Bb pre-offset by nh*8
  r.B0 = *(const float4*)bp; r.B1 = *(const float4*)(bp+4);
  return r;
}
__device__ __forceinline__ float dt_eval(float4 w4, float bb, float4 d4){
  return fsoftplus(fmaf(w4.x,d4.x,fmaf(w4.y,d4.y,fmaf(w4.z,d4.z,fmaf(w4.w,d4.w,bb)))));
}

// ---------------- k9: scan pass 1, n-split: thread=(d, n-half), 768 blocks
__global__ __launch_bounds__(256,4) void k_scan_part3(const float* __restrict__ dtr,
    const float* __restrict__ dtw, const float* __restrict__ dtb,
    const float* __restrict__ u_t, const float* __restrict__ Bp,
    const float* __restrict__ A_logs, float* __restrict__ hend, float* __restrict__ Ssum){
  int bx = blockIdx.x; int ch = bx & 31; int sk = bx >> 5;
  int k = sk & 3; int s = sk >> 2;
  int tid = threadIdx.x; int d = tid >> 1; int nh = tid & 1;
  float aco[8];
  {
    const float* ab = A_logs + (size_t)(k*DIC+d)*NST + nh*8;
    #pragma unroll
    for (int n=0;n<8;++n) aco[n] = -LOG2E * fexp(ab[n]);
  }
  float4 w4 = *(const float4*)(dtw + (size_t)(k*DIC+d)*4);
  float bb = dtb[k*DIC+d];
  float h[8]; float Sacc = 0.f;
  #pragma unroll
  for (int n=0;n<8;++n) h[n]=0.f;
  const float* dr = dtr + (size_t)sk*L2*4;
  const float* ub = u_t + (size_t)s*L2*DIC + d;
  const float* Bb = Bp + (size_t)sk*L2*NST + nh*8;
  StepH cur = loadH(dr, ub, Bb, scan_pix32(ch, 0, k));
  #pragma unroll 4
  for (int j=0;j<32;++j){
    StepH nxt;
    if (j < 31) nxt = loadH(dr, ub, Bb, scan_pix32(ch, j+1, k));
    float dtv = dt_eval(w4, bb, cur.dt4);
    Sacc += dtv;
    float tv = dtv*cur.uv;
    #define PSTEP(NI, BV) { float a_ = __builtin_amdgcn_exp2f(dtv*aco[NI]); \
      h[NI] = fmaf(a_, h[NI], tv*(BV)); }
    PSTEP(0,cur.B0.x) PSTEP(1,cur.B0.y) PSTEP(2,cur.B0.z) PSTEP(3,cur.B0.w)
    PSTEP(4,cur.B1.x) PSTEP(5,cur.B1.y) PSTEP(6,cur.B1.z) PSTEP(7,cur.B1.w)
    #undef PSTEP
    cur = nxt;
  }
  size_t base = ((size_t)(sk*NCH + ch)*DIC + d)*NST + nh*8;
  *(float4*)(hend + base)     = make_float4(h[0],h[1],h[2],h[3]);
  *(float4*)(hend + base + 4) = make_float4(h[4],h[5],h[6],h[7]);
  if (nh == 0) Ssum[(size_t)(sk*NCH + ch)*DIC + d] = Sacc;
}

// ---------------- k10: serial chunk prefix (unchanged; hend/Ssum layouts identical)
__global__ __launch_bounds__(256) void k_scan_fix3(const float* __restrict__ hend,
    const float* __restrict__ Ssum, const float* __restrict__ A_logs,
    float* __restrict__ Hin){
  int t = blockIdx.x*256 + threadIdx.x;
  int n = t & 15; int d = (t>>4) & 127; int sk = t >> 11; int k = sk & 3;
  float aco = -LOG2E * fexp(A_logs[(size_t)(k*DIC+d)*NST + n]);
  float H = 0.f;
  #pragma unroll 8
  for (int ch=0; ch<NCH; ++ch){
    size_t sidx = (size_t)(sk*NCH + ch)*DIC + d;
    float pa = __builtin_amdgcn_exp2f(aco * Ssum[sidx]);
    float he = hend[sidx*NST + n];
    Hin[sidx*NST + n] = H;
    H = fmaf(pa, H, he);
  }
}

// ---------------- k11: full scan + y output, n-split, 768 blocks
__global__ __launch_bounds__(256,4) void k_scan_y3(const float* __restrict__ dtr,
    const float* __restrict__ dtw, const float* __restrict__ dtb,
    const float* __restrict__ u_t, const float* __restrict__ Bp, const float* __restrict__ Cp,
    const float* __restrict__ A_logs, const float* __restrict__ Ds,
    const float* __restrict__ Hin, float* __restrict__ ys_t){
  int bx = blockIdx.x; int ch = bx & 31; int sk = bx >> 5;
  int k = sk & 3; int s = sk >> 2;
  int tid = threadIdx.x; int d = tid >> 1; int nh = tid & 1;
  float aco[8];
  {
    const float* ab = A_logs + (size_t)(k*DIC+d)*NST + nh*8;
    #pragma unroll
    for (int n=0;n<8;++n) aco[n] = -LOG2E * fexp(ab[n]);
  }
  float4 w4 = *(const float4*)(dtw + (size_t)(k*DIC+d)*4);
  float bb = dtb[k*DIC+d];
  float Dv = Ds[k*DIC+d];
  float h[8];
  size_t hbase = ((size_t)(sk*NCH + ch)*DIC + d)*NST + nh*8;
  {
    float4 h0 = *(const float4*)(Hin + hbase);
    float4 h1 = *(const float4*)(Hin + hbase + 4);
    h[0]=h0.x; h[1]=h0.y; h[2]=h0.z; h[3]=h0.w;
    h[4]=h1.x; h[5]=h1.y; h[6]=h1.z; h[7]=h1.w;
  }
  const float* dr = dtr + (size_t)sk*L2*4;
  const float* ub = u_t + (size_t)s*L2*DIC + d;
  const float* Bb = Bp + (size_t)sk*L2*NST + nh*8;
  const float* Cb = Cp + (size_t)sk*L2*NST + nh*8;
  float* yb = ys_t + (size_t)sk*L2*DIC + d;
  int pcur = scan_pix32(ch, 0, k);
  StepH cur = loadH(dr, ub, Bb, pcur);
  float4 Cc0 = *(const float4*)(Cb + pcur*NST);
  float4 Cc1 = *(const float4*)(Cb + pcur*NST + 4);
  #pragma unroll 4
  for (int j=0;j<32;++j){
    StepH nxt; float4 Cn0, Cn1; int pn = pcur;
    if (j < 31){
      pn = scan_pix32(ch, j+1, k);
      nxt = loadH(dr, ub, Bb, pn);
      Cn0 = *(const float4*)(Cb + pn*NST);
      Cn1 = *(const float4*)(Cb + pn*NST + 4);
    }
    float dtv = dt_eval(w4, bb, cur.dt4);
    float tv = dtv*cur.uv;
    float y0=0.f, y1=0.f, y2=0.f, y3=0.f;
    #define YSTEP(NI, BV, CV, YA) { float a_ = __builtin_amdgcn_exp2f(dtv*aco[NI]); \
      h[NI] = fmaf(a_, h[NI], tv*(BV)); YA = fmaf(h[NI], (CV), YA); }
    YSTEP(0,cur.B0.x,Cc0.x,y0) YSTEP(1,cur.B0.y,Cc0.y,y1) YSTEP(2,cur.B0.z,Cc0.z,y2) YSTEP(3,cur.B0.w,Cc0.w,y3)
    YSTEP(4,cur.B1.x,Cc1.x,y0) YSTEP(5,cur.B1.y,Cc1.y,y1) YSTEP(6,cur.B1.z,Cc1.z,y2) YSTEP(7,cur.B1.w,Cc1.w,y3)
    #undef YSTEP
    float py = (y0+y1)+(y2+y3);
    float tot = py + __shfl_xor(py, 1, 64);
    if (nh == 0) yb[(size_t)pcur*DIC] = fmaf(cur.uv, Dv, tot);
    cur = nxt; Cc0 = Cn0; Cc1 = Cn1; pcur = pn;
  }
}

// ---------------- k12: fused tail
__global__ __launch_bounds__(256) void k_tail(const float* __restrict__ ys_t,
    const float* __restrict__ z_t, const float* __restrict__ ong, const float* __restrict__ onb,
    const float* __restrict__ Wop, const float* __restrict__ x_cmaj,
    const float* __restrict__ g2, const float* __restrict__ b2n,
    const float* __restrict__ w1, const float* __restrict__ b1,
    const float* __restrict__ w2, const float* __restrict__ b2,
    float* __restrict__ out){
  __shared__ float yt[128*17];
  __shared__ float xvt[64*17];
  __shared__ float ts[64*17];
  int s = blockIdx.x >> 6; int pg = blockIdx.x & 63;
  int tid = threadIdx.x;
  {
    int wv = __builtin_amdgcn_readfirstlane(tid>>6); int lane = tid&63;
    int d0 = lane, d1 = lane+64;
    for (int i=0;i<4;++i){
      int px = i*4 + wv; int p = pg*16 + px;
      const float* yb = ys_t + ((size_t)(s*4)*L2 + p)*DIC;
      float ya = yb[d0] + yb[(size_t)L2*DIC + d0] + yb[(size_t)2*L2*DIC + d0] + yb[(size_t)3*L2*DIC + d0];
      float yc = yb[d1] + yb[(size_t)L2*DIC + d1] + yb[(size_t)2*L2*DIC + d1] + yb[(size_t)3*L2*DIC + d1];
      float sm = ya+yc, sq = ya*ya+yc*yc;
      for (int m=1;m<64;m<<=1){ sm+=__shfl_xor(sm,m,64); sq+=__shfl_xor(sq,m,64); }
      float mean = sm*(1.f/128.f); float var = sq*(1.f/128.f)-mean*mean;
      float rs = rsqrtf(var + 1e-5f);
      float yn0 = (ya-mean)*rs*ong[d0] + onb[d0];
      float yn1 = (yc-mean)*rs*ong[d1] + onb[d1];
      float zv0 = z_t[((size_t)s*DIC+d0)*L2 + p];
      float zv1 = z_t[((size_t)s*DIC+d1)*L2 + p];
      yt[d0*17 + px] = yn0 * fsilu(zv0);
      yt[d1*17 + px] = yn1 * fsilu(zv1);
    }
  }
  __syncthreads();
  {
    int px = tid & 15; int cgp = tid >> 4;
    int c0 = cgp*4;
    float a0=0.f,a1=0.f,a2=0.f,a3=0.f;
    for (int d=0; d<DIC; ++d){
      float yv = yt[d*17 + px];
      a0 = fmaf(Wop[(c0+0)*DIC + d], yv, a0);
      a1 = fmaf(Wop[(c0+1)*DIC + d], yv, a1);
      a2 = fmaf(Wop[(c0+2)*DIC + d], yv, a2);
      a3 = fmaf(Wop[(c0+3)*DIC + d], yv, a3);
    }
    int p = pg*16 + px;
    size_t base = ((size_t)s*CCH + c0)*L2 + p;
    xvt[(c0+0)*17 + px] = x_cmaj[base]      + a0;
    xvt[(c0+1)*17 + px] = x_cmaj[base+L2]   + a1;
    xvt[(c0+2)*17 + px] = x_cmaj[base+2*L2] + a2;
    xvt[(c0+3)*17 + px] = x_cmaj[base+3*L2] + a3;
  }
  __syncthreads();
  int px = tid & 15; int cgp = tid >> 4;
  float sm=0.f, sq=0.f;
  for (int c=0;c<64;++c){ float v = xvt[c*17+px]; sm+=v; sq+=v*v; }
  float mean = sm*(1.f/64.f);
  float rs = rsqrtf(sq*(1.f/64.f) - mean*mean + 1e-5f);
  int o0 = cgp*4;
  float t[4];
  #pragma unroll
  for (int oi=0;oi<4;++oi) t[oi] = b1[o0+oi];
  for (int c=0;c<64;++c){
    float xn = (xvt[c*17+px]-mean)*rs*g2[c] + b2n[c];
    #pragma unroll
    for (int oi=0;oi<4;++oi) t[oi] = fmaf(xn, w1[(o0+oi)*64 + c], t[oi]);
  }
  #pragma unroll
  for (int oi=0;oi<4;++oi) ts[(o0+oi)*17 + px] = fgelu(t[oi]);
  __syncthreads();
  int c0 = cgp*4;
  float acc[4];
  #pragma unroll
  for (int ci=0;ci<4;++ci) acc[ci] = xvt[(c0+ci)*17+px] + b2[c0+ci];
  for (int o=0;o<64;++o){
    float tv = ts[o*17+px];
    #pragma unroll
    for (int ci=0;ci<4;++ci) acc[ci] = fmaf(tv, w2[(c0+ci)*64 + o], acc[ci]);
  }
  int p = pg*16 + px;
  #pragma unroll
  for (int ci=0;ci<4;++ci) out[((size_t)s*CCH + c0+ci)*L2 + p] = acc[ci];
}

extern "C" void kernel_launch(void* const* d_in, const int* in_sizes, int n_in,
                              void* d_out, int out_size, void* d_ws, size_t ws_size,
                              hipStream_t stream){
  (void)in_sizes; (void)n_in; (void)out_size; (void)ws_size;
  const float* img      = (const float*)d_in[0];
  const float* dz       = (const float*)d_in[1];
  const float* sg       = (const float*)d_in[2];
  const float* norm_g   = (const float*)d_in[3];
  const float* norm_b   = (const float*)d_in[4];
  const float* gn1_g    = (const float*)d_in[5];
  const float* gn1_b    = (const float*)d_in[6];
  const float* conv1_w  = (const float*)d_in[7];
  const float* conv1_b  = (const float*)d_in[8];
  const float* gn2_g    = (const float*)d_in[9];
  const float* gn2_b    = (const float*)d_in[10];
  const float* conv2_w  = (const float*)d_in[11];
  const float* conv2_b  = (const float*)d_in[12];
  const float* skip_w   = (const float*)d_in[13];
  const float* skip_b   = (const float*)d_in[14];
  const float* ln1_g    = (const float*)d_in[15];
  const float* ln1_b    = (const float*)d_in[16];
  const float* ln2_g    = (const float*)d_in[17];
  const float* ln2_b    = (const float*)d_in[18];
  const float* in_proj_w= (const float*)d_in[19];
  const float* dwconv_w = (const float*)d_in[20];
  const float* dwconv_b = (const float*)d_in[21];
  const float* x_proj_w = (const float*)d_in[22];
  const float* dt_proj_w= (const float*)d_in[23];
  const float* dt_proj_b= (const float*)d_in[24];
  const float* A_logs   = (const float*)d_in[25];
  const float* Ds       = (const float*)d_in[26];
  const float* out_norm_g = (const float*)d_in[27];
  const float* out_norm_b = (const float*)d_in[28];
  const float* out_proj_w = (const float*)d_in[29];
  const float* fc1_w    = (const float*)d_in[30];
  const float* fc1_b    = (const float*)d_in[31];
  const float* fc2_w    = (const float*)d_in[32];
  const float* fc2_b    = (const float*)d_in[33];

  float* ws = (float*)d_ws;
  float* x3c    = ws;                       // 1,179,648
  float* xact1  = x3c    + 1179648;         // 1,253,376 (padded GN1 act)
  float* h1     = xact1  + 1253376;         // 393,216
  float* xact2  = h1     + 393216;          // 417,792 (padded GN2 act)
  float* xpslot = xact2  + 417792;          // 393,216 (hosts Bp)
  float* x_cmaj = xpslot + 393216;          // 393,216
  float* z_t    = x_cmaj + 393216;          // 786,432
  float* xc     = z_t    + 786432;          // 786,432
  float* cpslot = xc     + 786432;          // 786,432 (hosts Cp)
  float* hole   = cpslot + 786432;          // 884,736 (dtr + Ssum)
  float* scanbuf= hole   + 884736;          // 3,145,728 (conv1 partials, then Hin)
  float* ys_t   = scanbuf+ 3145728;         // 3,145,728 (conv2 partials first: 6 slots = 2,359,296)
  float* statsb = ys_t   + 3145728;         // psum1(384) psq1(384) psum2(384) psq2(384)
  float* psum1  = statsb;
  float* psq1   = statsb + 384;
  float* psum2  = statsb + 768;
  float* psq2   = statsb + 1152;
  // aliases into dead regions
  float* part1  = scanbuf;          // conv1 partials — consumed before Hin written
  float* part2  = ys_t;             // conv2 partials (6 slots) — consumed before ys_t written
  float* hend   = x3c;              // x3c+xact1 dead after conv2/conv1
  float* u_t    = h1;               // h1+xact2 dead after gnact2/conv2
  float* Bp     = xpslot;
  float* Cp     = cpslot;
  float* dtr    = hole;             // 98,304
  float* Ssum   = hole + 98304;     // 98,304
  float* Hin    = scanbuf;          // part1 dead after reduce1

  k_ln2d<<<384, 256, 0, stream>>>(img, dz, sg, norm_g, norm_b, x3c, psum1, psq1);
  k_gnact_pad<<<6*C3, 256, 0, stream>>>(x3c, psum1, psq1, gn1_g, gn1_b, C3, 64,
                                        1.f/(C3*L2), 1e-5f, xact1);
  k_conv1_split<<<1536, 256, 0, stream>>>(xact1, conv1_w, part1);
  k_reduce1<<<384, 256, 0, stream>>>(part1, conv1_b, h1, psum2, psq2);
  k_gnact_pad<<<6*CCH, 256, 0, stream>>>(h1, psum2, psq2, gn2_g, gn2_b, CCH, 64,
                                         1.f/(CCH*L2), 1e-5f, xact2);
  k_conv2_split<<<1152, 256, 0, stream>>>(xact2, x3c, conv2_w, skip_w, part2);
  k_red2_ln1_inproj<<<768, 256, 0, stream>>>(part2, conv2_b, skip_b, ln1_g, ln1_b, in_proj_w,
                                             x_cmaj, xc, z_t);
  k_xproj_dt<<<384, 256, 0, stream>>>(xc, dwconv_w, dwconv_b, x_proj_w, dtr, Bp, Cp, u_t);
  k_scan_part3<<<768, 256, 0, stream>>>(dtr, dt_proj_w, dt_proj_b, u_t, Bp, A_logs, hend, Ssum);
  k_scan_fix3<<<192, 256, 0, stream>>>(hend, Ssum, A_logs, Hin);
  k_scan_y3<<<768, 256, 0, stream>>>(dtr, dt_proj_w, dt_proj_b, u_t, Bp, Cp, A_logs, Ds, Hin, ys_t);
  k_tail<<<384, 256, 0, stream>>>(ys_t, z_t, out_norm_g, out_norm_b, out_proj_w, x_cmaj,
                                  ln2_g, ln2_b, fc1_w, fc1_b, fc2_w, fc2_b, (float*)d_out);
}

// Round 7
// 286.709 us; speedup vs baseline: 2.8575x; 1.0157x over previous
//
#include <hip/hip_runtime.h>
#include <math.h>

// Problem dims
#define BL    6
#define CCH   64
#define C3    192
#define L2    1024
#define DIC   128
#define NST   16
#define K4    4
#define PSTR  1088   // padded plane stride: 34 rows * 32 cols
#define NCH   32     // scan chunks per sequence (32 steps each)

#define LOG2E 1.44269504088896340736f
#define LN2C  0.69314718055994530942f

__device__ __forceinline__ float fexp(float x){ return __builtin_amdgcn_exp2f(x*LOG2E); }
__device__ __forceinline__ float fsilu(float x){ return x * __builtin_amdgcn_rcpf(1.f + fexp(-x)); }
__device__ __forceinline__ float fsoftplus(float x){
  if (x > 20.f) return x;
  return __builtin_amdgcn_logf(1.f + fexp(x)) * LN2C;
}
__device__ __forceinline__ float fgelu(float x){
  return 0.5f*x*(1.f + erff(x*0.70710678118654752440f));
}

// ---------------- k1: per-pixel LN + concat; GN1 partials. 768 blocks (8 px each).
__global__ __launch_bounds__(256) void k_ln2d(const float* __restrict__ img,
    const float* __restrict__ dz, const float* __restrict__ sg,
    const float* __restrict__ g, const float* __restrict__ b, float* __restrict__ x3c,
    float* __restrict__ psum1, float* __restrict__ psq1){
  __shared__ float ps[4][8], pq[4][8], gs[4], gq[4];
  int s = blockIdx.x >> 7;
  int pg = blockIdx.x & 127;
  int tid = threadIdx.x;
  int px = tid & 7; int cg = tid >> 3;      // 32 groups x 2 channels
  int wv = tid >> 6; int lane = tid & 63;
  int p = pg*8 + px;
  int bsmp = s/3;
  const float* fr = img + (size_t)s*CCH*L2;
  float vals[2]; float sm=0.f, sq=0.f;
  #pragma unroll
  for (int j=0;j<2;++j){
    int c = cg*2 + j;
    float v = fr[c*L2 + p];
    vals[j]=v; sm+=v; sq+=v*v;
  }
  // lanes sharing px within a wave: xor 8,16,32 (8 lanes -> 16 channels per wave)
  sm += __shfl_xor(sm,8,64);  sq += __shfl_xor(sq,8,64);
  sm += __shfl_xor(sm,16,64); sq += __shfl_xor(sq,16,64);
  sm += __shfl_xor(sm,32,64); sq += __shfl_xor(sq,32,64);
  if (lane < 8){ ps[wv][lane]=sm; pq[wv][lane]=sq; }
  __syncthreads();
  sm = ps[0][px]+ps[1][px]+ps[2][px]+ps[3][px];
  sq = pq[0][px]+pq[1][px]+pq[2][px]+pq[3][px];
  float mean = sm*(1.f/CCH); float var = sq*(1.f/CCH)-mean*mean;
  float rs = rsqrtf(var + 1e-6f);
  float* o = x3c + (size_t)s*C3*L2;
  const float* dzp = dz + (size_t)bsmp*CCH*L2;
  const float* sgp = sg + (size_t)bsmp*CCH*L2;
  float gsm=0.f, gsq=0.f;
  #pragma unroll
  for (int j=0;j<2;++j){
    int c = cg*2+j;
    float dzv = dzp[c*L2+p];
    float nv  = (vals[j]-mean)*rs*g[c] + b[c];
    float sgv = sgp[c*L2+p];
    o[c*L2+p] = dzv;
    o[(CCH+c)*L2+p] = nv;
    o[(2*CCH+c)*L2+p] = sgv;
    gsm += dzv+nv+sgv; gsq += dzv*dzv+nv*nv+sgv*sgv;
  }
  for (int m=1;m<64;m<<=1){ gsm+=__shfl_xor(gsm,m,64); gsq+=__shfl_xor(gsq,m,64); }
  if (lane==0){ gs[wv]=gsm; gq[wv]=gsq; }
  __syncthreads();
  if (tid==0){
    psum1[blockIdx.x] = gs[0]+gs[1]+gs[2]+gs[3];
    psq1 [blockIdx.x] = gq[0]+gq[1]+gq[2]+gq[3];
  }
}

// ---------------- k2: MERGED gnact1 (blocks 0..1151) + skip 1x1 (blocks 1152..1535)
__global__ __launch_bounds__(256) void k_gnact1_skip(const float* __restrict__ x3c,
    const float* __restrict__ psum, const float* __restrict__ psq,
    const float* __restrict__ g, const float* __restrict__ b,
    const float* __restrict__ wsk,
    float* __restrict__ xact1, float* __restrict__ part){
  int bx = blockIdx.x;
  int tid = threadIdx.x;
  if (bx < 1152){
    // ---- gnact1 body (parts = 128)
    int s = bx / C3; int c = bx % C3;
    float sm=0.f, sq=0.f;
    for (int i=0;i<128;++i){ sm += psum[s*128+i]; sq += psq[s*128+i]; }
    float mean = sm*(1.f/(C3*L2));
    float var = sq*(1.f/(C3*L2)) - mean*mean;
    float rs = rsqrtf(var + 1e-5f);
    float gc = g[c]*rs; float bc = b[c] - mean*rs*g[c];
    float4 v = *(const float4*)(x3c + (size_t)bx*1024 + tid*4);
    float4 o; o.x = fsilu(v.x*gc+bc); o.y = fsilu(v.y*gc+bc);
    o.z = fsilu(v.z*gc+bc); o.w = fsilu(v.w*gc+bc);
    float* pl = xact1 + (size_t)bx*PSTR;
    *(float4*)(pl + 32 + tid*4) = o;
    float4 z4 = make_float4(0.f,0.f,0.f,0.f);
    if (tid < 8)  *(float4*)(pl + tid*4) = z4;
    else if (tid < 16) *(float4*)(pl + 1056 + (tid-8)*4) = z4;
  } else {
    // ---- skip 1x1 body (2 roles x 96 ci), writes part2 slots 4/5
    int t = bx - 1152;
    int role = t & 1; int cop = (t>>1)&31; int s = t >> 6;
    int co0 = cop*2, co1 = co0+1;
    int row = tid>>3; int q = tid&7; int col0 = q*4;
    int p = row*32+col0;
    float4 a0 = make_float4(0.f,0.f,0.f,0.f);
    float4 a1 = make_float4(0.f,0.f,0.f,0.f);
    int ci0 = role*96;
    const float* x3 = x3c + ((size_t)s*C3 + ci0)*L2 + p;
    const float* w0p = wsk + co0*C3 + ci0;
    const float* w1p = wsk + co1*C3 + ci0;
    #pragma unroll 4
    for (int ci=0; ci<96; ++ci){
      float4 v = *(const float4*)(x3 + (size_t)ci*L2);
      float ws0 = w0p[ci], ws1 = w1p[ci];
      a0.x = fmaf(ws0,v.x,a0.x); a0.y = fmaf(ws0,v.y,a0.y); a0.z = fmaf(ws0,v.z,a0.z); a0.w = fmaf(ws0,v.w,a0.w);
      a1.x = fmaf(ws1,v.x,a1.x); a1.y = fmaf(ws1,v.y,a1.y); a1.z = fmaf(ws1,v.z,a1.z); a1.w = fmaf(ws1,v.w,a1.w);
    }
    float* pp = part + (size_t)(4+role)*(BL*CCH*L2) + ((size_t)s*CCH+co0)*L2 + p;
    *(float4*)pp = a0;
    *(float4*)(pp+L2) = a1;
  }
}

// ---------------- gnact2 (generic)
__global__ __launch_bounds__(256) void k_gnact_pad(const float* __restrict__ x,
    const float* __restrict__ psum, const float* __restrict__ psq,
    const float* __restrict__ g, const float* __restrict__ b,
    int ch, int parts, float inv_n, float eps, float* __restrict__ out){
  int bx = blockIdx.x;
  int s = bx / ch; int c = bx % ch;
  int tid = threadIdx.x;
  float sm=0.f, sq=0.f;
  for (int i=0;i<parts;++i){ sm += psum[s*parts+i]; sq += psq[s*parts+i]; }
  float mean = sm*inv_n;
  float var = sq*inv_n - mean*mean;
  float rs = rsqrtf(var + eps);
  float gc = g[c]*rs; float bc = b[c] - mean*rs*g[c];
  float4 v = *(const float4*)(x + (size_t)bx*1024 + tid*4);
  float4 o; o.x = fsilu(v.x*gc+bc); o.y = fsilu(v.y*gc+bc);
  o.z = fsilu(v.z*gc+bc); o.w = fsilu(v.w*gc+bc);
  float* pl = out + (size_t)bx*PSTR;
  *(float4*)(pl + 32 + tid*4) = o;
  float4 z4 = make_float4(0.f,0.f,0.f,0.f);
  if (tid < 8)  *(float4*)(pl + tid*4) = z4;
  else if (tid < 16) *(float4*)(pl + 1056 + (tid-8)*4) = z4;
}

// conv helpers (2-co)
__device__ __forceinline__ void conv_row_acc(float4& a0, float4& a1, float4 mid, float lf, float rt,
    const float* wp0, const float* wp1){
  float w0=wp0[0], w1=wp0[1], w2=wp0[2];
  a0.x = fmaf(w0,lf,   fmaf(w1,mid.x, fmaf(w2,mid.y, a0.x)));
  a0.y = fmaf(w0,mid.x,fmaf(w1,mid.y, fmaf(w2,mid.z, a0.y)));
  a0.z = fmaf(w0,mid.y,fmaf(w1,mid.z, fmaf(w2,mid.w, a0.z)));
  a0.w = fmaf(w0,mid.z,fmaf(w1,mid.w, fmaf(w2,rt,    a0.w)));
  float v0=wp1[0], v1=wp1[1], v2=wp1[2];
  a1.x = fmaf(v0,lf,   fmaf(v1,mid.x, fmaf(v2,mid.y, a1.x)));
  a1.y = fmaf(v0,mid.x,fmaf(v1,mid.y, fmaf(v2,mid.z, a1.y)));
  a1.z = fmaf(v0,mid.y,fmaf(v1,mid.z, fmaf(v2,mid.w, a1.z)));
  a1.w = fmaf(v0,mid.z,fmaf(v1,mid.w, fmaf(v2,rt,    a1.w)));
}

__device__ __forceinline__ void conv_ci_body(float4 m0, float4 m1, float4 m2, int q,
    const float* wp0, const float* wp1, float4& a0, float4& a1){
  float lf0=__shfl_up(m0.w,1,64), rt0=__shfl_down(m0.x,1,64);
  float lf1=__shfl_up(m1.w,1,64), rt1=__shfl_down(m1.x,1,64);
  float lf2=__shfl_up(m2.w,1,64), rt2=__shfl_down(m2.x,1,64);
  if (q==0){ lf0=0.f; lf1=0.f; lf2=0.f; }
  if (q==7){ rt0=0.f; rt1=0.f; rt2=0.f; }
  conv_row_acc(a0,a1,m0,lf0,rt0, wp0+0, wp1+0);
  conv_row_acc(a0,a1,m1,lf1,rt1, wp0+3, wp1+3);
  conv_row_acc(a0,a1,m2,lf2,rt2, wp0+6, wp1+6);
}

// ---------------- k3: conv1 192ci->64co, split-K=12 (16 ci each), 2304 blocks
__global__ __launch_bounds__(256) void k_conv1_split(const float* __restrict__ xact,
    const float* __restrict__ w, float* __restrict__ part){
  int bx = blockIdx.x; int kk = bx % 12; int r = bx / 12;
  int cop = r & 31; int s = r >> 5;
  int co0 = cop*2, co1 = co0+1;
  int tid = threadIdx.x; int row = tid>>3; int q = tid&7; int col0 = q*4;
  float4 a0 = make_float4(0.f,0.f,0.f,0.f);
  float4 a1 = make_float4(0.f,0.f,0.f,0.f);
  int ci0 = kk*16;
  const float* pl = xact + ((size_t)s*C3 + ci0)*PSTR + row*32 + col0;
  const float* wp0 = w + (size_t)(co0*C3 + ci0)*9;
  const float* wp1 = w + (size_t)(co1*C3 + ci0)*9;
  float4 m0 = *(const float4*)(pl);
  float4 m1 = *(const float4*)(pl+32);
  float4 m2 = *(const float4*)(pl+64);
  #pragma unroll 2
  for (int i=0;i<16;++i){
    const float* pn = pl + (i<15 ? PSTR : 0);
    float4 n0 = *(const float4*)(pn);
    float4 n1 = *(const float4*)(pn+32);
    float4 n2 = *(const float4*)(pn+64);
    conv_ci_body(m0,m1,m2,q, wp0, wp1, a0, a1);
    wp0 += 9; wp1 += 9; pl = pn; m0=n0; m1=n1; m2=n2;
  }
  float* pp = part + (size_t)kk*(BL*CCH*L2) + ((size_t)s*CCH+co0)*L2 + row*32+col0;
  *(float4*)pp = a0;
  *(float4*)(pp+L2) = a1;
}

// ---------------- k4: reduce conv1 partials (12) + bias -> h1; GN2 partials
__global__ __launch_bounds__(256) void k_reduce1(const float* __restrict__ part,
    const float* __restrict__ bias, float* __restrict__ h1,
    float* __restrict__ psum2, float* __restrict__ psq2){
  int co = blockIdx.x & 63; int s = blockIdx.x >> 6;
  size_t ofs = ((size_t)s*CCH+co)*L2 + threadIdx.x*4;
  const size_t stride = (size_t)BL*CCH*L2;
  float4 acc = *(const float4*)(part + ofs);
  #pragma unroll
  for (int kk=1;kk<12;++kk){
    float4 r = *(const float4*)(part + (size_t)kk*stride + ofs);
    acc.x += r.x; acc.y += r.y; acc.z += r.z; acc.w += r.w;
  }
  float bv = bias[co];
  acc.x += bv; acc.y += bv; acc.z += bv; acc.w += bv;
  *(float4*)(h1 + ofs) = acc;
  float sm = acc.x+acc.y+acc.z+acc.w;
  float sq = acc.x*acc.x+acc.y*acc.y+acc.z*acc.z+acc.w*acc.w;
  for (int m=1;m<64;m<<=1){ sm+=__shfl_xor(sm,m,64); sq+=__shfl_xor(sq,m,64); }
  __shared__ float s_sm[4], s_sq[4];
  int wv = threadIdx.x>>6;
  if ((threadIdx.x&63)==0){ s_sm[wv]=sm; s_sq[wv]=sq; }
  __syncthreads();
  if (threadIdx.x==0){
    psum2[blockIdx.x] = s_sm[0]+s_sm[1]+s_sm[2]+s_sm[3];
    psq2 [blockIdx.x] = s_sq[0]+s_sq[1]+s_sq[2]+s_sq[3];
  }
}

// ---------------- k6: conv2 FOUR roles x 16ci, 768 blocks (skip moved to k2)
__global__ __launch_bounds__(256) void k_conv2_split(const float* __restrict__ xact2,
    const float* __restrict__ w2, float* __restrict__ part){
  int bx = blockIdx.x; int role = bx & 3; int t = bx >> 2;
  int cop = t & 31; int s = t >> 5;
  int co0 = cop*2, co1 = co0+1;
  int tid = threadIdx.x; int row = tid>>3; int q = tid&7; int col0 = q*4;
  int p = row*32+col0;
  float4 a0 = make_float4(0.f,0.f,0.f,0.f);
  float4 a1 = make_float4(0.f,0.f,0.f,0.f);
  int ci0 = role*16;
  const float* pl = xact2 + ((size_t)s*CCH + ci0)*PSTR + row*32 + col0;
  const float* wp0 = w2 + (size_t)(co0*CCH + ci0)*9;
  const float* wp1 = w2 + (size_t)(co1*CCH + ci0)*9;
  float4 m0 = *(const float4*)(pl);
  float4 m1 = *(const float4*)(pl+32);
  float4 m2 = *(const float4*)(pl+64);
  #pragma unroll 2
  for (int i=0;i<16;++i){
    const float* pn = pl + (i<15 ? PSTR : 0);
    float4 n0 = *(const float4*)(pn);
    float4 n1 = *(const float4*)(pn+32);
    float4 n2 = *(const float4*)(pn+64);
    conv_ci_body(m0,m1,m2,q, wp0, wp1, a0, a1);
    wp0 += 9; wp1 += 9; pl = pn; m0=n0; m1=n1; m2=n2;
  }
  float* pp = part + (size_t)role*(BL*CCH*L2) + ((size_t)s*CCH+co0)*L2 + p;
  *(float4*)pp = a0;
  *(float4*)(pp+L2) = a1;
}

// ---------------- k7: reduce2(6 slots) + ln1 + in_proj fused, oq split x8
__global__ __launch_bounds__(256) void k_red2_ln1_inproj(const float* __restrict__ part,
    const float* __restrict__ b2, const float* __restrict__ bsk,
    const float* __restrict__ g, const float* __restrict__ b,
    const float* __restrict__ W,
    float* __restrict__ x_cmaj, float* __restrict__ xc, float* __restrict__ z_t){
  __shared__ float xn_s[64*65];
  int bx = blockIdx.x; int oq = bx & 7; int pg = (bx>>3)&15; int s = bx>>7;
  int p0 = pg*64;
  int tid = threadIdx.x;
  const size_t stride = (size_t)BL*CCH*L2;
  #pragma unroll
  for (int kq=0;kq<4;++kq){
    int f = kq*256 + tid;
    int co = f >> 4; int px4 = (f & 15)*4;
    size_t ofs = ((size_t)s*CCH+co)*L2 + p0 + px4;
    float4 r0 = *(const float4*)(part + ofs);
    float4 r1 = *(const float4*)(part + stride + ofs);
    float4 r2 = *(const float4*)(part + 2*stride + ofs);
    float4 r3 = *(const float4*)(part + 3*stride + ofs);
    float4 r4 = *(const float4*)(part + 4*stride + ofs);
    float4 r5 = *(const float4*)(part + 5*stride + ofs);
    float bv = b2[co]+bsk[co];
    float4 o;
    o.x = ((r0.x+r1.x)+(r2.x+r3.x))+(r4.x+r5.x)+bv;
    o.y = ((r0.y+r1.y)+(r2.y+r3.y))+(r4.y+r5.y)+bv;
    o.z = ((r0.z+r1.z)+(r2.z+r3.z))+(r4.z+r5.z)+bv;
    o.w = ((r0.w+r1.w)+(r2.w+r3.w))+(r4.w+r5.w)+bv;
    if (oq == 0) *(float4*)(x_cmaj + ofs) = o;
    xn_s[(px4+0)*65 + co] = o.x;
    xn_s[(px4+1)*65 + co] = o.y;
    xn_s[(px4+2)*65 + co] = o.z;
    xn_s[(px4+3)*65 + co] = o.w;
  }
  __syncthreads();
  {
    int wv = __builtin_amdgcn_readfirstlane(tid>>6); int lane = tid&63;
    for (int j=0;j<16;++j){
      int pl = wv*16 + j;
      float v = xn_s[pl*65 + lane];
      float sm = v, sq = v*v;
      for (int m=1;m<64;m<<=1){ sm += __shfl_xor(sm,m,64); sq += __shfl_xor(sq,m,64); }
      float mean = sm*(1.f/64.f); float var = sq*(1.f/64.f) - mean*mean;
      float rs = rsqrtf(var + 1e-5f);
      xn_s[pl*65 + lane] = (v-mean)*rs*g[lane] + b[lane];
    }
  }
  __syncthreads();
  int px_l = tid & 63;
  int og = __builtin_amdgcn_readfirstlane(tid >> 6);
  int o0 = oq*32 + og*8;
  float acc[8];
  #pragma unroll
  for (int oi=0;oi<8;++oi) acc[oi]=0.f;
  for (int c=0;c<64;++c){
    float xv = xn_s[px_l*65 + c];
    #pragma unroll
    for (int oi=0;oi<8;++oi) acc[oi] = fmaf(W[(o0+oi)*64 + c], xv, acc[oi]);
  }
  int p = p0 + px_l;
  if (oq < 4){
    #pragma unroll
    for (int oi=0;oi<8;++oi) xc[((size_t)s*DIC + o0 + oi)*L2 + p] = acc[oi];
  } else {
    #pragma unroll
    for (int oi=0;oi<8;++oi) z_t[((size_t)s*DIC + (o0-128) + oi)*L2 + p] = acc[oi];
  }
}

// ---------------- k8: x_proj + INLINE depthwise 3x3 + SiLU
__global__ __launch_bounds__(256) void k_xproj_dt(const float* __restrict__ xc,
    const float* __restrict__ dww, const float* __restrict__ dwb,
    const float* __restrict__ W,
    float* __restrict__ dtr, float* __restrict__ Bp, float* __restrict__ Cp,
    float* __restrict__ u_t){
  __shared__ float smem[128*68];
  int bx = blockIdx.x; int pg = bx & 15; int sk = bx >> 4;
  int k = sk & 3; int s = sk >> 2;
  int tid = threadIdx.x;
  for (int i = tid; i < 128*16; i += 256){
    int dr = i>>4; int j4 = (i&15)*4;
    int rw = j4>>5; int col0 = j4 & 31;
    int gr = pg*2 + rw;
    int q = i&7;
    const float* xr = xc + ((size_t)s*DIC+dr)*L2;
    const float* wp = dww + dr*9;
    float bv = dwb[dr];
    float4 acc = make_float4(bv,bv,bv,bv);
    #pragma unroll
    for (int dy=-1;dy<=1;++dy){
      int r = gr+dy;
      float4 mid = make_float4(0.f,0.f,0.f,0.f);
      if (0<=r && r<32) mid = *(const float4*)(xr + r*32 + col0);
      float lf = __shfl_up(mid.w,1,64); if(q==0) lf=0.f;
      float rt = __shfl_down(mid.x,1,64); if(q==7) rt=0.f;
      float w0=wp[(dy+1)*3], w1=wp[(dy+1)*3+1], w2=wp[(dy+1)*3+2];
      acc.x = fmaf(w0,lf,   fmaf(w1,mid.x, fmaf(w2,mid.y, acc.x)));
      acc.y = fmaf(w0,mid.x,fmaf(w1,mid.y, fmaf(w2,mid.z, acc.y)));
      acc.z = fmaf(w0,mid.y,fmaf(w1,mid.z, fmaf(w2,mid.w, acc.z)));
      acc.w = fmaf(w0,mid.z,fmaf(w1,mid.w, fmaf(w2,rt,    acc.w)));
    }
    acc.x = fsilu(acc.x); acc.y = fsilu(acc.y); acc.z = fsilu(acc.z); acc.w = fsilu(acc.w);
    *(float4*)&smem[dr*68 + j4] = acc;
  }
  __syncthreads();
  if (k == 0){
    float* ub = u_t + ((size_t)(s*L2) + pg*64)*DIC;
    for (int i = tid; i < 64*128; i += 256){
      int px2 = i>>7; int dd = i&127;
      ub[(size_t)px2*DIC + dd] = smem[dd*68 + px2];
    }
  }
  int px = tid & 63;
  int cgrp = __builtin_amdgcn_readfirstlane(tid >> 6);
  int c0 = cgrp*9;
  const float* wb = W + (size_t)(k*36 + c0)*DIC;
  float acc[9];
  #pragma unroll
  for (int ci=0;ci<9;++ci) acc[ci]=0.f;
  for (int d=0; d<DIC; ++d){
    float xv = smem[d*68 + px];
    #pragma unroll
    for (int ci=0;ci<9;++ci) acc[ci] = fmaf(wb[ci*DIC+d], xv, acc[ci]);
  }
  __syncthreads();
  #pragma unroll
  for (int ci=0;ci<9;++ci) smem[(c0+ci)*68 + px] = acc[ci];
  __syncthreads();
  {
    int pp = tid >> 2; int r = tid & 3;
    dtr[((size_t)sk*L2 + pg*64 + pp)*4 + r] = smem[r*68 + pp];
  }
  float* Bb = Bp + ((size_t)sk*L2 + pg*64)*NST;
  float* Cb = Cp + ((size_t)sk*L2 + pg*64)*NST;
  for (int i = tid; i < 1024; i += 256){
    int pp = i>>4; int n = i&15;
    Bb[pp*NST + n] = smem[(4+n)*68 + pp];
    Cb[pp*NST + n] = smem[(20+n)*68 + pp];
  }
}

// scan pixel for direction k, chunk ch (32 steps), step j
__device__ __forceinline__ int scan_pix32(int ch, int j, int k){
  if (k==0) return ch*32 + j;
  if (k==1) return j*32 + ch;
  if (k==2) return 1023 - (ch*32 + j);
  return 1023 - (j*32 + ch);
}

// half-state step (8 of 16 SSM states per thread)
struct StepH { float4 dt4; float uv; float4 B0,B1; };
__device__ __forceinline__ StepH loadH(const float* dr, const float* ub, const float* Bb, int p){
  StepH r;
  r.dt4 = *(const float4*)(dr + (size_t)p*4);
  r.uv = ub[(size_t)p*DIC];
  const float* bp = Bb + p*NST;   // Bb pre-offset by nh*8
  r.B0 = *(const float4*)bp; r.B1 = *(const float4*)(bp+4);
  return r;
}
__device__ __forceinline__ float dt_eval(float4 w4, float bb, float4 d4){
  return fsoftplus(fmaf(w4.x,d4.x,fmaf(w4.y,d4.y,fmaf(w4.z,d4.z,fmaf(w4.w,d4.w,bb)))));
}

// ---------------- k9: scan pass 1, n-split, 768 blocks
__global__ __launch_bounds__(256,4) void k_scan_part3(const float* __restrict__ dtr,
    const float* __restrict__ dtw, const float* __restrict__ dtb,
    const float* __restrict__ u_t, const float* __restrict__ Bp,
    const float* __restrict__ A_logs, float* __restrict__ hend, float* __restrict__ Ssum){
  int bx = blockIdx.x; int ch = bx & 31; int sk = bx >> 5;
  int k = sk & 3; int s = sk >> 2;
  int tid = threadIdx.x; int d = tid >> 1; int nh = tid & 1;
  float aco[8];
  {
    const float* ab = A_logs + (size_t)(k*DIC+d)*NST + nh*8;
    #pragma unroll
    for (int n=0;n<8;++n) aco[n] = -LOG2E * fexp(ab[n]);
  }
  float4 w4 = *(const float4*)(dtw + (size_t)(k*DIC+d)*4);
  float bb = dtb[k*DIC+d];
  float h[8]; float Sacc = 0.f;
  #pragma unroll
  for (int n=0;n<8;++n) h[n]=0.f;
  const float* dr = dtr + (size_t)sk*L2*4;
  const float* ub = u_t + (size_t)s*L2*DIC + d;
  const float* Bb = Bp + (size_t)sk*L2*NST + nh*8;
  StepH cur = loadH(dr, ub, Bb, scan_pix32(ch, 0, k));
  #pragma unroll 4
  for (int j=0;j<32;++j){
    StepH nxt;
    if (j < 31) nxt = loadH(dr, ub, Bb, scan_pix32(ch, j+1, k));
    float dtv = dt_eval(w4, bb, cur.dt4);
    Sacc += dtv;
    float tv = dtv*cur.uv;
    #define PSTEP(NI, BV) { float a_ = __builtin_amdgcn_exp2f(dtv*aco[NI]); \
      h[NI] = fmaf(a_, h[NI], tv*(BV)); }
    PSTEP(0,cur.B0.x) PSTEP(1,cur.B0.y) PSTEP(2,cur.B0.z) PSTEP(3,cur.B0.w)
    PSTEP(4,cur.B1.x) PSTEP(5,cur.B1.y) PSTEP(6,cur.B1.z) PSTEP(7,cur.B1.w)
    #undef PSTEP
    cur = nxt;
  }
  size_t base = ((size_t)(sk*NCH + ch)*DIC + d)*NST + nh*8;
  *(float4*)(hend + base)     = make_float4(h[0],h[1],h[2],h[3]);
  *(float4*)(hend + base + 4) = make_float4(h[4],h[5],h[6],h[7]);
  if (nh == 0) Ssum[(size_t)(sk*NCH + ch)*DIC + d] = Sacc;
}

// ---------------- k10: serial chunk prefix
__global__ __launch_bounds__(256) void k_scan_fix3(const float* __restrict__ hend,
    const float* __restrict__ Ssum, const float* __restrict__ A_logs,
    float* __restrict__ Hin){
  int t = blockIdx.x*256 + threadIdx.x;
  int n = t & 15; int d = (t>>4) & 127; int sk = t >> 11; int k = sk & 3;
  float aco = -LOG2E * fexp(A_logs[(size_t)(k*DIC+d)*NST + n]);
  float H = 0.f;
  #pragma unroll 8
  for (int ch=0; ch<NCH; ++ch){
    size_t sidx = (size_t)(sk*NCH + ch)*DIC + d;
    float pa = __builtin_amdgcn_exp2f(aco * Ssum[sidx]);
    float he = hend[sidx*NST + n];
    Hin[sidx*NST + n] = H;
    H = fmaf(pa, H, he);
  }
}

// ---------------- k11: full scan + y output, n-split, 768 blocks
__global__ __launch_bounds__(256,4) void k_scan_y3(const float* __restrict__ dtr,
    const float* __restrict__ dtw, const float* __restrict__ dtb,
    const float* __restrict__ u_t, const float* __restrict__ Bp, const float* __restrict__ Cp,
    const float* __restrict__ A_logs, const float* __restrict__ Ds,
    const float* __restrict__ Hin, float* __restrict__ ys_t){
  int bx = blockIdx.x; int ch = bx & 31; int sk = bx >> 5;
  int k = sk & 3; int s = sk >> 2;
  int tid = threadIdx.x; int d = tid >> 1; int nh = tid & 1;
  float aco[8];
  {
    const float* ab = A_logs + (size_t)(k*DIC+d)*NST + nh*8;
    #pragma unroll
    for (int n=0;n<8;++n) aco[n] = -LOG2E * fexp(ab[n]);
  }
  float4 w4 = *(const float4*)(dtw + (size_t)(k*DIC+d)*4);
  float bb = dtb[k*DIC+d];
  float Dv = Ds[k*DIC+d];
  float h[8];
  size_t hbase = ((size_t)(sk*NCH + ch)*DIC + d)*NST + nh*8;
  {
    float4 h0 = *(const float4*)(Hin + hbase);
    float4 h1 = *(const float4*)(Hin + hbase + 4);
    h[0]=h0.x; h[1]=h0.y; h[2]=h0.z; h[3]=h0.w;
    h[4]=h1.x; h[5]=h1.y; h[6]=h1.z; h[7]=h1.w;
  }
  const float* dr = dtr + (size_t)sk*L2*4;
  const float* ub = u_t + (size_t)s*L2*DIC + d;
  const float* Bb = Bp + (size_t)sk*L2*NST + nh*8;
  const float* Cb = Cp + (size_t)sk*L2*NST + nh*8;
  float* yb = ys_t + (size_t)sk*L2*DIC + d;
  int pcur = scan_pix32(ch, 0, k);
  StepH cur = loadH(dr, ub, Bb, pcur);
  float4 Cc0 = *(const float4*)(Cb + pcur*NST);
  float4 Cc1 = *(const float4*)(Cb + pcur*NST + 4);
  #pragma unroll 4
  for (int j=0;j<32;++j){
    StepH nxt; float4 Cn0, Cn1; int pn = pcur;
    if (j < 31){
      pn = scan_pix32(ch, j+1, k);
      nxt = loadH(dr, ub, Bb, pn);
      Cn0 = *(const float4*)(Cb + pn*NST);
      Cn1 = *(const float4*)(Cb + pn*NST + 4);
    }
    float dtv = dt_eval(w4, bb, cur.dt4);
    float tv = dtv*cur.uv;
    float y0=0.f, y1=0.f, y2=0.f, y3=0.f;
    #define YSTEP(NI, BV, CV, YA) { float a_ = __builtin_amdgcn_exp2f(dtv*aco[NI]); \
      h[NI] = fmaf(a_, h[NI], tv*(BV)); YA = fmaf(h[NI], (CV), YA); }
    YSTEP(0,cur.B0.x,Cc0.x,y0) YSTEP(1,cur.B0.y,Cc0.y,y1) YSTEP(2,cur.B0.z,Cc0.z,y2) YSTEP(3,cur.B0.w,Cc0.w,y3)
    YSTEP(4,cur.B1.x,Cc1.x,y0) YSTEP(5,cur.B1.y,Cc1.y,y1) YSTEP(6,cur.B1.z,Cc1.z,y2) YSTEP(7,cur.B1.w,Cc1.w,y3)
    #undef YSTEP
    float py = (y0+y1)+(y2+y3);
    float tot = py + __shfl_xor(py, 1, 64);
    if (nh == 0) yb[(size_t)pcur*DIC] = fmaf(cur.uv, Dv, tot);
    cur = nxt; Cc0 = Cn0; Cc1 = Cn1; pcur = pn;
  }
}

// ---------------- k12: fused tail, 8 px per block, 768 blocks
__global__ __launch_bounds__(256) void k_tail(const float* __restrict__ ys_t,
    const float* __restrict__ z_t, const float* __restrict__ ong, const float* __restrict__ onb,
    const float* __restrict__ Wop, const float* __restrict__ x_cmaj,
    const float* __restrict__ g2, const float* __restrict__ b2n,
    const float* __restrict__ w1, const float* __restrict__ b1,
    const float* __restrict__ w2, const float* __restrict__ b2,
    float* __restrict__ out){
  __shared__ float yt[128*9];
  __shared__ float xvt[64*9];
  __shared__ float ts[64*9];
  int s = blockIdx.x >> 7; int pg = blockIdx.x & 127;
  int tid = threadIdx.x;
  // --- combine + out_norm LN(128) + silu(z): 2 iters x 4 waves cover 8 px
  {
    int wv = __builtin_amdgcn_readfirstlane(tid>>6); int lane = tid&63;
    int d0 = lane, d1 = lane+64;
    for (int i=0;i<2;++i){
      int px = i*4 + wv; int p = pg*8 + px;
      const float* yb = ys_t + ((size_t)(s*4)*L2 + p)*DIC;
      float ya = yb[d0] + yb[(size_t)L2*DIC + d0] + yb[(size_t)2*L2*DIC + d0] + yb[(size_t)3*L2*DIC + d0];
      float yc = yb[d1] + yb[(size_t)L2*DIC + d1] + yb[(size_t)2*L2*DIC + d1] + yb[(size_t)3*L2*DIC + d1];
      float sm = ya+yc, sq = ya*ya+yc*yc;
      for (int m=1;m<64;m<<=1){ sm+=__shfl_xor(sm,m,64); sq+=__shfl_xor(sq,m,64); }
      float mean = sm*(1.f/128.f); float var = sq*(1.f/128.f)-mean*mean;
      float rs = rsqrtf(var + 1e-5f);
      float yn0 = (ya-mean)*rs*ong[d0] + onb[d0];
      float yn1 = (yc-mean)*rs*ong[d1] + onb[d1];
      float zv0 = z_t[((size_t)s*DIC+d0)*L2 + p];
      float zv1 = z_t[((size_t)s*DIC+d1)*L2 + p];
      yt[d0*9 + px] = yn0 * fsilu(zv0);
      yt[d1*9 + px] = yn1 * fsilu(zv1);
    }
  }
  __syncthreads();
  // --- out_proj + residual -> xvt: 32 cgroups x 2 co
  {
    int px = tid & 7; int cgp = tid >> 3;
    int c0 = cgp*2;
    float a0=0.f,a1=0.f;
    for (int d=0; d<DIC; ++d){
      float yv = yt[d*9 + px];
      a0 = fmaf(Wop[(c0+0)*DIC + d], yv, a0);
      a1 = fmaf(Wop[(c0+1)*DIC + d], yv, a1);
    }
    int p = pg*8 + px;
    size_t base = ((size_t)s*CCH + c0)*L2 + p;
    xvt[(c0+0)*9 + px] = x_cmaj[base]    + a0;
    xvt[(c0+1)*9 + px] = x_cmaj[base+L2] + a1;
  }
  __syncthreads();
  // --- ln2 + fc1 + gelu: 32 ogroups x 2 o
  int px = tid & 7; int cgp = tid >> 3;
  float sm=0.f, sq=0.f;
  for (int c=0;c<64;++c){ float v = xvt[c*9+px]; sm+=v; sq+=v*v; }
  float mean = sm*(1.f/64.f);
  float rs = rsqrtf(sq*(1.f/64.f) - mean*mean + 1e-5f);
  int o0 = cgp*2;
  float t0 = b1[o0], t1 = b1[o0+1];
  for (int c=0;c<64;++c){
    float xn = (xvt[c*9+px]-mean)*rs*g2[c] + b2n[c];
    t0 = fmaf(xn, w1[(o0+0)*64 + c], t0);
    t1 = fmaf(xn, w1[(o0+1)*64 + c], t1);
  }
  ts[(o0+0)*9 + px] = fgelu(t0);
  ts[(o0+1)*9 + px] = fgelu(t1);
  __syncthreads();
  // --- fc2 + residual -> out
  int c0 = cgp*2;
  float acc0 = xvt[(c0+0)*9+px] + b2[c0+0];
  float acc1 = xvt[(c0+1)*9+px] + b2[c0+1];
  for (int o=0;o<64;++o){
    float tv = ts[o*9+px];
    acc0 = fmaf(tv, w2[(c0+0)*64 + o], acc0);
    acc1 = fmaf(tv, w2[(c0+1)*64 + o], acc1);
  }
  int p = pg*8 + px;
  out[((size_t)s*CCH + c0+0)*L2 + p] = acc0;
  out[((size_t)s*CCH + c0+1)*L2 + p] = acc1;
}

extern "C" void kernel_launch(void* const* d_in, const int* in_sizes, int n_in,
                              void* d_out, int out_size, void* d_ws, size_t ws_size,
                              hipStream_t stream){
  (void)in_sizes; (void)n_in; (void)out_size; (void)ws_size;
  const float* img      = (const float*)d_in[0];
  const float* dz       = (const float*)d_in[1];
  const float* sg       = (const float*)d_in[2];
  const float* norm_g   = (const float*)d_in[3];
  const float* norm_b   = (const float*)d_in[4];
  const float* gn1_g    = (const float*)d_in[5];
  const float* gn1_b    = (const float*)d_in[6];
  const float* conv1_w  = (const float*)d_in[7];
  const float* conv1_b  = (const float*)d_in[8];
  const float* gn2_g    = (const float*)d_in[9];
  const float* gn2_b    = (const float*)d_in[10];
  const float* conv2_w  = (const float*)d_in[11];
  const float* conv2_b  = (const float*)d_in[12];
  const float* skip_w   = (const float*)d_in[13];
  const float* skip_b   = (const float*)d_in[14];
  const float* ln1_g    = (const float*)d_in[15];
  const float* ln1_b    = (const float*)d_in[16];
  const float* ln2_g    = (const float*)d_in[17];
  const float* ln2_b    = (const float*)d_in[18];
  const float* in_proj_w= (const float*)d_in[19];
  const float* dwconv_w = (const float*)d_in[20];
  const float* dwconv_b = (const float*)d_in[21];
  const float* x_proj_w = (const float*)d_in[22];
  const float* dt_proj_w= (const float*)d_in[23];
  const float* dt_proj_b= (const float*)d_in[24];
  const float* A_logs   = (const float*)d_in[25];
  const float* Ds       = (const float*)d_in[26];
  const float* out_norm_g = (const float*)d_in[27];
  const float* out_norm_b = (const float*)d_in[28];
  const float* out_proj_w = (const float*)d_in[29];
  const float* fc1_w    = (const float*)d_in[30];
  const float* fc1_b    = (const float*)d_in[31];
  const float* fc2_w    = (const float*)d_in[32];
  const float* fc2_b    = (const float*)d_in[33];

  float* ws = (float*)d_ws;
  float* x3c    = ws;                       // 1,179,648
  float* xact1  = x3c    + 1179648;         // 1,253,376 (padded GN1 act)
  float* h1     = xact1  + 1253376;         // 393,216
  float* xact2  = h1     + 393216;          // 417,792 (padded GN2 act)
  float* xpslot = xact2  + 417792;          // 393,216 (hosts Bp)
  float* x_cmaj = xpslot + 393216;          // 393,216
  float* z_t    = x_cmaj + 393216;          // 786,432
  float* xc     = z_t    + 786432;          // 786,432
  float* cpslot = xc     + 786432;          // 786,432 (hosts Cp)
  float* hole   = cpslot + 786432;          // 884,736 (dtr + Ssum)
  float* scanbuf= hole   + 884736;          // 3,145,728
  float* ys_t   = scanbuf+ 3145728;         // 3,145,728
  float* statsb = ys_t   + 3145728;         // psum1(768) psq1(768) psum2(384) psq2(384)
  float* psum1  = statsb;
  float* psq1   = statsb + 768;
  float* psum2  = statsb + 1536;
  float* psq2   = statsb + 1920;
  // aliases into dead regions (timeline-verified):
  // part1 = 12 slots: scanbuf (8 slots) + ys_t[0 .. 4 slots) — written by conv1,
  //   consumed by reduce1 BEFORE conv2 writes part2 slots 0-3 (same ys_t region).
  // part2 slots 4,5 (= ys_t + 4..6 slots) written EARLY by k_gnact1_skip — disjoint
  //   from part1's spill (exactly slots 0-3).
  float* part1  = scanbuf;
  float* part2  = ys_t;
  float* hend   = x3c;              // x3c dead after k_gnact1_skip (last reader)
  float* u_t    = h1;               // h1+xact2 dead after gnact2/conv2
  float* Bp     = xpslot;
  float* Cp     = cpslot;
  float* dtr    = hole;             // 98,304
  float* Ssum   = hole + 98304;     // 98,304
  float* Hin    = scanbuf;          // part1 dead after reduce1

  k_ln2d<<<768, 256, 0, stream>>>(img, dz, sg, norm_g, norm_b, x3c, psum1, psq1);
  k_gnact1_skip<<<1536, 256, 0, stream>>>(x3c, psum1, psq1, gn1_g, gn1_b, skip_w,
                                          xact1, part2);
  k_conv1_split<<<2304, 256, 0, stream>>>(xact1, conv1_w, part1);
  k_reduce1<<<384, 256, 0, stream>>>(part1, conv1_b, h1, psum2, psq2);
  k_gnact_pad<<<6*CCH, 256, 0, stream>>>(h1, psum2, psq2, gn2_g, gn2_b, CCH, 64,
                                         1.f/(CCH*L2), 1e-5f, xact2);
  k_conv2_split<<<768, 256, 0, stream>>>(xact2, conv2_w, part2);
  k_red2_ln1_inproj<<<768, 256, 0, stream>>>(part2, conv2_b, skip_b, ln1_g, ln1_b, in_proj_w,
                                             x_cmaj, xc, z_t);
  k_xproj_dt<<<384, 256, 0, stream>>>(xc, dwconv_w, dwconv_b, x_proj_w, dtr, Bp, Cp, u_t);
  k_scan_part3<<<768, 256, 0, stream>>>(dtr, dt_proj_w, dt_proj_b, u_t, Bp, A_logs, hend, Ssum);
  k_scan_fix3<<<192, 256, 0, stream>>>(hend, Ssum, A_logs, Hin);
  k_scan_y3<<<768, 256, 0, stream>>>(dtr, dt_proj_w, dt_proj_b, u_t, Bp, Cp, A_logs, Ds, Hin, ys_t);
  k_tail<<<768, 256, 0, stream>>>(ys_t, z_t, out_norm_g, out_norm_b, out_proj_w, x_cmaj,
                                  ln2_g, ln2_b, fc1_w, fc1_b, fc2_w, fc2_b, (float*)d_out);
}

// Round 8
// 286.354 us; speedup vs baseline: 2.8611x; 1.0012x over previous
//
#include <hip/hip_runtime.h>
#include <math.h>

// Problem dims
#define BL    6
#define CCH   64
#define C3    192
#define L2    1024
#define DIC   128
#define NST   16
#define K4    4
#define PSTR  1088   // padded plane stride: 34 rows * 32 cols
#define NCH   32     // scan chunks per sequence (32 steps each)

#define LOG2E 1.44269504088896340736f
#define LN2C  0.69314718055994530942f

typedef float f2 __attribute__((ext_vector_type(2)));
__device__ __forceinline__ f2 mkf2(float a, float b){ f2 r; r.x=a; r.y=b; return r; }
__device__ __forceinline__ f2 fma2(f2 a, float b, f2 c){
  f2 bb; bb.x=b; bb.y=b;
  return __builtin_elementwise_fma(a, bb, c);
}

__device__ __forceinline__ float fexp(float x){ return __builtin_amdgcn_exp2f(x*LOG2E); }
__device__ __forceinline__ float fsilu(float x){ return x * __builtin_amdgcn_rcpf(1.f + fexp(-x)); }
__device__ __forceinline__ float fsoftplus(float x){
  if (x > 20.f) return x;
  return __builtin_amdgcn_logf(1.f + fexp(x)) * LN2C;
}
__device__ __forceinline__ float fgelu(float x){
  return 0.5f*x*(1.f + erff(x*0.70710678118654752440f));
}

// ---------------- k1: per-pixel LN + concat; GN1 partials. 768 blocks (8 px each).
__global__ __launch_bounds__(256) void k_ln2d(const float* __restrict__ img,
    const float* __restrict__ dz, const float* __restrict__ sg,
    const float* __restrict__ g, const float* __restrict__ b, float* __restrict__ x3c,
    float* __restrict__ psum1, float* __restrict__ psq1){
  __shared__ float ps[4][8], pq[4][8], gs[4], gq[4];
  int s = blockIdx.x >> 7;
  int pg = blockIdx.x & 127;
  int tid = threadIdx.x;
  int px = tid & 7; int cg = tid >> 3;
  int wv = tid >> 6; int lane = tid & 63;
  int p = pg*8 + px;
  int bsmp = s/3;
  const float* fr = img + (size_t)s*CCH*L2;
  float vals[2]; float sm=0.f, sq=0.f;
  #pragma unroll
  for (int j=0;j<2;++j){
    int c = cg*2 + j;
    float v = fr[c*L2 + p];
    vals[j]=v; sm+=v; sq+=v*v;
  }
  sm += __shfl_xor(sm,8,64);  sq += __shfl_xor(sq,8,64);
  sm += __shfl_xor(sm,16,64); sq += __shfl_xor(sq,16,64);
  sm += __shfl_xor(sm,32,64); sq += __shfl_xor(sq,32,64);
  if (lane < 8){ ps[wv][lane]=sm; pq[wv][lane]=sq; }
  __syncthreads();
  sm = ps[0][px]+ps[1][px]+ps[2][px]+ps[3][px];
  sq = pq[0][px]+pq[1][px]+pq[2][px]+pq[3][px];
  float mean = sm*(1.f/CCH); float var = sq*(1.f/CCH)-mean*mean;
  float rs = rsqrtf(var + 1e-6f);
  float* o = x3c + (size_t)s*C3*L2;
  const float* dzp = dz + (size_t)bsmp*CCH*L2;
  const float* sgp = sg + (size_t)bsmp*CCH*L2;
  float gsm=0.f, gsq=0.f;
  #pragma unroll
  for (int j=0;j<2;++j){
    int c = cg*2+j;
    float dzv = dzp[c*L2+p];
    float nv  = (vals[j]-mean)*rs*g[c] + b[c];
    float sgv = sgp[c*L2+p];
    o[c*L2+p] = dzv;
    o[(CCH+c)*L2+p] = nv;
    o[(2*CCH+c)*L2+p] = sgv;
    gsm += dzv+nv+sgv; gsq += dzv*dzv+nv*nv+sgv*sgv;
  }
  for (int m=1;m<64;m<<=1){ gsm+=__shfl_xor(gsm,m,64); gsq+=__shfl_xor(gsq,m,64); }
  if (lane==0){ gs[wv]=gsm; gq[wv]=gsq; }
  __syncthreads();
  if (tid==0){
    psum1[blockIdx.x] = gs[0]+gs[1]+gs[2]+gs[3];
    psq1 [blockIdx.x] = gq[0]+gq[1]+gq[2]+gq[3];
  }
}

// ---------------- k2: MERGED gnact1 (blocks 0..1151) + skip 1x1 (blocks 1152..1535)
__global__ __launch_bounds__(256) void k_gnact1_skip(const float* __restrict__ x3c,
    const float* __restrict__ psum, const float* __restrict__ psq,
    const float* __restrict__ g, const float* __restrict__ b,
    const float* __restrict__ wsk,
    float* __restrict__ xact1, float* __restrict__ part){
  int bx = blockIdx.x;
  int tid = threadIdx.x;
  if (bx < 1152){
    int s = bx / C3; int c = bx % C3;
    float sm=0.f, sq=0.f;
    for (int i=0;i<128;++i){ sm += psum[s*128+i]; sq += psq[s*128+i]; }
    float mean = sm*(1.f/(C3*L2));
    float var = sq*(1.f/(C3*L2)) - mean*mean;
    float rs = rsqrtf(var + 1e-5f);
    float gc = g[c]*rs; float bc = b[c] - mean*rs*g[c];
    float4 v = *(const float4*)(x3c + (size_t)bx*1024 + tid*4);
    float4 o; o.x = fsilu(v.x*gc+bc); o.y = fsilu(v.y*gc+bc);
    o.z = fsilu(v.z*gc+bc); o.w = fsilu(v.w*gc+bc);
    float* pl = xact1 + (size_t)bx*PSTR;
    *(float4*)(pl + 32 + tid*4) = o;
    float4 z4 = make_float4(0.f,0.f,0.f,0.f);
    if (tid < 8)  *(float4*)(pl + tid*4) = z4;
    else if (tid < 16) *(float4*)(pl + 1056 + (tid-8)*4) = z4;
  } else {
    // skip 1x1 (2 roles x 96 ci), packed over co pair
    int t = bx - 1152;
    int role = t & 1; int cop = (t>>1)&31; int s = t >> 6;
    int co0 = cop*2, co1 = co0+1;
    int row = tid>>3; int q = tid&7; int col0 = q*4;
    int p = row*32+col0;
    f2 a[4];
    #pragma unroll
    for (int i=0;i<4;++i){ a[i].x=0.f; a[i].y=0.f; }
    int ci0 = role*96;
    const float* x3 = x3c + ((size_t)s*C3 + ci0)*L2 + p;
    const float* w0p = wsk + co0*C3 + ci0;
    const float* w1p = wsk + co1*C3 + ci0;
    #pragma unroll 4
    for (int ci=0; ci<96; ++ci){
      float4 v = *(const float4*)(x3 + (size_t)ci*L2);
      f2 w = mkf2(w0p[ci], w1p[ci]);
      a[0] = fma2(w, v.x, a[0]);
      a[1] = fma2(w, v.y, a[1]);
      a[2] = fma2(w, v.z, a[2]);
      a[3] = fma2(w, v.w, a[3]);
    }
    float* pp = part + (size_t)(4+role)*(BL*CCH*L2) + ((size_t)s*CCH+co0)*L2 + p;
    *(float4*)pp = make_float4(a[0].x,a[1].x,a[2].x,a[3].x);
    *(float4*)(pp+L2) = make_float4(a[0].y,a[1].y,a[2].y,a[3].y);
  }
}

// ---------------- gnact2 (generic)
__global__ __launch_bounds__(256) void k_gnact_pad(const float* __restrict__ x,
    const float* __restrict__ psum, const float* __restrict__ psq,
    const float* __restrict__ g, const float* __restrict__ b,
    int ch, int parts, float inv_n, float eps, float* __restrict__ out){
  int bx = blockIdx.x;
  int s = bx / ch; int c = bx % ch;
  int tid = threadIdx.x;
  float sm=0.f, sq=0.f;
  for (int i=0;i<parts;++i){ sm += psum[s*parts+i]; sq += psq[s*parts+i]; }
  float mean = sm*inv_n;
  float var = sq*inv_n - mean*mean;
  float rs = rsqrtf(var + eps);
  float gc = g[c]*rs; float bc = b[c] - mean*rs*g[c];
  float4 v = *(const float4*)(x + (size_t)bx*1024 + tid*4);
  float4 o; o.x = fsilu(v.x*gc+bc); o.y = fsilu(v.y*gc+bc);
  o.z = fsilu(v.z*gc+bc); o.w = fsilu(v.w*gc+bc);
  float* pl = out + (size_t)bx*PSTR;
  *(float4*)(pl + 32 + tid*4) = o;
  float4 z4 = make_float4(0.f,0.f,0.f,0.f);
  if (tid < 8)  *(float4*)(pl + tid*4) = z4;
  else if (tid < 16) *(float4*)(pl + 1056 + (tid-8)*4) = z4;
}

// packed conv helpers: a[4] = (co0,co1) accumulators per px
__device__ __forceinline__ void conv_row_acc2(f2* a, float4 mid, float lf, float rt,
    const float* wp0, const float* wp1){
  f2 w0 = mkf2(wp0[0],wp1[0]);
  f2 w1 = mkf2(wp0[1],wp1[1]);
  f2 w2 = mkf2(wp0[2],wp1[2]);
  a[0] = fma2(w0,lf,   fma2(w1,mid.x, fma2(w2,mid.y, a[0])));
  a[1] = fma2(w0,mid.x,fma2(w1,mid.y, fma2(w2,mid.z, a[1])));
  a[2] = fma2(w0,mid.y,fma2(w1,mid.z, fma2(w2,mid.w, a[2])));
  a[3] = fma2(w0,mid.z,fma2(w1,mid.w, fma2(w2,rt,    a[3])));
}

__device__ __forceinline__ void conv_ci_body2(float4 m0, float4 m1, float4 m2, int q,
    const float* wp0, const float* wp1, f2* a){
  float lf0=__shfl_up(m0.w,1,64), rt0=__shfl_down(m0.x,1,64);
  float lf1=__shfl_up(m1.w,1,64), rt1=__shfl_down(m1.x,1,64);
  float lf2=__shfl_up(m2.w,1,64), rt2=__shfl_down(m2.x,1,64);
  if (q==0){ lf0=0.f; lf1=0.f; lf2=0.f; }
  if (q==7){ rt0=0.f; rt1=0.f; rt2=0.f; }
  conv_row_acc2(a,m0,lf0,rt0, wp0+0, wp1+0);
  conv_row_acc2(a,m1,lf1,rt1, wp0+3, wp1+3);
  conv_row_acc2(a,m2,lf2,rt2, wp0+6, wp1+6);
}

// ---------------- k3: conv1 192ci->64co, split-K=12 (16 ci each), 2304 blocks
__global__ __launch_bounds__(256) void k_conv1_split(const float* __restrict__ xact,
    const float* __restrict__ w, float* __restrict__ part){
  int bx = blockIdx.x; int kk = bx % 12; int r = bx / 12;
  int cop = r & 31; int s = r >> 5;
  int co0 = cop*2, co1 = co0+1;
  int tid = threadIdx.x; int row = tid>>3; int q = tid&7; int col0 = q*4;
  f2 a[4];
  #pragma unroll
  for (int i=0;i<4;++i){ a[i].x=0.f; a[i].y=0.f; }
  int ci0 = kk*16;
  const float* pl = xact + ((size_t)s*C3 + ci0)*PSTR + row*32 + col0;
  const float* wp0 = w + (size_t)(co0*C3 + ci0)*9;
  const float* wp1 = w + (size_t)(co1*C3 + ci0)*9;
  float4 m0 = *(const float4*)(pl);
  float4 m1 = *(const float4*)(pl+32);
  float4 m2 = *(const float4*)(pl+64);
  #pragma unroll 2
  for (int i=0;i<16;++i){
    const float* pn = pl + (i<15 ? PSTR : 0);
    float4 n0 = *(const float4*)(pn);
    float4 n1 = *(const float4*)(pn+32);
    float4 n2 = *(const float4*)(pn+64);
    conv_ci_body2(m0,m1,m2,q, wp0, wp1, a);
    wp0 += 9; wp1 += 9; pl = pn; m0=n0; m1=n1; m2=n2;
  }
  float* pp = part + (size_t)kk*(BL*CCH*L2) + ((size_t)s*CCH+co0)*L2 + row*32+col0;
  *(float4*)pp = make_float4(a[0].x,a[1].x,a[2].x,a[3].x);
  *(float4*)(pp+L2) = make_float4(a[0].y,a[1].y,a[2].y,a[3].y);
}

// ---------------- k4: reduce conv1 partials (12) + bias -> h1; GN2 partials
__global__ __launch_bounds__(256) void k_reduce1(const float* __restrict__ part,
    const float* __restrict__ bias, float* __restrict__ h1,
    float* __restrict__ psum2, float* __restrict__ psq2){
  int co = blockIdx.x & 63; int s = blockIdx.x >> 6;
  size_t ofs = ((size_t)s*CCH+co)*L2 + threadIdx.x*4;
  const size_t stride = (size_t)BL*CCH*L2;
  float4 acc = *(const float4*)(part + ofs);
  #pragma unroll
  for (int kk=1;kk<12;++kk){
    float4 r = *(const float4*)(part + (size_t)kk*stride + ofs);
    acc.x += r.x; acc.y += r.y; acc.z += r.z; acc.w += r.w;
  }
  float bv = bias[co];
  acc.x += bv; acc.y += bv; acc.z += bv; acc.w += bv;
  *(float4*)(h1 + ofs) = acc;
  float sm = acc.x+acc.y+acc.z+acc.w;
  float sq = acc.x*acc.x+acc.y*acc.y+acc.z*acc.z+acc.w*acc.w;
  for (int m=1;m<64;m<<=1){ sm+=__shfl_xor(sm,m,64); sq+=__shfl_xor(sq,m,64); }
  __shared__ float s_sm[4], s_sq[4];
  int wv = threadIdx.x>>6;
  if ((threadIdx.x&63)==0){ s_sm[wv]=sm; s_sq[wv]=sq; }
  __syncthreads();
  if (threadIdx.x==0){
    psum2[blockIdx.x] = s_sm[0]+s_sm[1]+s_sm[2]+s_sm[3];
    psq2 [blockIdx.x] = s_sq[0]+s_sq[1]+s_sq[2]+s_sq[3];
  }
}

// ---------------- k6: conv2 FOUR roles x 16ci, 768 blocks
__global__ __launch_bounds__(256) void k_conv2_split(const float* __restrict__ xact2,
    const float* __restrict__ w2, float* __restrict__ part){
  int bx = blockIdx.x; int role = bx & 3; int t = bx >> 2;
  int cop = t & 31; int s = t >> 5;
  int co0 = cop*2, co1 = co0+1;
  int tid = threadIdx.x; int row = tid>>3; int q = tid&7; int col0 = q*4;
  int p = row*32+col0;
  f2 a[4];
  #pragma unroll
  for (int i=0;i<4;++i){ a[i].x=0.f; a[i].y=0.f; }
  int ci0 = role*16;
  const float* pl = xact2 + ((size_t)s*CCH + ci0)*PSTR + row*32 + col0;
  const float* wp0 = w2 + (size_t)(co0*CCH + ci0)*9;
  const float* wp1 = w2 + (size_t)(co1*CCH + ci0)*9;
  float4 m0 = *(const float4*)(pl);
  float4 m1 = *(const float4*)(pl+32);
  float4 m2 = *(const float4*)(pl+64);
  #pragma unroll 2
  for (int i=0;i<16;++i){
    const float* pn = pl + (i<15 ? PSTR : 0);
    float4 n0 = *(const float4*)(pn);
    float4 n1 = *(const float4*)(pn+32);
    float4 n2 = *(const float4*)(pn+64);
    conv_ci_body2(m0,m1,m2,q, wp0, wp1, a);
    wp0 += 9; wp1 += 9; pl = pn; m0=n0; m1=n1; m2=n2;
  }
  float* pp = part + (size_t)role*(BL*CCH*L2) + ((size_t)s*CCH+co0)*L2 + p;
  *(float4*)pp = make_float4(a[0].x,a[1].x,a[2].x,a[3].x);
  *(float4*)(pp+L2) = make_float4(a[0].y,a[1].y,a[2].y,a[3].y);
}

// ---------------- k7: reduce2(6 slots) + ln1 + in_proj fused, oq split x8, packed GEMM
__global__ __launch_bounds__(256) void k_red2_ln1_inproj(const float* __restrict__ part,
    const float* __restrict__ b2, const float* __restrict__ bsk,
    const float* __restrict__ g, const float* __restrict__ b,
    const float* __restrict__ W,
    float* __restrict__ x_cmaj, float* __restrict__ xc, float* __restrict__ z_t){
  __shared__ float xn_s[64*65];
  int bx = blockIdx.x; int oq = bx & 7; int pg = (bx>>3)&15; int s = bx>>7;
  int p0 = pg*64;
  int tid = threadIdx.x;
  const size_t stride = (size_t)BL*CCH*L2;
  #pragma unroll
  for (int kq=0;kq<4;++kq){
    int f = kq*256 + tid;
    int co = f >> 4; int px4 = (f & 15)*4;
    size_t ofs = ((size_t)s*CCH+co)*L2 + p0 + px4;
    float4 r0 = *(const float4*)(part + ofs);
    float4 r1 = *(const float4*)(part + stride + ofs);
    float4 r2 = *(const float4*)(part + 2*stride + ofs);
    float4 r3 = *(const float4*)(part + 3*stride + ofs);
    float4 r4 = *(const float4*)(part + 4*stride + ofs);
    float4 r5 = *(const float4*)(part + 5*stride + ofs);
    float bv = b2[co]+bsk[co];
    float4 o;
    o.x = ((r0.x+r1.x)+(r2.x+r3.x))+(r4.x+r5.x)+bv;
    o.y = ((r0.y+r1.y)+(r2.y+r3.y))+(r4.y+r5.y)+bv;
    o.z = ((r0.z+r1.z)+(r2.z+r3.z))+(r4.z+r5.z)+bv;
    o.w = ((r0.w+r1.w)+(r2.w+r3.w))+(r4.w+r5.w)+bv;
    if (oq == 0) *(float4*)(x_cmaj + ofs) = o;
    xn_s[(px4+0)*65 + co] = o.x;
    xn_s[(px4+1)*65 + co] = o.y;
    xn_s[(px4+2)*65 + co] = o.z;
    xn_s[(px4+3)*65 + co] = o.w;
  }
  __syncthreads();
  {
    int wv = __builtin_amdgcn_readfirstlane(tid>>6); int lane = tid&63;
    for (int j=0;j<16;++j){
      int pl = wv*16 + j;
      float v = xn_s[pl*65 + lane];
      float sm = v, sq = v*v;
      for (int m=1;m<64;m<<=1){ sm += __shfl_xor(sm,m,64); sq += __shfl_xor(sq,m,64); }
      float mean = sm*(1.f/64.f); float var = sq*(1.f/64.f) - mean*mean;
      float rs = rsqrtf(var + 1e-5f);
      xn_s[pl*65 + lane] = (v-mean)*rs*g[lane] + b[lane];
    }
  }
  __syncthreads();
  int px_l = tid & 63;
  int og = __builtin_amdgcn_readfirstlane(tid >> 6);
  int o0 = oq*32 + og*8;
  f2 acc[4];
  #pragma unroll
  for (int oi=0;oi<4;++oi){ acc[oi].x=0.f; acc[oi].y=0.f; }
  for (int c=0;c<64;++c){
    float xv = xn_s[px_l*65 + c];
    #pragma unroll
    for (int oi=0;oi<4;++oi)
      acc[oi] = fma2(mkf2(W[(o0+2*oi)*64 + c], W[(o0+2*oi+1)*64 + c]), xv, acc[oi]);
  }
  int p = p0 + px_l;
  if (oq < 4){
    #pragma unroll
    for (int oi=0;oi<4;++oi){
      xc[((size_t)s*DIC + o0 + 2*oi)*L2 + p]   = acc[oi].x;
      xc[((size_t)s*DIC + o0 + 2*oi+1)*L2 + p] = acc[oi].y;
    }
  } else {
    #pragma unroll
    for (int oi=0;oi<4;++oi){
      z_t[((size_t)s*DIC + (o0-128) + 2*oi)*L2 + p]   = acc[oi].x;
      z_t[((size_t)s*DIC + (o0-128) + 2*oi+1)*L2 + p] = acc[oi].y;
    }
  }
}

// ---------------- k8: x_proj + INLINE depthwise 3x3 + SiLU (packed GEMM 4x f2 + 1 scalar)
__global__ __launch_bounds__(256) void k_xproj_dt(const float* __restrict__ xc,
    const float* __restrict__ dww, const float* __restrict__ dwb,
    const float* __restrict__ W,
    float* __restrict__ dtr, float* __restrict__ Bp, float* __restrict__ Cp,
    float* __restrict__ u_t){
  __shared__ float smem[128*68];
  int bx = blockIdx.x; int pg = bx & 15; int sk = bx >> 4;
  int k = sk & 3; int s = sk >> 2;
  int tid = threadIdx.x;
  for (int i = tid; i < 128*16; i += 256){
    int dr = i>>4; int j4 = (i&15)*4;
    int rw = j4>>5; int col0 = j4 & 31;
    int gr = pg*2 + rw;
    int q = i&7;
    const float* xr = xc + ((size_t)s*DIC+dr)*L2;
    const float* wp = dww + dr*9;
    float bv = dwb[dr];
    float4 acc = make_float4(bv,bv,bv,bv);
    #pragma unroll
    for (int dy=-1;dy<=1;++dy){
      int r = gr+dy;
      float4 mid = make_float4(0.f,0.f,0.f,0.f);
      if (0<=r && r<32) mid = *(const float4*)(xr + r*32 + col0);
      float lf = __shfl_up(mid.w,1,64); if(q==0) lf=0.f;
      float rt = __shfl_down(mid.x,1,64); if(q==7) rt=0.f;
      float w0=wp[(dy+1)*3], w1=wp[(dy+1)*3+1], w2=wp[(dy+1)*3+2];
      acc.x = fmaf(w0,lf,   fmaf(w1,mid.x, fmaf(w2,mid.y, acc.x)));
      acc.y = fmaf(w0,mid.x,fmaf(w1,mid.y, fmaf(w2,mid.z, acc.y)));
      acc.z = fmaf(w0,mid.y,fmaf(w1,mid.z, fmaf(w2,mid.w, acc.z)));
      acc.w = fmaf(w0,mid.z,fmaf(w1,mid.w, fmaf(w2,rt,    acc.w)));
    }
    acc.x = fsilu(acc.x); acc.y = fsilu(acc.y); acc.z = fsilu(acc.z); acc.w = fsilu(acc.w);
    *(float4*)&smem[dr*68 + j4] = acc;
  }
  __syncthreads();
  if (k == 0){
    float* ub = u_t + ((size_t)(s*L2) + pg*64)*DIC;
    for (int i = tid; i < 64*128; i += 256){
      int px2 = i>>7; int dd = i&127;
      ub[(size_t)px2*DIC + dd] = smem[dd*68 + px2];
    }
  }
  int px = tid & 63;
  int cgrp = __builtin_amdgcn_readfirstlane(tid >> 6);
  int c0 = cgrp*9;
  const float* wb = W + (size_t)(k*36 + c0)*DIC;
  f2 acc2[4]; float acc8 = 0.f;
  #pragma unroll
  for (int ci=0;ci<4;++ci){ acc2[ci].x=0.f; acc2[ci].y=0.f; }
  for (int d=0; d<DIC; ++d){
    float xv = smem[d*68 + px];
    #pragma unroll
    for (int ci=0;ci<4;++ci)
      acc2[ci] = fma2(mkf2(wb[(2*ci)*DIC+d], wb[(2*ci+1)*DIC+d]), xv, acc2[ci]);
    acc8 = fmaf(wb[8*DIC+d], xv, acc8);
  }
  __syncthreads();
  #pragma unroll
  for (int ci=0;ci<4;++ci){
    smem[(c0+2*ci)*68 + px]   = acc2[ci].x;
    smem[(c0+2*ci+1)*68 + px] = acc2[ci].y;
  }
  smem[(c0+8)*68 + px] = acc8;
  __syncthreads();
  {
    int pp = tid >> 2; int r = tid & 3;
    dtr[((size_t)sk*L2 + pg*64 + pp)*4 + r] = smem[r*68 + pp];
  }
  float* Bb = Bp + ((size_t)sk*L2 + pg*64)*NST;
  float* Cb = Cp + ((size_t)sk*L2 + pg*64)*NST;
  for (int i = tid; i < 1024; i += 256){
    int pp = i>>4; int n = i&15;
    Bb[pp*NST + n] = smem[(4+n)*68 + pp];
    Cb[pp*NST + n] = smem[(20+n)*68 + pp];
  }
}

// scan pixel for direction k, chunk ch (32 steps), step j
__device__ __forceinline__ int scan_pix32(int ch, int j, int k){
  if (k==0) return ch*32 + j;
  if (k==1) return j*32 + ch;
  if (k==2) return 1023 - (ch*32 + j);
  return 1023 - (j*32 + ch);
}

// half-state step (8 of 16 SSM states per thread)
struct StepH { float4 dt4; float uv; float4 B0,B1; };
__device__ __forceinline__ StepH loadH(const float* dr, const float* ub, const float* Bb, int p){
  StepH r;
  r.dt4 = *(const float4*)(dr + (size_t)p*4);
  r.uv = ub[(size_t)p*DIC];
  const float* bp = Bb + p*NST;   // Bb pre-offset by nh*8
  r.B0 = *(const float4*)bp; r.B1 = *(const float4*)(bp+4);
  return r;
}
__device__ __forceinline__ float dt_eval(float4 w4, float bb, float4 d4){
  return fsoftplus(fmaf(w4.x,d4.x,fmaf(w4.y,d4.y,fmaf(w4.z,d4.z,fmaf(w4.w,d4.w,bb)))));
}

// check: aco[n] == (gbase+n+1)*acoR for all local n (A = -(n+1) structure)
__device__ __forceinline__ bool aco_linear(const float* aco, float acoR, int gbase){
  bool ok = true;
  #pragma unroll
  for (int n=0;n<8;++n){
    float ideal = (float)(gbase+n+1) * acoR;
    ok = ok && (fabsf(aco[n]-ideal) <= 1e-5f*fabsf(ideal) + 1e-12f);
  }
  return ok;
}

// ---------------- k9: scan pass 1, n-split, 768 blocks
__global__ __launch_bounds__(256,4) void k_scan_part3(const float* __restrict__ dtr,
    const float* __restrict__ dtw, const float* __restrict__ dtb,
    const float* __restrict__ u_t, const float* __restrict__ Bp,
    const float* __restrict__ A_logs, float* __restrict__ hend, float* __restrict__ Ssum){
  int bx = blockIdx.x; int ch = bx & 31; int sk = bx >> 5;
  int k = sk & 3; int s = sk >> 2;
  int tid = threadIdx.x; int d = tid >> 1; int nh = tid & 1;
  float aco[8];
  float acoR = -LOG2E * fexp(A_logs[(size_t)(k*DIC+d)*NST]);
  {
    const float* ab = A_logs + (size_t)(k*DIC+d)*NST + nh*8;
    #pragma unroll
    for (int n=0;n<8;++n) aco[n] = -LOG2E * fexp(ab[n]);
  }
  bool fast = aco_linear(aco, acoR, nh*8);
  float aco0 = aco[0];
  float4 w4 = *(const float4*)(dtw + (size_t)(k*DIC+d)*4);
  float bb = dtb[k*DIC+d];
  float h[8]; float Sacc = 0.f;
  #pragma unroll
  for (int n=0;n<8;++n) h[n]=0.f;
  const float* dr = dtr + (size_t)sk*L2*4;
  const float* ub = u_t + (size_t)s*L2*DIC + d;
  const float* Bb = Bp + (size_t)sk*L2*NST + nh*8;
  StepH cur = loadH(dr, ub, Bb, scan_pix32(ch, 0, k));
  if (fast){
    #pragma unroll 4
    for (int j=0;j<32;++j){
      StepH nxt;
      if (j < 31) nxt = loadH(dr, ub, Bb, scan_pix32(ch, j+1, k));
      float dtv = dt_eval(w4, bb, cur.dt4);
      Sacc += dtv;
      float tv = dtv*cur.uv;
      float rr = __builtin_amdgcn_exp2f(dtv*acoR);
      float a_ = __builtin_amdgcn_exp2f(dtv*aco0);
      h[0] = fmaf(a_, h[0], tv*cur.B0.x);
      a_ *= rr; h[1] = fmaf(a_, h[1], tv*cur.B0.y);
      a_ *= rr; h[2] = fmaf(a_, h[2], tv*cur.B0.z);
      a_ *= rr; h[3] = fmaf(a_, h[3], tv*cur.B0.w);
      a_ *= rr; h[4] = fmaf(a_, h[4], tv*cur.B1.x);
      a_ *= rr; h[5] = fmaf(a_, h[5], tv*cur.B1.y);
      a_ *= rr; h[6] = fmaf(a_, h[6], tv*cur.B1.z);
      a_ *= rr; h[7] = fmaf(a_, h[7], tv*cur.B1.w);
      cur = nxt;
    }
  } else {
    #pragma unroll 4
    for (int j=0;j<32;++j){
      StepH nxt;
      if (j < 31) nxt = loadH(dr, ub, Bb, scan_pix32(ch, j+1, k));
      float dtv = dt_eval(w4, bb, cur.dt4);
      Sacc += dtv;
      float tv = dtv*cur.uv;
      #define PSTEP(NI, BV) { float a_ = __builtin_amdgcn_exp2f(dtv*aco[NI]); \
        h[NI] = fmaf(a_, h[NI], tv*(BV)); }
      PSTEP(0,cur.B0.x) PSTEP(1,cur.B0.y) PSTEP(2,cur.B0.z) PSTEP(3,cur.B0.w)
      PSTEP(4,cur.B1.x) PSTEP(5,cur.B1.y) PSTEP(6,cur.B1.z) PSTEP(7,cur.B1.w)
      #undef PSTEP
      cur = nxt;
    }
  }
  size_t base = ((size_t)(sk*NCH + ch)*DIC + d)*NST + nh*8;
  *(float4*)(hend + base)     = make_float4(h[0],h[1],h[2],h[3]);
  *(float4*)(hend + base + 4) = make_float4(h[4],h[5],h[6],h[7]);
  if (nh == 0) Ssum[(size_t)(sk*NCH + ch)*DIC + d] = Sacc;
}

// ---------------- k10: serial chunk prefix
__global__ __launch_bounds__(256) void k_scan_fix3(const float* __restrict__ hend,
    const float* __restrict__ Ssum, const float* __restrict__ A_logs,
    float* __restrict__ Hin){
  int t = blockIdx.x*256 + threadIdx.x;
  int n = t & 15; int d = (t>>4) & 127; int sk = t >> 11; int k = sk & 3;
  float aco = -LOG2E * fexp(A_logs[(size_t)(k*DIC+d)*NST + n]);
  float H = 0.f;
  #pragma unroll 8
  for (int ch=0; ch<NCH; ++ch){
    size_t sidx = (size_t)(sk*NCH + ch)*DIC + d;
    float pa = __builtin_amdgcn_exp2f(aco * Ssum[sidx]);
    float he = hend[sidx*NST + n];
    Hin[sidx*NST + n] = H;
    H = fmaf(pa, H, he);
  }
}

// ---------------- k11: full scan + y output, n-split, 768 blocks
__global__ __launch_bounds__(256,4) void k_scan_y3(const float* __restrict__ dtr,
    const float* __restrict__ dtw, const float* __restrict__ dtb,
    const float* __restrict__ u_t, const float* __restrict__ Bp, const float* __restrict__ Cp,
    const float* __restrict__ A_logs, const float* __restrict__ Ds,
    const float* __restrict__ Hin, float* __restrict__ ys_t){
  int bx = blockIdx.x; int ch = bx & 31; int sk = bx >> 5;
  int k = sk & 3; int s = sk >> 2;
  int tid = threadIdx.x; int d = tid >> 1; int nh = tid & 1;
  float aco[8];
  float acoR = -LOG2E * fexp(A_logs[(size_t)(k*DIC+d)*NST]);
  {
    const float* ab = A_logs + (size_t)(k*DIC+d)*NST + nh*8;
    #pragma unroll
    for (int n=0;n<8;++n) aco[n] = -LOG2E * fexp(ab[n]);
  }
  bool fast = aco_linear(aco, acoR, nh*8);
  float aco0 = aco[0];
  float4 w4 = *(const float4*)(dtw + (size_t)(k*DIC+d)*4);
  float bb = dtb[k*DIC+d];
  float Dv = Ds[k*DIC+d];
  float h[8];
  size_t hbase = ((size_t)(sk*NCH + ch)*DIC + d)*NST + nh*8;
  {
    float4 h0 = *(const float4*)(Hin + hbase);
    float4 h1 = *(const float4*)(Hin + hbase + 4);
    h[0]=h0.x; h[1]=h0.y; h[2]=h0.z; h[3]=h0.w;
    h[4]=h1.x; h[5]=h1.y; h[6]=h1.z; h[7]=h1.w;
  }
  const float* dr = dtr + (size_t)sk*L2*4;
  const float* ub = u_t + (size_t)s*L2*DIC + d;
  const float* Bb = Bp + (size_t)sk*L2*NST + nh*8;
  const float* Cb = Cp + (size_t)sk*L2*NST + nh*8;
  float* yb = ys_t + (size_t)sk*L2*DIC + d;
  int pcur = scan_pix32(ch, 0, k);
  StepH cur = loadH(dr, ub, Bb, pcur);
  float4 Cc0 = *(const float4*)(Cb + pcur*NST);
  float4 Cc1 = *(const float4*)(Cb + pcur*NST + 4);
  if (fast){
    #pragma unroll 4
    for (int j=0;j<32;++j){
      StepH nxt; float4 Cn0, Cn1; int pn = pcur;
      if (j < 31){
        pn = scan_pix32(ch, j+1, k);
        nxt = loadH(dr, ub, Bb, pn);
        Cn0 = *(const float4*)(Cb + pn*NST);
        Cn1 = *(const float4*)(Cb + pn*NST + 4);
      }
      float dtv = dt_eval(w4, bb, cur.dt4);
      float tv = dtv*cur.uv;
      float y0=0.f, y1=0.f, y2=0.f, y3=0.f;
      float rr = __builtin_amdgcn_exp2f(dtv*acoR);
      float a_ = __builtin_amdgcn_exp2f(dtv*aco0);
      h[0] = fmaf(a_, h[0], tv*cur.B0.x); y0 = fmaf(h[0], Cc0.x, y0);
      a_ *= rr; h[1] = fmaf(a_, h[1], tv*cur.B0.y); y1 = fmaf(h[1], Cc0.y, y1);
      a_ *= rr; h[2] = fmaf(a_, h[2], tv*cur.B0.z); y2 = fmaf(h[2], Cc0.z, y2);
      a_ *= rr; h[3] = fmaf(a_, h[3], tv*cur.B0.w); y3 = fmaf(h[3], Cc0.w, y3);
      a_ *= rr; h[4] = fmaf(a_, h[4], tv*cur.B1.x); y0 = fmaf(h[4], Cc1.x, y0);
      a_ *= rr; h[5] = fmaf(a_, h[5], tv*cur.B1.y); y1 = fmaf(h[5], Cc1.y, y1);
      a_ *= rr; h[6] = fmaf(a_, h[6], tv*cur.B1.z); y2 = fmaf(h[6], Cc1.z, y2);
      a_ *= rr; h[7] = fmaf(a_, h[7], tv*cur.B1.w); y3 = fmaf(h[7], Cc1.w, y3);
      float py = (y0+y1)+(y2+y3);
      float tot = py + __shfl_xor(py, 1, 64);
      if (nh == 0) yb[(size_t)pcur*DIC] = fmaf(cur.uv, Dv, tot);
      cur = nxt; Cc0 = Cn0; Cc1 = Cn1; pcur = pn;
    }
  } else {
    #pragma unroll 4
    for (int j=0;j<32;++j){
      StepH nxt; float4 Cn0, Cn1; int pn = pcur;
      if (j < 31){
        pn = scan_pix32(ch, j+1, k);
        nxt = loadH(dr, ub, Bb, pn);
        Cn0 = *(const float4*)(Cb + pn*NST);
        Cn1 = *(const float4*)(Cb + pn*NST + 4);
      }
      float dtv = dt_eval(w4, bb, cur.dt4);
      float tv = dtv*cur.uv;
      float y0=0.f, y1=0.f, y2=0.f, y3=0.f;
      #define YSTEP(NI, BV, CV, YA) { float a_ = __builtin_amdgcn_exp2f(dtv*aco[NI]); \
        h[NI] = fmaf(a_, h[NI], tv*(BV)); YA = fmaf(h[NI], (CV), YA); }
      YSTEP(0,cur.B0.x,Cc0.x,y0) YSTEP(1,cur.B0.y,Cc0.y,y1) YSTEP(2,cur.B0.z,Cc0.z,y2) YSTEP(3,cur.B0.w,Cc0.w,y3)
      YSTEP(4,cur.B1.x,Cc1.x,y0) YSTEP(5,cur.B1.y,Cc1.y,y1) YSTEP(6,cur.B1.z,Cc1.z,y2) YSTEP(7,cur.B1.w,Cc1.w,y3)
      #undef YSTEP
      float py = (y0+y1)+(y2+y3);
      float tot = py + __shfl_xor(py, 1, 64);
      if (nh == 0) yb[(size_t)pcur*DIC] = fmaf(cur.uv, Dv, tot);
      cur = nxt; Cc0 = Cn0; Cc1 = Cn1; pcur = pn;
    }
  }
}

// ---------------- k12: fused tail, 8 px per block, 768 blocks, packed GEMMs
__global__ __launch_bounds__(256) void k_tail(const float* __restrict__ ys_t,
    const float* __restrict__ z_t, const float* __restrict__ ong, const float* __restrict__ onb,
    const float* __restrict__ Wop, const float* __restrict__ x_cmaj,
    const float* __restrict__ g2, const float* __restrict__ b2n,
    const float* __restrict__ w1, const float* __restrict__ b1,
    const float* __restrict__ w2, const float* __restrict__ b2,
    float* __restrict__ out){
  __shared__ float yt[128*9];
  __shared__ float xvt[64*9];
  __shared__ float ts[64*9];
  int s = blockIdx.x >> 7; int pg = blockIdx.x & 127;
  int tid = threadIdx.x;
  {
    int wv = __builtin_amdgcn_readfirstlane(tid>>6); int lane = tid&63;
    int d0 = lane, d1 = lane+64;
    for (int i=0;i<2;++i){
      int px = i*4 + wv; int p = pg*8 + px;
      const float* yb = ys_t + ((size_t)(s*4)*L2 + p)*DIC;
      float ya = yb[d0] + yb[(size_t)L2*DIC + d0] + yb[(size_t)2*L2*DIC + d0] + yb[(size_t)3*L2*DIC + d0];
      float yc = yb[d1] + yb[(size_t)L2*DIC + d1] + yb[(size_t)2*L2*DIC + d1] + yb[(size_t)3*L2*DIC + d1];
      float sm = ya+yc, sq = ya*ya+yc*yc;
      for (int m=1;m<64;m<<=1){ sm+=__shfl_xor(sm,m,64); sq+=__shfl_xor(sq,m,64); }
      float mean = sm*(1.f/128.f); float var = sq*(1.f/128.f)-mean*mean;
      float rs = rsqrtf(var + 1e-5f);
      float yn0 = (ya-mean)*rs*ong[d0] + onb[d0];
      float yn1 = (yc-mean)*rs*ong[d1] + onb[d1];
      float zv0 = z_t[((size_t)s*DIC+d0)*L2 + p];
      float zv1 = z_t[((size_t)s*DIC+d1)*L2 + p];
      yt[d0*9 + px] = yn0 * fsilu(zv0);
      yt[d1*9 + px] = yn1 * fsilu(zv1);
    }
  }
  __syncthreads();
  {
    int px = tid & 7; int cgp = tid >> 3;
    int c0 = cgp*2;
    f2 A; A.x=0.f; A.y=0.f;
    for (int d=0; d<DIC; ++d){
      float yv = yt[d*9 + px];
      A = fma2(mkf2(Wop[(c0+0)*DIC + d], Wop[(c0+1)*DIC + d]), yv, A);
    }
    int p = pg*8 + px;
    size_t base = ((size_t)s*CCH + c0)*L2 + p;
    xvt[(c0+0)*9 + px] = x_cmaj[base]    + A.x;
    xvt[(c0+1)*9 + px] = x_cmaj[base+L2] + A.y;
  }
  __syncthreads();
  int px = tid & 7; int cgp = tid >> 3;
  float sm=0.f, sq=0.f;
  for (int c=0;c<64;++c){ float v = xvt[c*9+px]; sm+=v; sq+=v*v; }
  float mean = sm*(1.f/64.f);
  float rs = rsqrtf(sq*(1.f/64.f) - mean*mean + 1e-5f);
  int o0 = cgp*2;
  f2 T = mkf2(b1[o0], b1[o0+1]);
  for (int c=0;c<64;++c){
    float xn = (xvt[c*9+px]-mean)*rs*g2[c] + b2n[c];
    T = fma2(mkf2(w1[(o0+0)*64 + c], w1[(o0+1)*64 + c]), xn, T);
  }
  ts[(o0+0)*9 + px] = fgelu(T.x);
  ts[(o0+1)*9 + px] = fgelu(T.y);
  __syncthreads();
  int c0 = cgp*2;
  f2 ACC = mkf2(xvt[(c0+0)*9+px] + b2[c0+0], xvt[(c0+1)*9+px] + b2[c0+1]);
  for (int o=0;o<64;++o){
    float tv = ts[o*9+px];
    ACC = fma2(mkf2(w2[(c0+0)*64 + o], w2[(c0+1)*64 + o]), tv, ACC);
  }
  int p = pg*8 + px;
  out[((size_t)s*CCH + c0+0)*L2 + p] = ACC.x;
  out[((size_t)s*CCH + c0+1)*L2 + p] = ACC.y;
}

extern "C" void kernel_launch(void* const* d_in, const int* in_sizes, int n_in,
                              void* d_out, int out_size, void* d_ws, size_t ws_size,
                              hipStream_t stream){
  (void)in_sizes; (void)n_in; (void)out_size; (void)ws_size;
  const float* img      = (const float*)d_in[0];
  const float* dz       = (const float*)d_in[1];
  const float* sg       = (const float*)d_in[2];
  const float* norm_g   = (const float*)d_in[3];
  const float* norm_b   = (const float*)d_in[4];
  const float* gn1_g    = (const float*)d_in[5];
  const float* gn1_b    = (const float*)d_in[6];
  const float* conv1_w  = (const float*)d_in[7];
  const float* conv1_b  = (const float*)d_in[8];
  const float* gn2_g    = (const float*)d_in[9];
  const float* gn2_b    = (const float*)d_in[10];
  const float* conv2_w  = (const float*)d_in[11];
  const float* conv2_b  = (const float*)d_in[12];
  const float* skip_w   = (const float*)d_in[13];
  const float* skip_b   = (const float*)d_in[14];
  const float* ln1_g    = (const float*)d_in[15];
  const float* ln1_b    = (const float*)d_in[16];
  const float* ln2_g    = (const float*)d_in[17];
  const float* ln2_b    = (const float*)d_in[18];
  const float* in_proj_w= (const float*)d_in[19];
  const float* dwconv_w = (const float*)d_in[20];
  const float* dwconv_b = (const float*)d_in[21];
  const float* x_proj_w = (const float*)d_in[22];
  const float* dt_proj_w= (const float*)d_in[23];
  const float* dt_proj_b= (const float*)d_in[24];
  const float* A_logs   = (const float*)d_in[25];
  const float* Ds       = (const float*)d_in[26];
  const float* out_norm_g = (const float*)d_in[27];
  const float* out_norm_b = (const float*)d_in[28];
  const float* out_proj_w = (const float*)d_in[29];
  const float* fc1_w    = (const float*)d_in[30];
  const float* fc1_b    = (const float*)d_in[31];
  const float* fc2_w    = (const float*)d_in[32];
  const float* fc2_b    = (const float*)d_in[33];

  float* ws = (float*)d_ws;
  float* x3c    = ws;                       // 1,179,648
  float* xact1  = x3c    + 1179648;         // 1,253,376 (padded GN1 act)
  float* h1     = xact1  + 1253376;         // 393,216
  float* xact2  = h1     + 393216;          // 417,792 (padded GN2 act)
  float* xpslot = xact2  + 417792;          // 393,216 (hosts Bp)
  float* x_cmaj = xpslot + 393216;          // 393,216
  float* z_t    = x_cmaj + 393216;          // 786,432
  float* xc     = z_t    + 786432;          // 786,432
  float* cpslot = xc     + 786432;          // 786,432 (hosts Cp)
  float* hole   = cpslot + 786432;          // 884,736 (dtr + Ssum)
  float* scanbuf= hole   + 884736;          // 3,145,728
  float* ys_t   = scanbuf+ 3145728;         // 3,145,728
  float* statsb = ys_t   + 3145728;         // psum1(768) psq1(768) psum2(384) psq2(384)
  float* psum1  = statsb;
  float* psq1   = statsb + 768;
  float* psum2  = statsb + 1536;
  float* psq2   = statsb + 1920;
  // aliases into dead regions (timeline-verified, same as R7):
  float* part1  = scanbuf;          // conv1 partials (12 slots: scanbuf + ys_t[0..4))
  float* part2  = ys_t;             // conv2 partials slots 0-3; skip slots 4,5
  float* hend   = x3c;              // x3c dead after k_gnact1_skip
  float* u_t    = h1;               // h1+xact2 dead after gnact2/conv2
  float* Bp     = xpslot;
  float* Cp     = cpslot;
  float* dtr    = hole;             // 98,304
  float* Ssum   = hole + 98304;     // 98,304
  float* Hin    = scanbuf;          // part1 dead after reduce1

  k_ln2d<<<768, 256, 0, stream>>>(img, dz, sg, norm_g, norm_b, x3c, psum1, psq1);
  k_gnact1_skip<<<1536, 256, 0, stream>>>(x3c, psum1, psq1, gn1_g, gn1_b, skip_w,
                                          xact1, part2);
  k_conv1_split<<<2304, 256, 0, stream>>>(xact1, conv1_w, part1);
  k_reduce1<<<384, 256, 0, stream>>>(part1, conv1_b, h1, psum2, psq2);
  k_gnact_pad<<<6*CCH, 256, 0, stream>>>(h1, psum2, psq2, gn2_g, gn2_b, CCH, 64,
                                         1.f/(CCH*L2), 1e-5f, xact2);
  k_conv2_split<<<768, 256, 0, stream>>>(xact2, conv2_w, part2);
  k_red2_ln1_inproj<<<768, 256, 0, stream>>>(part2, conv2_b, skip_b, ln1_g, ln1_b, in_proj_w,
                                             x_cmaj, xc, z_t);
  k_xproj_dt<<<384, 256, 0, stream>>>(xc, dwconv_w, dwconv_b, x_proj_w, dtr, Bp, Cp, u_t);
  k_scan_part3<<<768, 256, 0, stream>>>(dtr, dt_proj_w, dt_proj_b, u_t, Bp, A_logs, hend, Ssum);
  k_scan_fix3<<<192, 256, 0, stream>>>(hend, Ssum, A_logs, Hin);
  k_scan_y3<<<768, 256, 0, stream>>>(dtr, dt_proj_w, dt_proj_b, u_t, Bp, Cp, A_logs, Ds, Hin, ys_t);
  k_tail<<<768, 256, 0, stream>>>(ys_t, z_t, out_norm_g, out_norm_b, out_proj_w, x_cmaj,
                                  ln2_g, ln2_b, fc1_w, fc1_b, fc2_w, fc2_b, (float*)d_out);
}

// Round 9
// 284.720 us; speedup vs baseline: 2.8775x; 1.0057x over previous
//
#include <hip/hip_runtime.h>
#include <math.h>

// Problem dims
#define BL    6
#define CCH   64
#define C3    192
#define L2    1024
#define DIC   128
#define NST   16
#define K4    4
#define PSTR  1088   // padded plane stride: 34 rows * 32 cols
#define NCH   32     // scan chunks per sequence (32 steps each)

#define LOG2E 1.44269504088896340736f
#define LN2C  0.69314718055994530942f

typedef float f2 __attribute__((ext_vector_type(2)));
__device__ __forceinline__ f2 mkf2(float a, float b){ f2 r; r.x=a; r.y=b; return r; }
__device__ __forceinline__ f2 fma2(f2 a, float b, f2 c){
  f2 bb; bb.x=b; bb.y=b;
  return __builtin_elementwise_fma(a, bb, c);
}

__device__ __forceinline__ float fexp(float x){ return __builtin_amdgcn_exp2f(x*LOG2E); }
__device__ __forceinline__ float fsilu(float x){ return x * __builtin_amdgcn_rcpf(1.f + fexp(-x)); }
__device__ __forceinline__ float fsoftplus(float x){
  if (x > 20.f) return x;
  return __builtin_amdgcn_logf(1.f + fexp(x)) * LN2C;
}
__device__ __forceinline__ float fgelu(float x){
  return 0.5f*x*(1.f + erff(x*0.70710678118654752440f));
}

// ---------------- k1: per-pixel LN + concat; GN1 partials. 768 blocks (8 px each).
__global__ __launch_bounds__(256) void k_ln2d(const float* __restrict__ img,
    const float* __restrict__ dz, const float* __restrict__ sg,
    const float* __restrict__ g, const float* __restrict__ b, float* __restrict__ x3c,
    float* __restrict__ psum1, float* __restrict__ psq1){
  __shared__ float ps[4][8], pq[4][8], gs[4], gq[4];
  int s = blockIdx.x >> 7;
  int pg = blockIdx.x & 127;
  int tid = threadIdx.x;
  int px = tid & 7; int cg = tid >> 3;
  int wv = tid >> 6; int lane = tid & 63;
  int p = pg*8 + px;
  int bsmp = s/3;
  const float* fr = img + (size_t)s*CCH*L2;
  float vals[2]; float sm=0.f, sq=0.f;
  #pragma unroll
  for (int j=0;j<2;++j){
    int c = cg*2 + j;
    float v = fr[c*L2 + p];
    vals[j]=v; sm+=v; sq+=v*v;
  }
  sm += __shfl_xor(sm,8,64);  sq += __shfl_xor(sq,8,64);
  sm += __shfl_xor(sm,16,64); sq += __shfl_xor(sq,16,64);
  sm += __shfl_xor(sm,32,64); sq += __shfl_xor(sq,32,64);
  if (lane < 8){ ps[wv][lane]=sm; pq[wv][lane]=sq; }
  __syncthreads();
  sm = ps[0][px]+ps[1][px]+ps[2][px]+ps[3][px];
  sq = pq[0][px]+pq[1][px]+pq[2][px]+pq[3][px];
  float mean = sm*(1.f/CCH); float var = sq*(1.f/CCH)-mean*mean;
  float rs = rsqrtf(var + 1e-6f);
  float* o = x3c + (size_t)s*C3*L2;
  const float* dzp = dz + (size_t)bsmp*CCH*L2;
  const float* sgp = sg + (size_t)bsmp*CCH*L2;
  float gsm=0.f, gsq=0.f;
  #pragma unroll
  for (int j=0;j<2;++j){
    int c = cg*2+j;
    float dzv = dzp[c*L2+p];
    float nv  = (vals[j]-mean)*rs*g[c] + b[c];
    float sgv = sgp[c*L2+p];
    o[c*L2+p] = dzv;
    o[(CCH+c)*L2+p] = nv;
    o[(2*CCH+c)*L2+p] = sgv;
    gsm += dzv+nv+sgv; gsq += dzv*dzv+nv*nv+sgv*sgv;
  }
  for (int m=1;m<64;m<<=1){ gsm+=__shfl_xor(gsm,m,64); gsq+=__shfl_xor(gsq,m,64); }
  if (lane==0){ gs[wv]=gsm; gq[wv]=gsq; }
  __syncthreads();
  if (tid==0){
    psum1[blockIdx.x] = gs[0]+gs[1]+gs[2]+gs[3];
    psq1 [blockIdx.x] = gq[0]+gq[1]+gq[2]+gq[3];
  }
}

// ---------------- k2: MERGED gnact1 (blocks 0..1151) + skip 1x1 (blocks 1152..1535)
__global__ __launch_bounds__(256) void k_gnact1_skip(const float* __restrict__ x3c,
    const float* __restrict__ psum, const float* __restrict__ psq,
    const float* __restrict__ g, const float* __restrict__ b,
    const float* __restrict__ wsk,
    float* __restrict__ xact1, float* __restrict__ part){
  int bx = blockIdx.x;
  int tid = threadIdx.x;
  if (bx < 1152){
    int s = bx / C3; int c = bx % C3;
    float sm=0.f, sq=0.f;
    for (int i=0;i<128;++i){ sm += psum[s*128+i]; sq += psq[s*128+i]; }
    float mean = sm*(1.f/(C3*L2));
    float var = sq*(1.f/(C3*L2)) - mean*mean;
    float rs = rsqrtf(var + 1e-5f);
    float gc = g[c]*rs; float bc = b[c] - mean*rs*g[c];
    float4 v = *(const float4*)(x3c + (size_t)bx*1024 + tid*4);
    float4 o; o.x = fsilu(v.x*gc+bc); o.y = fsilu(v.y*gc+bc);
    o.z = fsilu(v.z*gc+bc); o.w = fsilu(v.w*gc+bc);
    float* pl = xact1 + (size_t)bx*PSTR;
    *(float4*)(pl + 32 + tid*4) = o;
    float4 z4 = make_float4(0.f,0.f,0.f,0.f);
    if (tid < 8)  *(float4*)(pl + tid*4) = z4;
    else if (tid < 16) *(float4*)(pl + 1056 + (tid-8)*4) = z4;
  } else {
    // skip 1x1 (2 roles x 96 ci), packed over co pair
    int t = bx - 1152;
    int role = t & 1; int cop = (t>>1)&31; int s = t >> 6;
    int co0 = cop*2, co1 = co0+1;
    int row = tid>>3; int q = tid&7; int col0 = q*4;
    int p = row*32+col0;
    f2 a[4];
    #pragma unroll
    for (int i=0;i<4;++i){ a[i].x=0.f; a[i].y=0.f; }
    int ci0 = role*96;
    const float* x3 = x3c + ((size_t)s*C3 + ci0)*L2 + p;
    const float* w0p = wsk + co0*C3 + ci0;
    const float* w1p = wsk + co1*C3 + ci0;
    #pragma unroll 4
    for (int ci=0; ci<96; ++ci){
      float4 v = *(const float4*)(x3 + (size_t)ci*L2);
      f2 w = mkf2(w0p[ci], w1p[ci]);
      a[0] = fma2(w, v.x, a[0]);
      a[1] = fma2(w, v.y, a[1]);
      a[2] = fma2(w, v.z, a[2]);
      a[3] = fma2(w, v.w, a[3]);
    }
    float* pp = part + (size_t)(4+role)*(BL*CCH*L2) + ((size_t)s*CCH+co0)*L2 + p;
    *(float4*)pp = make_float4(a[0].x,a[1].x,a[2].x,a[3].x);
    *(float4*)(pp+L2) = make_float4(a[0].y,a[1].y,a[2].y,a[3].y);
  }
}

// ---------------- gnact2 (generic)
__global__ __launch_bounds__(256) void k_gnact_pad(const float* __restrict__ x,
    const float* __restrict__ psum, const float* __restrict__ psq,
    const float* __restrict__ g, const float* __restrict__ b,
    int ch, int parts, float inv_n, float eps, float* __restrict__ out){
  int bx = blockIdx.x;
  int s = bx / ch; int c = bx % ch;
  int tid = threadIdx.x;
  float sm=0.f, sq=0.f;
  for (int i=0;i<parts;++i){ sm += psum[s*parts+i]; sq += psq[s*parts+i]; }
  float mean = sm*inv_n;
  float var = sq*inv_n - mean*mean;
  float rs = rsqrtf(var + eps);
  float gc = g[c]*rs; float bc = b[c] - mean*rs*g[c];
  float4 v = *(const float4*)(x + (size_t)bx*1024 + tid*4);
  float4 o; o.x = fsilu(v.x*gc+bc); o.y = fsilu(v.y*gc+bc);
  o.z = fsilu(v.z*gc+bc); o.w = fsilu(v.w*gc+bc);
  float* pl = out + (size_t)bx*PSTR;
  *(float4*)(pl + 32 + tid*4) = o;
  float4 z4 = make_float4(0.f,0.f,0.f,0.f);
  if (tid < 8)  *(float4*)(pl + tid*4) = z4;
  else if (tid < 16) *(float4*)(pl + 1056 + (tid-8)*4) = z4;
}

// packed conv helpers: a[4] = (co0,co1) accumulators per px
__device__ __forceinline__ void conv_row_acc2(f2* a, float4 mid, float lf, float rt,
    const float* wp0, const float* wp1){
  f2 w0 = mkf2(wp0[0],wp1[0]);
  f2 w1 = mkf2(wp0[1],wp1[1]);
  f2 w2 = mkf2(wp0[2],wp1[2]);
  a[0] = fma2(w0,lf,   fma2(w1,mid.x, fma2(w2,mid.y, a[0])));
  a[1] = fma2(w0,mid.x,fma2(w1,mid.y, fma2(w2,mid.z, a[1])));
  a[2] = fma2(w0,mid.y,fma2(w1,mid.z, fma2(w2,mid.w, a[2])));
  a[3] = fma2(w0,mid.z,fma2(w1,mid.w, fma2(w2,rt,    a[3])));
}

__device__ __forceinline__ void conv_ci_body2(float4 m0, float4 m1, float4 m2, int q,
    const float* wp0, const float* wp1, f2* a){
  float lf0=__shfl_up(m0.w,1,64), rt0=__shfl_down(m0.x,1,64);
  float lf1=__shfl_up(m1.w,1,64), rt1=__shfl_down(m1.x,1,64);
  float lf2=__shfl_up(m2.w,1,64), rt2=__shfl_down(m2.x,1,64);
  if (q==0){ lf0=0.f; lf1=0.f; lf2=0.f; }
  if (q==7){ rt0=0.f; rt1=0.f; rt2=0.f; }
  conv_row_acc2(a,m0,lf0,rt0, wp0+0, wp1+0);
  conv_row_acc2(a,m1,lf1,rt1, wp0+3, wp1+3);
  conv_row_acc2(a,m2,lf2,rt2, wp0+6, wp1+6);
}

// ---------------- k3: conv1 192ci->64co, split-K=12 (16 ci each), 2304 blocks
__global__ __launch_bounds__(256) void k_conv1_split(const float* __restrict__ xact,
    const float* __restrict__ w, float* __restrict__ part){
  int bx = blockIdx.x; int kk = bx % 12; int r = bx / 12;
  int cop = r & 31; int s = r >> 5;
  int co0 = cop*2, co1 = co0+1;
  int tid = threadIdx.x; int row = tid>>3; int q = tid&7; int col0 = q*4;
  f2 a[4];
  #pragma unroll
  for (int i=0;i<4;++i){ a[i].x=0.f; a[i].y=0.f; }
  int ci0 = kk*16;
  const float* pl = xact + ((size_t)s*C3 + ci0)*PSTR + row*32 + col0;
  const float* wp0 = w + (size_t)(co0*C3 + ci0)*9;
  const float* wp1 = w + (size_t)(co1*C3 + ci0)*9;
  float4 m0 = *(const float4*)(pl);
  float4 m1 = *(const float4*)(pl+32);
  float4 m2 = *(const float4*)(pl+64);
  #pragma unroll 2
  for (int i=0;i<16;++i){
    const float* pn = pl + (i<15 ? PSTR : 0);
    float4 n0 = *(const float4*)(pn);
    float4 n1 = *(const float4*)(pn+32);
    float4 n2 = *(const float4*)(pn+64);
    conv_ci_body2(m0,m1,m2,q, wp0, wp1, a);
    wp0 += 9; wp1 += 9; pl = pn; m0=n0; m1=n1; m2=n2;
  }
  float* pp = part + (size_t)kk*(BL*CCH*L2) + ((size_t)s*CCH+co0)*L2 + row*32+col0;
  *(float4*)pp = make_float4(a[0].x,a[1].x,a[2].x,a[3].x);
  *(float4*)(pp+L2) = make_float4(a[0].y,a[1].y,a[2].y,a[3].y);
}

// ---------------- k4: reduce conv1 partials (12) + bias -> h1; GN2 partials
__global__ __launch_bounds__(256) void k_reduce1(const float* __restrict__ part,
    const float* __restrict__ bias, float* __restrict__ h1,
    float* __restrict__ psum2, float* __restrict__ psq2){
  int co = blockIdx.x & 63; int s = blockIdx.x >> 6;
  size_t ofs = ((size_t)s*CCH+co)*L2 + threadIdx.x*4;
  const size_t stride = (size_t)BL*CCH*L2;
  float4 acc = *(const float4*)(part + ofs);
  #pragma unroll
  for (int kk=1;kk<12;++kk){
    float4 r = *(const float4*)(part + (size_t)kk*stride + ofs);
    acc.x += r.x; acc.y += r.y; acc.z += r.z; acc.w += r.w;
  }
  float bv = bias[co];
  acc.x += bv; acc.y += bv; acc.z += bv; acc.w += bv;
  *(float4*)(h1 + ofs) = acc;
  float sm = acc.x+acc.y+acc.z+acc.w;
  float sq = acc.x*acc.x+acc.y*acc.y+acc.z*acc.z+acc.w*acc.w;
  for (int m=1;m<64;m<<=1){ sm+=__shfl_xor(sm,m,64); sq+=__shfl_xor(sq,m,64); }
  __shared__ float s_sm[4], s_sq[4];
  int wv = threadIdx.x>>6;
  if ((threadIdx.x&63)==0){ s_sm[wv]=sm; s_sq[wv]=sq; }
  __syncthreads();
  if (threadIdx.x==0){
    psum2[blockIdx.x] = s_sm[0]+s_sm[1]+s_sm[2]+s_sm[3];
    psq2 [blockIdx.x] = s_sq[0]+s_sq[1]+s_sq[2]+s_sq[3];
  }
}

// ---------------- k6: conv2 FOUR roles x 16ci, 768 blocks
__global__ __launch_bounds__(256) void k_conv2_split(const float* __restrict__ xact2,
    const float* __restrict__ w2, float* __restrict__ part){
  int bx = blockIdx.x; int role = bx & 3; int t = bx >> 2;
  int cop = t & 31; int s = t >> 5;
  int co0 = cop*2, co1 = co0+1;
  int tid = threadIdx.x; int row = tid>>3; int q = tid&7; int col0 = q*4;
  int p = row*32+col0;
  f2 a[4];
  #pragma unroll
  for (int i=0;i<4;++i){ a[i].x=0.f; a[i].y=0.f; }
  int ci0 = role*16;
  const float* pl = xact2 + ((size_t)s*CCH + ci0)*PSTR + row*32 + col0;
  const float* wp0 = w2 + (size_t)(co0*CCH + ci0)*9;
  const float* wp1 = w2 + (size_t)(co1*CCH + ci0)*9;
  float4 m0 = *(const float4*)(pl);
  float4 m1 = *(const float4*)(pl+32);
  float4 m2 = *(const float4*)(pl+64);
  #pragma unroll 2
  for (int i=0;i<16;++i){
    const float* pn = pl + (i<15 ? PSTR : 0);
    float4 n0 = *(const float4*)(pn);
    float4 n1 = *(const float4*)(pn+32);
    float4 n2 = *(const float4*)(pn+64);
    conv_ci_body2(m0,m1,m2,q, wp0, wp1, a);
    wp0 += 9; wp1 += 9; pl = pn; m0=n0; m1=n1; m2=n2;
  }
  float* pp = part + (size_t)role*(BL*CCH*L2) + ((size_t)s*CCH+co0)*L2 + p;
  *(float4*)pp = make_float4(a[0].x,a[1].x,a[2].x,a[3].x);
  *(float4*)(pp+L2) = make_float4(a[0].y,a[1].y,a[2].y,a[3].y);
}

// ---------------- k7: reduce2(6 slots) + ln1 + in_proj fused, oq split x8, packed GEMM
__global__ __launch_bounds__(256) void k_red2_ln1_inproj(const float* __restrict__ part,
    const float* __restrict__ b2, const float* __restrict__ bsk,
    const float* __restrict__ g, const float* __restrict__ b,
    const float* __restrict__ W,
    float* __restrict__ x_cmaj, float* __restrict__ xc, float* __restrict__ z_t){
  __shared__ float xn_s[64*65];
  int bx = blockIdx.x; int oq = bx & 7; int pg = (bx>>3)&15; int s = bx>>7;
  int p0 = pg*64;
  int tid = threadIdx.x;
  const size_t stride = (size_t)BL*CCH*L2;
  #pragma unroll
  for (int kq=0;kq<4;++kq){
    int f = kq*256 + tid;
    int co = f >> 4; int px4 = (f & 15)*4;
    size_t ofs = ((size_t)s*CCH+co)*L2 + p0 + px4;
    float4 r0 = *(const float4*)(part + ofs);
    float4 r1 = *(const float4*)(part + stride + ofs);
    float4 r2 = *(const float4*)(part + 2*stride + ofs);
    float4 r3 = *(const float4*)(part + 3*stride + ofs);
    float4 r4 = *(const float4*)(part + 4*stride + ofs);
    float4 r5 = *(const float4*)(part + 5*stride + ofs);
    float bv = b2[co]+bsk[co];
    float4 o;
    o.x = ((r0.x+r1.x)+(r2.x+r3.x))+(r4.x+r5.x)+bv;
    o.y = ((r0.y+r1.y)+(r2.y+r3.y))+(r4.y+r5.y)+bv;
    o.z = ((r0.z+r1.z)+(r2.z+r3.z))+(r4.z+r5.z)+bv;
    o.w = ((r0.w+r1.w)+(r2.w+r3.w))+(r4.w+r5.w)+bv;
    if (oq == 0) *(float4*)(x_cmaj + ofs) = o;
    xn_s[(px4+0)*65 + co] = o.x;
    xn_s[(px4+1)*65 + co] = o.y;
    xn_s[(px4+2)*65 + co] = o.z;
    xn_s[(px4+3)*65 + co] = o.w;
  }
  __syncthreads();
  {
    int wv = __builtin_amdgcn_readfirstlane(tid>>6); int lane = tid&63;
    for (int j=0;j<16;++j){
      int pl = wv*16 + j;
      float v = xn_s[pl*65 + lane];
      float sm = v, sq = v*v;
      for (int m=1;m<64;m<<=1){ sm += __shfl_xor(sm,m,64); sq += __shfl_xor(sq,m,64); }
      float mean = sm*(1.f/64.f); float var = sq*(1.f/64.f) - mean*mean;
      float rs = rsqrtf(var + 1e-5f);
      xn_s[pl*65 + lane] = (v-mean)*rs*g[lane] + b[lane];
    }
  }
  __syncthreads();
  int px_l = tid & 63;
  int og = __builtin_amdgcn_readfirstlane(tid >> 6);
  int o0 = oq*32 + og*8;
  f2 acc[4];
  #pragma unroll
  for (int oi=0;oi<4;++oi){ acc[oi].x=0.f; acc[oi].y=0.f; }
  for (int c=0;c<64;++c){
    float xv = xn_s[px_l*65 + c];
    #pragma unroll
    for (int oi=0;oi<4;++oi)
      acc[oi] = fma2(mkf2(W[(o0+2*oi)*64 + c], W[(o0+2*oi+1)*64 + c]), xv, acc[oi]);
  }
  int p = p0 + px_l;
  if (oq < 4){
    #pragma unroll
    for (int oi=0;oi<4;++oi){
      xc[((size_t)s*DIC + o0 + 2*oi)*L2 + p]   = acc[oi].x;
      xc[((size_t)s*DIC + o0 + 2*oi+1)*L2 + p] = acc[oi].y;
    }
  } else {
    #pragma unroll
    for (int oi=0;oi<4;++oi){
      z_t[((size_t)s*DIC + (o0-128) + 2*oi)*L2 + p]   = acc[oi].x;
      z_t[((size_t)s*DIC + (o0-128) + 2*oi+1)*L2 + p] = acc[oi].y;
    }
  }
}

// ---------------- k8: x_proj + INLINE depthwise 3x3 + SiLU — HALF-SPLIT, 768 blocks
// half0: dt ranks (rows 0-3) + B (rows 4-19), 5 outputs/thread
// half1: C (rows 20-35), 4 outputs/thread, + u_t write (k==0)
__global__ __launch_bounds__(256) void k_xproj_dt(const float* __restrict__ xc,
    const float* __restrict__ dww, const float* __restrict__ dwb,
    const float* __restrict__ W,
    float* __restrict__ dtr, float* __restrict__ Bp, float* __restrict__ Cp,
    float* __restrict__ u_t){
  __shared__ float smem[128*68];
  int bx = blockIdx.x; int half = bx & 1; int pg = (bx>>1) & 15; int sk = bx >> 5;
  int k = sk & 3; int s = sk >> 2;
  int tid = threadIdx.x;
  // dwconv+silu into smem (both halves duplicate this cheap fill)
  for (int i = tid; i < 128*16; i += 256){
    int dr = i>>4; int j4 = (i&15)*4;
    int rw = j4>>5; int col0 = j4 & 31;
    int gr = pg*2 + rw;
    int q = i&7;
    const float* xr = xc + ((size_t)s*DIC+dr)*L2;
    const float* wp = dww + dr*9;
    float bv = dwb[dr];
    float4 acc = make_float4(bv,bv,bv,bv);
    #pragma unroll
    for (int dy=-1;dy<=1;++dy){
      int r = gr+dy;
      float4 mid = make_float4(0.f,0.f,0.f,0.f);
      if (0<=r && r<32) mid = *(const float4*)(xr + r*32 + col0);
      float lf = __shfl_up(mid.w,1,64); if(q==0) lf=0.f;
      float rt = __shfl_down(mid.x,1,64); if(q==7) rt=0.f;
      float w0=wp[(dy+1)*3], w1=wp[(dy+1)*3+1], w2=wp[(dy+1)*3+2];
      acc.x = fmaf(w0,lf,   fmaf(w1,mid.x, fmaf(w2,mid.y, acc.x)));
      acc.y = fmaf(w0,mid.x,fmaf(w1,mid.y, fmaf(w2,mid.z, acc.y)));
      acc.z = fmaf(w0,mid.y,fmaf(w1,mid.z, fmaf(w2,mid.w, acc.z)));
      acc.w = fmaf(w0,mid.z,fmaf(w1,mid.w, fmaf(w2,rt,    acc.w)));
    }
    acc.x = fsilu(acc.x); acc.y = fsilu(acc.y); acc.z = fsilu(acc.z); acc.w = fsilu(acc.w);
    *(float4*)&smem[dr*68 + j4] = acc;
  }
  __syncthreads();
  int px = tid & 63;
  int cgrp = __builtin_amdgcn_readfirstlane(tid >> 6);
  if (half == 1){
    if (k == 0){
      float* ub = u_t + ((size_t)(s*L2) + pg*64)*DIC;
      for (int i = tid; i < 64*128; i += 256){
        int px2 = i>>7; int dd = i&127;
        ub[(size_t)px2*DIC + dd] = smem[dd*68 + px2];
      }
    }
    // C rows: c0 = 20 + cgrp*4
    int c0 = 20 + cgrp*4;
    const float* wb = W + (size_t)(k*36 + c0)*DIC;
    f2 acc2[2];
    acc2[0].x=0.f; acc2[0].y=0.f; acc2[1].x=0.f; acc2[1].y=0.f;
    for (int d=0; d<DIC; ++d){
      float xv = smem[d*68 + px];
      acc2[0] = fma2(mkf2(wb[0*DIC+d], wb[1*DIC+d]), xv, acc2[0]);
      acc2[1] = fma2(mkf2(wb[2*DIC+d], wb[3*DIC+d]), xv, acc2[1]);
    }
    __syncthreads();
    smem[(c0+0)*68 + px] = acc2[0].x;
    smem[(c0+1)*68 + px] = acc2[0].y;
    smem[(c0+2)*68 + px] = acc2[1].x;
    smem[(c0+3)*68 + px] = acc2[1].y;
    __syncthreads();
    float* Cb = Cp + ((size_t)sk*L2 + pg*64)*NST;
    for (int i = tid; i < 1024; i += 256){
      int pp = i>>4; int n = i&15;
      Cb[pp*NST + n] = smem[(20+n)*68 + pp];
    }
  } else {
    // dt + B rows: c0 = cgrp*5, 5 outputs
    int c0 = cgrp*5;
    const float* wb = W + (size_t)(k*36 + c0)*DIC;
    f2 acc2[2]; float acc4 = 0.f;
    acc2[0].x=0.f; acc2[0].y=0.f; acc2[1].x=0.f; acc2[1].y=0.f;
    for (int d=0; d<DIC; ++d){
      float xv = smem[d*68 + px];
      acc2[0] = fma2(mkf2(wb[0*DIC+d], wb[1*DIC+d]), xv, acc2[0]);
      acc2[1] = fma2(mkf2(wb[2*DIC+d], wb[3*DIC+d]), xv, acc2[1]);
      acc4 = fmaf(wb[4*DIC+d], xv, acc4);
    }
    __syncthreads();
    smem[(c0+0)*68 + px] = acc2[0].x;
    smem[(c0+1)*68 + px] = acc2[0].y;
    smem[(c0+2)*68 + px] = acc2[1].x;
    smem[(c0+3)*68 + px] = acc2[1].y;
    smem[(c0+4)*68 + px] = acc4;
    __syncthreads();
    {
      int pp = tid >> 2; int r = tid & 3;
      dtr[((size_t)sk*L2 + pg*64 + pp)*4 + r] = smem[r*68 + pp];
    }
    float* Bb = Bp + ((size_t)sk*L2 + pg*64)*NST;
    for (int i = tid; i < 1024; i += 256){
      int pp = i>>4; int n = i&15;
      Bb[pp*NST + n] = smem[(4+n)*68 + pp];
    }
  }
}

// scan pixel for direction k, chunk ch (32 steps), step j
__device__ __forceinline__ int scan_pix32(int ch, int j, int k){
  if (k==0) return ch*32 + j;
  if (k==1) return j*32 + ch;
  if (k==2) return 1023 - (ch*32 + j);
  return 1023 - (j*32 + ch);
}

// half-state step (8 of 16 SSM states per thread)
struct StepH { float4 dt4; float uv; float4 B0,B1; };
__device__ __forceinline__ StepH loadH(const float* dr, const float* ub, const float* Bb, int p){
  StepH r;
  r.dt4 = *(const float4*)(dr + (size_t)p*4);
  r.uv = ub[(size_t)p*DIC];
  const float* bp = Bb + p*NST;   // Bb pre-offset by nh*8
  r.B0 = *(const float4*)bp; r.B1 = *(const float4*)(bp+4);
  return r;
}
__device__ __forceinline__ float dt_eval(float4 w4, float bb, float4 d4){
  return fsoftplus(fmaf(w4.x,d4.x,fmaf(w4.y,d4.y,fmaf(w4.z,d4.z,fmaf(w4.w,d4.w,bb)))));
}

// check: aco[n] == (gbase+n+1)*acoR for all local n (A = -(n+1) structure)
__device__ __forceinline__ bool aco_linear(const float* aco, float acoR, int gbase){
  bool ok = true;
  #pragma unroll
  for (int n=0;n<8;++n){
    float ideal = (float)(gbase+n+1) * acoR;
    ok = ok && (fabsf(aco[n]-ideal) <= 1e-5f*fabsf(ideal) + 1e-12f);
  }
  return ok;
}

// ---------------- k9: scan pass 1, n-split, 768 blocks
__global__ __launch_bounds__(256,4) void k_scan_part3(const float* __restrict__ dtr,
    const float* __restrict__ dtw, const float* __restrict__ dtb,
    const float* __restrict__ u_t, const float* __restrict__ Bp,
    const float* __restrict__ A_logs, float* __restrict__ hend, float* __restrict__ Ssum){
  int bx = blockIdx.x; int ch = bx & 31; int sk = bx >> 5;
  int k = sk & 3; int s = sk >> 2;
  int tid = threadIdx.x; int d = tid >> 1; int nh = tid & 1;
  float aco[8];
  float acoR = -LOG2E * fexp(A_logs[(size_t)(k*DIC+d)*NST]);
  {
    const float* ab = A_logs + (size_t)(k*DIC+d)*NST + nh*8;
    #pragma unroll
    for (int n=0;n<8;++n) aco[n] = -LOG2E * fexp(ab[n]);
  }
  bool fast = aco_linear(aco, acoR, nh*8);
  float aco0 = aco[0];
  float4 w4 = *(const float4*)(dtw + (size_t)(k*DIC+d)*4);
  float bb = dtb[k*DIC+d];
  float h[8]; float Sacc = 0.f;
  #pragma unroll
  for (int n=0;n<8;++n) h[n]=0.f;
  const float* dr = dtr + (size_t)sk*L2*4;
  const float* ub = u_t + (size_t)s*L2*DIC + d;
  const float* Bb = Bp + (size_t)sk*L2*NST + nh*8;
  StepH cur = loadH(dr, ub, Bb, scan_pix32(ch, 0, k));
  if (fast){
    #pragma unroll 4
    for (int j=0;j<32;++j){
      StepH nxt;
      if (j < 31) nxt = loadH(dr, ub, Bb, scan_pix32(ch, j+1, k));
      float dtv = dt_eval(w4, bb, cur.dt4);
      Sacc += dtv;
      float tv = dtv*cur.uv;
      float rr = __builtin_amdgcn_exp2f(dtv*acoR);
      float a_ = __builtin_amdgcn_exp2f(dtv*aco0);
      h[0] = fmaf(a_, h[0], tv*cur.B0.x);
      a_ *= rr; h[1] = fmaf(a_, h[1], tv*cur.B0.y);
      a_ *= rr; h[2] = fmaf(a_, h[2], tv*cur.B0.z);
      a_ *= rr; h[3] = fmaf(a_, h[3], tv*cur.B0.w);
      a_ *= rr; h[4] = fmaf(a_, h[4], tv*cur.B1.x);
      a_ *= rr; h[5] = fmaf(a_, h[5], tv*cur.B1.y);
      a_ *= rr; h[6] = fmaf(a_, h[6], tv*cur.B1.z);
      a_ *= rr; h[7] = fmaf(a_, h[7], tv*cur.B1.w);
      cur = nxt;
    }
  } else {
    #pragma unroll 4
    for (int j=0;j<32;++j){
      StepH nxt;
      if (j < 31) nxt = loadH(dr, ub, Bb, scan_pix32(ch, j+1, k));
      float dtv = dt_eval(w4, bb, cur.dt4);
      Sacc += dtv;
      float tv = dtv*cur.uv;
      #define PSTEP(NI, BV) { float a_ = __builtin_amdgcn_exp2f(dtv*aco[NI]); \
        h[NI] = fmaf(a_, h[NI], tv*(BV)); }
      PSTEP(0,cur.B0.x) PSTEP(1,cur.B0.y) PSTEP(2,cur.B0.z) PSTEP(3,cur.B0.w)
      PSTEP(4,cur.B1.x) PSTEP(5,cur.B1.y) PSTEP(6,cur.B1.z) PSTEP(7,cur.B1.w)
      #undef PSTEP
      cur = nxt;
    }
  }
  size_t base = ((size_t)(sk*NCH + ch)*DIC + d)*NST + nh*8;
  *(float4*)(hend + base)     = make_float4(h[0],h[1],h[2],h[3]);
  *(float4*)(hend + base + 4) = make_float4(h[4],h[5],h[6],h[7]);
  if (nh == 0) Ssum[(size_t)(sk*NCH + ch)*DIC + d] = Sacc;
}

// ---------------- k10: full scan + y output, n-split, 768 blocks
// (scan_fix eliminated: each block computes its own chunk-prefix from hend/Ssum)
__global__ __launch_bounds__(256,4) void k_scan_y3(const float* __restrict__ dtr,
    const float* __restrict__ dtw, const float* __restrict__ dtb,
    const float* __restrict__ u_t, const float* __restrict__ Bp, const float* __restrict__ Cp,
    const float* __restrict__ A_logs, const float* __restrict__ Ds,
    const float* __restrict__ hend, const float* __restrict__ Ssum,
    float* __restrict__ ys_t){
  int bx = blockIdx.x; int ch = bx & 31; int sk = bx >> 5;
  int k = sk & 3; int s = sk >> 2;
  int tid = threadIdx.x; int d = tid >> 1; int nh = tid & 1;
  float aco[8];
  float acoR = -LOG2E * fexp(A_logs[(size_t)(k*DIC+d)*NST]);
  {
    const float* ab = A_logs + (size_t)(k*DIC+d)*NST + nh*8;
    #pragma unroll
    for (int n=0;n<8;++n) aco[n] = -LOG2E * fexp(ab[n]);
  }
  bool fast = aco_linear(aco, acoR, nh*8);
  float aco0 = aco[0];
  float4 w4 = *(const float4*)(dtw + (size_t)(k*DIC+d)*4);
  float bb = dtb[k*DIC+d];
  float Dv = Ds[k*DIC+d];
  // inline chunk-prefix: H over chunks 0..ch-1 (same recurrence as old scan_fix)
  float h[8];
  #pragma unroll
  for (int n=0;n<8;++n) h[n]=0.f;
  {
    const float* Sb = Ssum + (size_t)sk*NCH*DIC + d;
    const float* Hb = hend + ((size_t)sk*NCH*DIC + d)*NST + nh*8;
    for (int cc=0; cc<ch; ++cc){
      float Sv = Sb[(size_t)cc*DIC];
      float4 e0 = *(const float4*)(Hb + (size_t)cc*DIC*NST);
      float4 e1 = *(const float4*)(Hb + (size_t)cc*DIC*NST + 4);
      if (fast){
        float rr = __builtin_amdgcn_exp2f(acoR*Sv);
        float a_ = __builtin_amdgcn_exp2f(aco0*Sv);
        h[0] = fmaf(a_, h[0], e0.x);
        a_ *= rr; h[1] = fmaf(a_, h[1], e0.y);
        a_ *= rr; h[2] = fmaf(a_, h[2], e0.z);
        a_ *= rr; h[3] = fmaf(a_, h[3], e0.w);
        a_ *= rr; h[4] = fmaf(a_, h[4], e1.x);
        a_ *= rr; h[5] = fmaf(a_, h[5], e1.y);
        a_ *= rr; h[6] = fmaf(a_, h[6], e1.z);
        a_ *= rr; h[7] = fmaf(a_, h[7], e1.w);
      } else {
        float he[8] = {e0.x,e0.y,e0.z,e0.w,e1.x,e1.y,e1.z,e1.w};
        #pragma unroll
        for (int n=0;n<8;++n){
          float pa = __builtin_amdgcn_exp2f(aco[n]*Sv);
          h[n] = fmaf(pa, h[n], he[n]);
        }
      }
    }
  }
  const float* dr = dtr + (size_t)sk*L2*4;
  const float* ub = u_t + (size_t)s*L2*DIC + d;
  const float* Bb = Bp + (size_t)sk*L2*NST + nh*8;
  const float* Cb = Cp + (size_t)sk*L2*NST + nh*8;
  float* yb = ys_t + (size_t)sk*L2*DIC + d;
  int pcur = scan_pix32(ch, 0, k);
  StepH cur = loadH(dr, ub, Bb, pcur);
  float4 Cc0 = *(const float4*)(Cb + pcur*NST);
  float4 Cc1 = *(const float4*)(Cb + pcur*NST + 4);
  if (fast){
    #pragma unroll 4
    for (int j=0;j<32;++j){
      StepH nxt; float4 Cn0, Cn1; int pn = pcur;
      if (j < 31){
        pn = scan_pix32(ch, j+1, k);
        nxt = loadH(dr, ub, Bb, pn);
        Cn0 = *(const float4*)(Cb + pn*NST);
        Cn1 = *(const float4*)(Cb + pn*NST + 4);
      }
      float dtv = dt_eval(w4, bb, cur.dt4);
      float tv = dtv*cur.uv;
      float y0=0.f, y1=0.f, y2=0.f, y3=0.f;
      float rr = __builtin_amdgcn_exp2f(dtv*acoR);
      float a_ = __builtin_amdgcn_exp2f(dtv*aco0);
      h[0] = fmaf(a_, h[0], tv*cur.B0.x); y0 = fmaf(h[0], Cc0.x, y0);
      a_ *= rr; h[1] = fmaf(a_, h[1], tv*cur.B0.y); y1 = fmaf(h[1], Cc0.y, y1);
      a_ *= rr; h[2] = fmaf(a_, h[2], tv*cur.B0.z); y2 = fmaf(h[2], Cc0.z, y2);
      a_ *= rr; h[3] = fmaf(a_, h[3], tv*cur.B0.w); y3 = fmaf(h[3], Cc0.w, y3);
      a_ *= rr; h[4] = fmaf(a_, h[4], tv*cur.B1.x); y0 = fmaf(h[4], Cc1.x, y0);
      a_ *= rr; h[5] = fmaf(a_, h[5], tv*cur.B1.y); y1 = fmaf(h[5], Cc1.y, y1);
      a_ *= rr; h[6] = fmaf(a_, h[6], tv*cur.B1.z); y2 = fmaf(h[6], Cc1.z, y2);
      a_ *= rr; h[7] = fmaf(a_, h[7], tv*cur.B1.w); y3 = fmaf(h[7], Cc1.w, y3);
      float py = (y0+y1)+(y2+y3);
      float tot = py + __shfl_xor(py, 1, 64);
      if (nh == 0) yb[(size_t)pcur*DIC] = fmaf(cur.uv, Dv, tot);
      cur = nxt; Cc0 = Cn0; Cc1 = Cn1; pcur = pn;
    }
  } else {
    #pragma unroll 4
    for (int j=0;j<32;++j){
      StepH nxt; float4 Cn0, Cn1; int pn = pcur;
      if (j < 31){
        pn = scan_pix32(ch, j+1, k);
        nxt = loadH(dr, ub, Bb, pn);
        Cn0 = *(const float4*)(Cb + pn*NST);
        Cn1 = *(const float4*)(Cb + pn*NST + 4);
      }
      float dtv = dt_eval(w4, bb, cur.dt4);
      float tv = dtv*cur.uv;
      float y0=0.f, y1=0.f, y2=0.f, y3=0.f;
      #define YSTEP(NI, BV, CV, YA) { float a_ = __builtin_amdgcn_exp2f(dtv*aco[NI]); \
        h[NI] = fmaf(a_, h[NI], tv*(BV)); YA = fmaf(h[NI], (CV), YA); }
      YSTEP(0,cur.B0.x,Cc0.x,y0) YSTEP(1,cur.B0.y,Cc0.y,y1) YSTEP(2,cur.B0.z,Cc0.z,y2) YSTEP(3,cur.B0.w,Cc0.w,y3)
      YSTEP(4,cur.B1.x,Cc1.x,y0) YSTEP(5,cur.B1.y,Cc1.y,y1) YSTEP(6,cur.B1.z,Cc1.z,y2) YSTEP(7,cur.B1.w,Cc1.w,y3)
      #undef YSTEP
      float py = (y0+y1)+(y2+y3);
      float tot = py + __shfl_xor(py, 1, 64);
      if (nh == 0) yb[(size_t)pcur*DIC] = fmaf(cur.uv, Dv, tot);
      cur = nxt; Cc0 = Cn0; Cc1 = Cn1; pcur = pn;
    }
  }
}

// ---------------- k11: fused tail, 8 px per block, 768 blocks, packed GEMMs
__global__ __launch_bounds__(256) void k_tail(const float* __restrict__ ys_t,
    const float* __restrict__ z_t, const float* __restrict__ ong, const float* __restrict__ onb,
    const float* __restrict__ Wop, const float* __restrict__ x_cmaj,
    const float* __restrict__ g2, const float* __restrict__ b2n,
    const float* __restrict__ w1, const float* __restrict__ b1,
    const float* __restrict__ w2, const float* __restrict__ b2,
    float* __restrict__ out){
  __shared__ float yt[128*9];
  __shared__ float xvt[64*9];
  __shared__ float ts[64*9];
  int s = blockIdx.x >> 7; int pg = blockIdx.x & 127;
  int tid = threadIdx.x;
  {
    int wv = __builtin_amdgcn_readfirstlane(tid>>6); int lane = tid&63;
    int d0 = lane, d1 = lane+64;
    for (int i=0;i<2;++i){
      int px = i*4 + wv; int p = pg*8 + px;
      const float* yb = ys_t + ((size_t)(s*4)*L2 + p)*DIC;
      float ya = yb[d0] + yb[(size_t)L2*DIC + d0] + yb[(size_t)2*L2*DIC + d0] + yb[(size_t)3*L2*DIC + d0];
      float yc = yb[d1] + yb[(size_t)L2*DIC + d1] + yb[(size_t)2*L2*DIC + d1] + yb[(size_t)3*L2*DIC + d1];
      float sm = ya+yc, sq = ya*ya+yc*yc;
      for (int m=1;m<64;m<<=1){ sm+=__shfl_xor(sm,m,64); sq+=__shfl_xor(sq,m,64); }
      float mean = sm*(1.f/128.f); float var = sq*(1.f/128.f)-mean*mean;
      float rs = rsqrtf(var + 1e-5f);
      float yn0 = (ya-mean)*rs*ong[d0] + onb[d0];
      float yn1 = (yc-mean)*rs*ong[d1] + onb[d1];
      float zv0 = z_t[((size_t)s*DIC+d0)*L2 + p];
      float zv1 = z_t[((size_t)s*DIC+d1)*L2 + p];
      yt[d0*9 + px] = yn0 * fsilu(zv0);
      yt[d1*9 + px] = yn1 * fsilu(zv1);
    }
  }
  __syncthreads();
  {
    int px = tid & 7; int cgp = tid >> 3;
    int c0 = cgp*2;
    f2 A; A.x=0.f; A.y=0.f;
    for (int d=0; d<DIC; ++d){
      float yv = yt[d*9 + px];
      A = fma2(mkf2(Wop[(c0+0)*DIC + d], Wop[(c0+1)*DIC + d]), yv, A);
    }
    int p = pg*8 + px;
    size_t base = ((size_t)s*CCH + c0)*L2 + p;
    xvt[(c0+0)*9 + px] = x_cmaj[base]    + A.x;
    xvt[(c0+1)*9 + px] = x_cmaj[base+L2] + A.y;
  }
  __syncthreads();
  int px = tid & 7; int cgp = tid >> 3;
  float sm=0.f, sq=0.f;
  for (int c=0;c<64;++c){ float v = xvt[c*9+px]; sm+=v; sq+=v*v; }
  float mean = sm*(1.f/64.f);
  float rs = rsqrtf(sq*(1.f/64.f) - mean*mean + 1e-5f);
  int o0 = cgp*2;
  f2 T = mkf2(b1[o0], b1[o0+1]);
  for (int c=0;c<64;++c){
    float xn = (xvt[c*9+px]-mean)*rs*g2[c] + b2n[c];
    T = fma2(mkf2(w1[(o0+0)*64 + c], w1[(o0+1)*64 + c]), xn, T);
  }
  ts[(o0+0)*9 + px] = fgelu(T.x);
  ts[(o0+1)*9 + px] = fgelu(T.y);
  __syncthreads();
  int c0 = cgp*2;
  f2 ACC = mkf2(xvt[(c0+0)*9+px] + b2[c0+0], xvt[(c0+1)*9+px] + b2[c0+1]);
  for (int o=0;o<64;++o){
    float tv = ts[o*9+px];
    ACC = fma2(mkf2(w2[(c0+0)*64 + o], w2[(c0+1)*64 + o]), tv, ACC);
  }
  int p = pg*8 + px;
  out[((size_t)s*CCH + c0+0)*L2 + p] = ACC.x;
  out[((size_t)s*CCH + c0+1)*L2 + p] = ACC.y;
}

extern "C" void kernel_launch(void* const* d_in, const int* in_sizes, int n_in,
                              void* d_out, int out_size, void* d_ws, size_t ws_size,
                              hipStream_t stream){
  (void)in_sizes; (void)n_in; (void)out_size; (void)ws_size;
  const float* img      = (const float*)d_in[0];
  const float* dz       = (const float*)d_in[1];
  const float* sg       = (const float*)d_in[2];
  const float* norm_g   = (const float*)d_in[3];
  const float* norm_b   = (const float*)d_in[4];
  const float* gn1_g    = (const float*)d_in[5];
  const float* gn1_b    = (const float*)d_in[6];
  const float* conv1_w  = (const float*)d_in[7];
  const float* conv1_b  = (const float*)d_in[8];
  const float* gn2_g    = (const float*)d_in[9];
  const float* gn2_b    = (const float*)d_in[10];
  const float* conv2_w  = (const float*)d_in[11];
  const float* conv2_b  = (const float*)d_in[12];
  const float* skip_w   = (const float*)d_in[13];
  const float* skip_b   = (const float*)d_in[14];
  const float* ln1_g    = (const float*)d_in[15];
  const float* ln1_b    = (const float*)d_in[16];
  const float* ln2_g    = (const float*)d_in[17];
  const float* ln2_b    = (const float*)d_in[18];
  const float* in_proj_w= (const float*)d_in[19];
  const float* dwconv_w = (const float*)d_in[20];
  const float* dwconv_b = (const float*)d_in[21];
  const float* x_proj_w = (const float*)d_in[22];
  const float* dt_proj_w= (const float*)d_in[23];
  const float* dt_proj_b= (const float*)d_in[24];
  const float* A_logs   = (const float*)d_in[25];
  const float* Ds       = (const float*)d_in[26];
  const float* out_norm_g = (const float*)d_in[27];
  const float* out_norm_b = (const float*)d_in[28];
  const float* out_proj_w = (const float*)d_in[29];
  const float* fc1_w    = (const float*)d_in[30];
  const float* fc1_b    = (const float*)d_in[31];
  const float* fc2_w    = (const float*)d_in[32];
  const float* fc2_b    = (const float*)d_in[33];

  float* ws = (float*)d_ws;
  float* x3c    = ws;                       // 1,179,648
  float* xact1  = x3c    + 1179648;         // 1,253,376 (padded GN1 act)
  float* h1     = xact1  + 1253376;         // 393,216
  float* xact2  = h1     + 393216;          // 417,792 (padded GN2 act)
  float* xpslot = xact2  + 417792;          // 393,216 (hosts Bp)
  float* x_cmaj = xpslot + 393216;          // 393,216
  float* z_t    = x_cmaj + 393216;          // 786,432
  float* xc     = z_t    + 786432;          // 786,432
  float* cpslot = xc     + 786432;          // 786,432 (hosts Cp)
  float* hole   = cpslot + 786432;          // 884,736 (dtr + Ssum)
  float* scanbuf= hole   + 884736;          // 3,145,728 (conv1 partials)
  float* ys_t   = scanbuf+ 3145728;         // 3,145,728 (conv2 partials + skip first)
  float* statsb = ys_t   + 3145728;         // psum1(768) psq1(768) psum2(384) psq2(384)
  float* psum1  = statsb;
  float* psq1   = statsb + 768;
  float* psum2  = statsb + 1536;
  float* psq2   = statsb + 1920;
  // aliases into dead regions (timeline-verified, same as R7/R8):
  float* part1  = scanbuf;          // conv1 partials (12 slots: scanbuf + ys_t[0..4))
  float* part2  = ys_t;             // conv2 partials slots 0-3; skip slots 4,5
  float* hend   = x3c;              // x3c+xact1 dead after k_gnact1_skip/conv1
  float* u_t    = h1;               // h1+xact2 dead after gnact2/conv2
  float* Bp     = xpslot;
  float* Cp     = cpslot;
  float* dtr    = hole;             // 98,304
  float* Ssum   = hole + 98304;     // 98,304

  k_ln2d<<<768, 256, 0, stream>>>(img, dz, sg, norm_g, norm_b, x3c, psum1, psq1);
  k_gnact1_skip<<<1536, 256, 0, stream>>>(x3c, psum1, psq1, gn1_g, gn1_b, skip_w,
                                          xact1, part2);
  k_conv1_split<<<2304, 256, 0, stream>>>(xact1, conv1_w, part1);
  k_reduce1<<<384, 256, 0, stream>>>(part1, conv1_b, h1, psum2, psq2);
  k_gnact_pad<<<6*CCH, 256, 0, stream>>>(h1, psum2, psq2, gn2_g, gn2_b, CCH, 64,
                                         1.f/(CCH*L2), 1e-5f, xact2);
  k_conv2_split<<<768, 256, 0, stream>>>(xact2, conv2_w, part2);
  k_red2_ln1_inproj<<<768, 256, 0, stream>>>(part2, conv2_b, skip_b, ln1_g, ln1_b, in_proj_w,
                                             x_cmaj, xc, z_t);
  k_xproj_dt<<<768, 256, 0, stream>>>(xc, dwconv_w, dwconv_b, x_proj_w, dtr, Bp, Cp, u_t);
  k_scan_part3<<<768, 256, 0, stream>>>(dtr, dt_proj_w, dt_proj_b, u_t, Bp, A_logs, hend, Ssum);
  k_scan_y3<<<768, 256, 0, stream>>>(dtr, dt_proj_w, dt_proj_b, u_t, Bp, Cp, A_logs, Ds,
                                     hend, Ssum, ys_t);
  k_tail<<<768, 256, 0, stream>>>(ys_t, z_t, out_norm_g, out_norm_b, out_proj_w, x_cmaj,
                                  ln2_g, ln2_b, fc1_w, fc1_b, fc2_w, fc2_b, (float*)d_out);
}